// Round 1
// baseline (605.180 us; speedup 1.0000x reference)
//
#include <hip/hip_runtime.h>
#include <math.h>

#define NNODES 50000
#define NEDGES 800000
#define NEG_SLOPE 0.2f

// ---------------------------------------------------------------------------
// CSR build: dst is sorted ascending; row_ptr[n] = lower_bound(dst, n).
// ---------------------------------------------------------------------------
__global__ __launch_bounds__(256) void build_row_ptr(const int* __restrict__ dst,
                                                     int* __restrict__ row_ptr) {
    int n = blockIdx.x * blockDim.x + threadIdx.x;
    if (n > NNODES) return;
    int lo = 0, hi = NEDGES;
    while (lo < hi) {
        int mid = (lo + hi) >> 1;
        if (dst[mid] < n) lo = mid + 1; else hi = mid;
    }
    row_ptr[n] = lo;
}

// ---------------------------------------------------------------------------
// fp32 SGEMM: C[M,N] = A[M,K] * B[K,N].  BM=BN=64, BK=16, 256 thr, 4x4 micro.
// K must be a multiple of 16 (256 here). Guards on M rows and N cols.
// ---------------------------------------------------------------------------
#define BM 64
#define BN 64
#define BK 16

__global__ __launch_bounds__(256) void sgemm(const float* __restrict__ A,
                                             const float* __restrict__ B,
                                             float* __restrict__ C,
                                             int M, int N, int K) {
    __shared__ float As[BK][BM];
    __shared__ float Bs[BK][BN];
    const int tid = threadIdx.x;
    const int bm = blockIdx.x * BM;
    const int bn = blockIdx.y * BN;
    const int tx = tid & 15;          // 0..15 -> col group
    const int ty = tid >> 4;          // 0..15 -> row group
    const int a_k = tid & 15;         // k index for A loads
    const int a_m = tid >> 4;         // m base for A loads (+16*i)
    const int b_n = tid & 63;         // n index for B loads
    const int b_k = tid >> 6;         // k base for B loads (+4*i)

    float acc[4][4] = {};

    for (int k0 = 0; k0 < K; k0 += BK) {
#pragma unroll
        for (int i = 0; i < 4; i++) {
            int m = a_m + 16 * i;
            int row = bm + m;
            As[a_k][m] = (row < M) ? A[(long)row * K + k0 + a_k] : 0.f;
        }
#pragma unroll
        for (int i = 0; i < 4; i++) {
            int k = b_k + 4 * i;
            int col = bn + b_n;
            Bs[k][b_n] = (col < N) ? B[(long)(k0 + k) * N + col] : 0.f;
        }
        __syncthreads();
#pragma unroll
        for (int k = 0; k < BK; k++) {
            float a[4], b[4];
#pragma unroll
            for (int i = 0; i < 4; i++) a[i] = As[k][ty * 4 + i];
#pragma unroll
            for (int j = 0; j < 4; j++) b[j] = Bs[k][tx * 4 + j];
#pragma unroll
            for (int i = 0; i < 4; i++)
#pragma unroll
                for (int j = 0; j < 4; j++) acc[i][j] += a[i] * b[j];
        }
        __syncthreads();
    }
#pragma unroll
    for (int i = 0; i < 4; i++) {
        int row = bm + ty * 4 + i;
        if (row >= M) continue;
#pragma unroll
        for (int j = 0; j < 4; j++) {
            int col = bn + tx * 4 + j;
            if (col < N) C[(long)row * N + col] = acc[i][j];
        }
    }
}

// ---------------------------------------------------------------------------
// Layer-1 attention logits: el[n,h] = sum_d fs1[n,h,d]*al1[h,d]; same for er.
// One block per node; wave w (64 lanes) reduces head w.
// ---------------------------------------------------------------------------
__global__ __launch_bounds__(256) void logits1(const float* __restrict__ fs1,
                                               const float* __restrict__ al,
                                               const float* __restrict__ ar,
                                               float* __restrict__ el,
                                               float* __restrict__ er) {
    int n = blockIdx.x;
    int tid = threadIdx.x;
    int h = tid >> 6, d = tid & 63;
    float v = fs1[n * 256 + tid];
    float pa = v * al[h * 64 + d];
    float pb = v * ar[h * 64 + d];
    for (int off = 32; off > 0; off >>= 1) {
        pa += __shfl_down(pa, off);
        pb += __shfl_down(pb, off);
    }
    if (d == 0) { el[n * 4 + h] = pa; er[n * 4 + h] = pb; }
}

// ---------------------------------------------------------------------------
// Layer-1 segment softmax + aggregate. One block per dst node, 256 threads =
// 4 waves = 4 heads; wave w owns head w, thread owns channel c = tid.
// Pass A: exact segment max + exp-sum (butterfly so all lanes hold m,s).
// Pass B: acc = sum_e exp(e-m) * fs1[src_e, c];  out = relu(acc/s + b1).
// ---------------------------------------------------------------------------
__global__ __launch_bounds__(256) void agg1(const int* __restrict__ row_ptr,
                                            const int* __restrict__ src,
                                            const float* __restrict__ el,
                                            const float* __restrict__ er,
                                            const float* __restrict__ fs1,
                                            const float* __restrict__ b1,
                                            float* __restrict__ hout) {
    int n = blockIdx.x;
    int tid = threadIdx.x;
    int h = tid >> 6, d = tid & 63;
    int start = row_ptr[n], end = row_ptr[n + 1];
    float erv = er[n * 4 + h];

    float m = -1e30f, s = 0.f;
    for (int i = start + d; i < end; i += 64) {
        int sv = src[i];
        float e = el[sv * 4 + h] + erv;
        e = e > 0.f ? e : NEG_SLOPE * e;
        float nm = fmaxf(m, e);
        s = s * __expf(m - nm) + __expf(e - nm);
        m = nm;
    }
    for (int off = 32; off > 0; off >>= 1) {
        float mo = __shfl_xor(m, off), so = __shfl_xor(s, off);
        float nm = fmaxf(m, mo);
        s = s * __expf(m - nm) + so * __expf(mo - nm);
        m = nm;
    }

    float acc = 0.f;
    for (int i = start; i < end; i++) {
        int sv = src[i];
        float e = el[sv * 4 + h] + erv;
        e = e > 0.f ? e : NEG_SLOPE * e;
        float w = __expf(e - m);
        acc += w * fs1[sv * 256 + tid];
    }
    float val = (end > start) ? acc / s : 0.f;
    val += b1[tid];
    hout[n * 256 + tid] = fmaxf(val, 0.f);
}

// ---------------------------------------------------------------------------
// Layer-2 logits: single head, dot over 47 channels. One wave per node,
// 4 nodes per block.
// ---------------------------------------------------------------------------
__global__ __launch_bounds__(256) void logits2(const float* __restrict__ fs2,
                                               const float* __restrict__ al,
                                               const float* __restrict__ ar,
                                               float* __restrict__ el,
                                               float* __restrict__ er) {
    int lane = threadIdx.x & 63;
    int n = blockIdx.x * 4 + (threadIdx.x >> 6);
    if (n >= NNODES) return;
    float pa = 0.f, pb = 0.f;
    if (lane < 47) {
        float v = fs2[n * 47 + lane];
        pa = v * al[lane];
        pb = v * ar[lane];
    }
    for (int off = 32; off > 0; off >>= 1) {
        pa += __shfl_down(pa, off);
        pb += __shfl_down(pb, off);
    }
    if (lane == 0) { el[n] = pa; er[n] = pb; }
}

// ---------------------------------------------------------------------------
// Layer-2 segment softmax + aggregate. One wave per node (4 nodes / block).
// Lanes 0..46 own output channels. Final: out = acc/s + b2 (mean over 1 head).
// ---------------------------------------------------------------------------
__global__ __launch_bounds__(256) void agg2(const int* __restrict__ row_ptr,
                                            const int* __restrict__ src,
                                            const float* __restrict__ el,
                                            const float* __restrict__ er,
                                            const float* __restrict__ fs2,
                                            const float* __restrict__ b2,
                                            float* __restrict__ out) {
    int lane = threadIdx.x & 63;
    int n = blockIdx.x * 4 + (threadIdx.x >> 6);
    if (n >= NNODES) return;
    int start = row_ptr[n], end = row_ptr[n + 1];
    float erv = er[n];

    float m = -1e30f, s = 0.f;
    for (int i = start + lane; i < end; i += 64) {
        float e = el[src[i]] + erv;
        e = e > 0.f ? e : NEG_SLOPE * e;
        float nm = fmaxf(m, e);
        s = s * __expf(m - nm) + __expf(e - nm);
        m = nm;
    }
    for (int off = 32; off > 0; off >>= 1) {
        float mo = __shfl_xor(m, off), so = __shfl_xor(s, off);
        float nm = fmaxf(m, mo);
        s = s * __expf(m - nm) + so * __expf(mo - nm);
        m = nm;
    }

    float acc = 0.f;
    for (int i = start; i < end; i++) {
        int sv = src[i];
        float e = el[sv] + erv;
        e = e > 0.f ? e : NEG_SLOPE * e;
        float w = __expf(e - m);
        if (lane < 47) acc += w * fs2[sv * 47 + lane];
    }
    if (lane < 47) {
        float val = (end > start) ? acc / s : 0.f;
        out[n * 47 + lane] = val + b2[lane];
    }
}

// ---------------------------------------------------------------------------
// Launch. Inputs (setup_inputs order):
// 0:x 1:W1 2:al1 3:ar1 4:b1 5:W2 6:al2 7:ar2 8:b2 9:src 10:dst
// Workspace layout (~114 MB): row_ptr | fs1 | el1 | er1 | h1 | fs2 | el2 | er2
// ---------------------------------------------------------------------------
extern "C" void kernel_launch(void* const* d_in, const int* in_sizes, int n_in,
                              void* d_out, int out_size, void* d_ws, size_t ws_size,
                              hipStream_t stream) {
    const float* x   = (const float*)d_in[0];
    const float* W1  = (const float*)d_in[1];
    const float* al1 = (const float*)d_in[2];
    const float* ar1 = (const float*)d_in[3];
    const float* b1  = (const float*)d_in[4];
    const float* W2  = (const float*)d_in[5];
    const float* al2 = (const float*)d_in[6];
    const float* ar2 = (const float*)d_in[7];
    const float* b2  = (const float*)d_in[8];
    const int*   src = (const int*)d_in[9];
    const int*   dst = (const int*)d_in[10];
    float* out = (float*)d_out;

    char* ws = (char*)d_ws;
    size_t off = 0;
    auto alloc = [&](size_t bytes) {
        void* p = ws + off;
        off += (bytes + 255) & ~(size_t)255;
        return p;
    };
    int*   row_ptr = (int*)alloc((NNODES + 1) * sizeof(int));
    float* fs1     = (float*)alloc((size_t)NNODES * 256 * sizeof(float));
    float* el1     = (float*)alloc((size_t)NNODES * 4 * sizeof(float));
    float* er1     = (float*)alloc((size_t)NNODES * 4 * sizeof(float));
    float* h1      = (float*)alloc((size_t)NNODES * 256 * sizeof(float));
    float* fs2     = (float*)alloc((size_t)NNODES * 47 * sizeof(float));
    float* el2     = (float*)alloc((size_t)NNODES * sizeof(float));
    float* er2     = (float*)alloc((size_t)NNODES * sizeof(float));
    (void)ws_size; (void)n_in; (void)in_sizes; (void)out_size;

    build_row_ptr<<<(NNODES + 256) / 256, 256, 0, stream>>>(dst, row_ptr);

    // Layer 1
    sgemm<<<dim3((NNODES + BM - 1) / BM, 256 / BN), 256, 0, stream>>>(x, W1, fs1, NNODES, 256, 256);
    logits1<<<NNODES, 256, 0, stream>>>(fs1, al1, ar1, el1, er1);
    agg1<<<NNODES, 256, 0, stream>>>(row_ptr, src, el1, er1, fs1, b1, h1);

    // Layer 2
    sgemm<<<dim3((NNODES + BM - 1) / BM, 1), 256, 0, stream>>>(h1, W2, fs2, NNODES, 47, 256);
    logits2<<<(NNODES + 3) / 4, 256, 0, stream>>>(fs2, al2, ar2, el2, er2);
    agg2<<<(NNODES + 3) / 4, 256, 0, stream>>>(row_ptr, src, el2, er2, fs2, b2, out);
}

// Round 2
// 462.835 us; speedup vs baseline: 1.3076x; 1.3076x over previous
//
#include <hip/hip_runtime.h>
#include <math.h>

#define NNODES 50000
#define NEDGES 800000
#define NEG_SLOPE 0.2f
#define MPAD 50048   // 391 * 128, padded M for the 128-row GEMM tiles

typedef __attribute__((ext_vector_type(8))) short short8;
typedef __attribute__((ext_vector_type(4))) float floatx4;

// bf16 helpers (RNE to match numpy/JAX rounding closely)
__device__ __forceinline__ unsigned short f2bf(float f) {
    union { float f; unsigned int u; } v; v.f = f;
    unsigned int r = v.u + 0x7FFFu + ((v.u >> 16) & 1u);
    return (unsigned short)(r >> 16);
}
__device__ __forceinline__ float bf2f(unsigned int s) {
    union { unsigned int u; float f; } v; v.u = s << 16; return v.f;
}

// ---------------------------------------------------------------------------
// CSR build: dst is sorted ascending; row_ptr[n] = lower_bound(dst, n).
// ---------------------------------------------------------------------------
__global__ __launch_bounds__(256) void build_row_ptr(const int* __restrict__ dst,
                                                     int* __restrict__ row_ptr) {
    int n = blockIdx.x * blockDim.x + threadIdx.x;
    if (n > NNODES) return;
    int lo = 0, hi = NEDGES;
    while (lo < hi) {
        int mid = (lo + hi) >> 1;
        if (dst[mid] < n) lo = mid + 1; else hi = mid;
    }
    row_ptr[n] = lo;
}

// ---------------------------------------------------------------------------
// x (fp32 [50000,256]) -> xb (bf16 [MPAD,256]); pad rows zeroed.
// ---------------------------------------------------------------------------
__global__ __launch_bounds__(256) void convert_x(const float* __restrict__ x,
                                                 unsigned short* __restrict__ xb) {
    long e = ((long)blockIdx.x * 256 + threadIdx.x) * 4;
    const long NE = (long)NNODES * 256;
    ushort4 o;
    o.x = (e + 0 < NE) ? f2bf(x[e + 0]) : 0;
    o.y = (e + 1 < NE) ? f2bf(x[e + 1]) : 0;
    o.z = (e + 2 < NE) ? f2bf(x[e + 2]) : 0;
    o.w = (e + 3 < NE) ? f2bf(x[e + 3]) : 0;
    *(ushort4*)(xb + e) = o;
}

// ---------------------------------------------------------------------------
// W1 (fp32 [K=256][N=256]) -> bf16 B-fragment table laid out so a wave's
// B-frag load is one contiguous 1KB dwordx4 sweep:
//   chunk c = (t*8 + kk)*64 + lane,  lane: n = t*16 + (lane&15),
//   k = kk*32 + (lane>>4)*8 + j  (j = 0..7 within the chunk)
// ---------------------------------------------------------------------------
__global__ __launch_bounds__(256) void build_bfrag(const float* __restrict__ W1,
                                                   unsigned short* __restrict__ bfrag) {
    int c = blockIdx.x * 256 + threadIdx.x;   // 8192 chunks
    if (c >= 16 * 8 * 64) return;
    int l = c & 63, kk = (c >> 6) & 7, t = c >> 9;
    int n = t * 16 + (l & 15);
    int kbase = kk * 32 + (l >> 4) * 8;
#pragma unroll
    for (int j = 0; j < 8; j++)
        bfrag[c * 8 + j] = f2bf(W1[(kbase + j) * 256 + n]);
}

// ---------------------------------------------------------------------------
// GEMM1: fs1b[M,256] = xb[M,256] @ W1  (bf16 in, fp32 acc, bf16 out).
// Block 256 thr = 4 waves; BM=128 (wave owns 32 rows), BN=64, K-loop of 8.
// Fragments straight from global: A chunks are 16B contiguous; B from the
// L2-resident pre-swizzled table. MFMA layouts (measured, m89/m120):
//   A: lane l -> m = l&15, k = (l>>4)*8 + j   (B symmetric: n = l&15)
//   D: col = l&15, row = (l>>4)*4 + reg
// ---------------------------------------------------------------------------
__global__ __launch_bounds__(256) void mfma_gemm1(const unsigned short* __restrict__ xb,
                                                  const unsigned short* __restrict__ bfrag,
                                                  unsigned short* __restrict__ fs1b) {
    const int w = threadIdx.x >> 6;
    const int l = threadIdx.x & 63;
    const int bm = blockIdx.x * 128;
    const int n0 = blockIdx.y * 64;
    const int lm = l & 15, lk = l >> 4;

    floatx4 acc[2][4];
#pragma unroll
    for (int i = 0; i < 2; i++)
#pragma unroll
        for (int j = 0; j < 4; j++) acc[i][j] = (floatx4){0.f, 0.f, 0.f, 0.f};

    const int t0 = n0 >> 4;
#pragma unroll
    for (int kk = 0; kk < 8; kk++) {
        const unsigned short* abase = xb + (long)(bm + w * 32 + lm) * 256 + kk * 32 + lk * 8;
        short8 a0 = *(const short8*)(abase);
        short8 a1 = *(const short8*)(abase + 16 * 256);
        const unsigned short* bbase = bfrag + ((t0 * 8 + kk) * 64 + l) * 8;
        short8 b[4];
#pragma unroll
        for (int j = 0; j < 4; j++) b[j] = *(const short8*)(bbase + j * 8 * 64 * 8);
#pragma unroll
        for (int j = 0; j < 4; j++) {
            acc[0][j] = __builtin_amdgcn_mfma_f32_16x16x32_bf16(a0, b[j], acc[0][j], 0, 0, 0);
            acc[1][j] = __builtin_amdgcn_mfma_f32_16x16x32_bf16(a1, b[j], acc[1][j], 0, 0, 0);
        }
    }
#pragma unroll
    for (int i = 0; i < 2; i++) {
        int row0 = bm + w * 32 + i * 16 + lk * 4;
#pragma unroll
        for (int r = 0; r < 4; r++) {
            int row = row0 + r;
            if (row >= NNODES) continue;
#pragma unroll
            for (int j = 0; j < 4; j++) {
                int col = n0 + j * 16 + lm;
                fs1b[(long)row * 256 + col] = f2bf(acc[i][j][r]);
            }
        }
    }
}

// ---------------------------------------------------------------------------
// Layer-1 logits from the bf16 fs1 table. One block per node, wave = head.
// ---------------------------------------------------------------------------
__global__ __launch_bounds__(256) void logits1(const unsigned short* __restrict__ fs1b,
                                               const float* __restrict__ al,
                                               const float* __restrict__ ar,
                                               float* __restrict__ el,
                                               float* __restrict__ er) {
    int n = blockIdx.x;
    int tid = threadIdx.x;
    int h = tid >> 6, d = tid & 63;
    float v = bf2f(fs1b[(long)n * 256 + tid]);
    float pa = v * al[h * 64 + d];
    float pb = v * ar[h * 64 + d];
    for (int off = 32; off > 0; off >>= 1) {
        pa += __shfl_down(pa, off);
        pb += __shfl_down(pb, off);
    }
    if (d == 0) { el[n * 4 + h] = pa; er[n * 4 + h] = pb; }
}

// ---------------------------------------------------------------------------
// Layer-1 segment softmax + aggregate. Block = node, 4 waves.
// Pass A: wave w = head w, exact online max+sum, butterfly, -> LDS.
// Pass B: one WAVE per edge (wave w takes edges start+w, step 4); lane owns
// channels 4l..4l+3 (head = l>>4, one exp per lane), dwordx2 bf16 gather.
// Cross-wave combine via LDS, then val = relu(acc/s + b1).
// ---------------------------------------------------------------------------
__global__ __launch_bounds__(256) void agg1(const int* __restrict__ row_ptr,
                                            const int* __restrict__ src,
                                            const float* __restrict__ el,
                                            const float* __restrict__ er,
                                            const unsigned short* __restrict__ fs1b,
                                            const float* __restrict__ b1,
                                            float* __restrict__ hout) {
    __shared__ float sm_m[4], sm_s[4];
    __shared__ float red[4][256];
    int n = blockIdx.x;
    int tid = threadIdx.x;
    int w = tid >> 6, l = tid & 63;
    int start = row_ptr[n], end = row_ptr[n + 1];

    {   // Pass A
        float erv = er[n * 4 + w];
        float m = -1e30f, s = 0.f;
        for (int i = start + l; i < end; i += 64) {
            float e = el[src[i] * 4 + w] + erv;
            e = e > 0.f ? e : NEG_SLOPE * e;
            float nm = fmaxf(m, e);
            s = s * __expf(m - nm) + __expf(e - nm);
            m = nm;
        }
        for (int off = 32; off > 0; off >>= 1) {
            float mo = __shfl_xor(m, off), so = __shfl_xor(s, off);
            float nm = fmaxf(m, mo);
            s = s * __expf(m - nm) + so * __expf(mo - nm);
            m = nm;
        }
        if (l == 0) { sm_m[w] = m; sm_s[w] = s; }
    }
    __syncthreads();

    int hl = l >> 4;
    float mh = sm_m[hl];
    float erv = er[n * 4 + hl];
    float a0 = 0.f, a1 = 0.f, a2 = 0.f, a3 = 0.f;
    for (int i = start + w; i < end; i += 4) {
        int sv = src[i];
        float e = el[sv * 4 + hl] + erv;
        e = e > 0.f ? e : NEG_SLOPE * e;
        float we = __expf(e - mh);
        uint2 q = *(const uint2*)(fs1b + (long)sv * 256 + l * 4);
        a0 += we * bf2f(q.x & 0xFFFFu);
        a1 += we * bf2f(q.x >> 16);
        a2 += we * bf2f(q.y & 0xFFFFu);
        a3 += we * bf2f(q.y >> 16);
    }
    *(float4*)(&red[w][l * 4]) = make_float4(a0, a1, a2, a3);
    __syncthreads();

    int c = tid;
    float tot = red[0][c] + red[1][c] + red[2][c] + red[3][c];
    float val = (end > start) ? tot / sm_s[c >> 6] : 0.f;
    val += b1[c];
    hout[(long)n * 256 + c] = fmaxf(val, 0.f);
}

// ---------------------------------------------------------------------------
// fp32 SGEMM (kept for layer 2: [50000,256]x[256,47]). BM=BN=64, BK=16.
// ---------------------------------------------------------------------------
#define BM 64
#define BN 64
#define BK 16
__global__ __launch_bounds__(256) void sgemm(const float* __restrict__ A,
                                             const float* __restrict__ B,
                                             float* __restrict__ C,
                                             int M, int N, int K) {
    __shared__ float As[BK][BM];
    __shared__ float Bs[BK][BN];
    const int tid = threadIdx.x;
    const int bm = blockIdx.x * BM;
    const int bn = blockIdx.y * BN;
    const int tx = tid & 15;
    const int ty = tid >> 4;
    const int a_k = tid & 15;
    const int a_m = tid >> 4;
    const int b_n = tid & 63;
    const int b_k = tid >> 6;

    float acc[4][4] = {};
    for (int k0 = 0; k0 < K; k0 += BK) {
#pragma unroll
        for (int i = 0; i < 4; i++) {
            int m = a_m + 16 * i;
            int row = bm + m;
            As[a_k][m] = (row < M) ? A[(long)row * K + k0 + a_k] : 0.f;
        }
#pragma unroll
        for (int i = 0; i < 4; i++) {
            int k = b_k + 4 * i;
            int col = bn + b_n;
            Bs[k][b_n] = (col < N) ? B[(long)(k0 + k) * N + col] : 0.f;
        }
        __syncthreads();
#pragma unroll
        for (int k = 0; k < BK; k++) {
            float a[4], b[4];
#pragma unroll
            for (int i = 0; i < 4; i++) a[i] = As[k][ty * 4 + i];
#pragma unroll
            for (int j = 0; j < 4; j++) b[j] = Bs[k][tx * 4 + j];
#pragma unroll
            for (int i = 0; i < 4; i++)
#pragma unroll
                for (int j = 0; j < 4; j++) acc[i][j] += a[i] * b[j];
        }
        __syncthreads();
    }
#pragma unroll
    for (int i = 0; i < 4; i++) {
        int row = bm + ty * 4 + i;
        if (row >= M) continue;
#pragma unroll
        for (int j = 0; j < 4; j++) {
            int col = bn + tx * 4 + j;
            if (col < N) C[(long)row * N + col] = acc[i][j];
        }
    }
}

// ---------------------------------------------------------------------------
// Layer-2 logits: dot over 47 channels, one wave per node, 4 nodes/block.
// ---------------------------------------------------------------------------
__global__ __launch_bounds__(256) void logits2(const float* __restrict__ fs2,
                                               const float* __restrict__ al,
                                               const float* __restrict__ ar,
                                               float* __restrict__ el,
                                               float* __restrict__ er) {
    int lane = threadIdx.x & 63;
    int n = blockIdx.x * 4 + (threadIdx.x >> 6);
    if (n >= NNODES) return;
    float pa = 0.f, pb = 0.f;
    if (lane < 47) {
        float v = fs2[(long)n * 47 + lane];
        pa = v * al[lane];
        pb = v * ar[lane];
    }
    for (int off = 32; off > 0; off >>= 1) {
        pa += __shfl_down(pa, off);
        pb += __shfl_down(pb, off);
    }
    if (lane == 0) { el[n] = pa; er[n] = pb; }
}

// ---------------------------------------------------------------------------
// Layer-2 segment softmax + aggregate. 2 nodes/block, 2 waves per node.
// ---------------------------------------------------------------------------
__global__ __launch_bounds__(256) void agg2(const int* __restrict__ row_ptr,
                                            const int* __restrict__ src,
                                            const float* __restrict__ el,
                                            const float* __restrict__ er,
                                            const float* __restrict__ fs2,
                                            const float* __restrict__ b2,
                                            float* __restrict__ out) {
    __shared__ float sm[2][2][2];    // [node][wave-pair][m,s]
    __shared__ float red[2][2][64];  // [node][wave-pair][chan]
    int tid = threadIdx.x;
    int q = tid >> 6;
    int nd = q >> 1, v = q & 1;
    int l = tid & 63;
    int n = blockIdx.x * 2 + nd;     // NNODES even -> always valid
    int start = row_ptr[n], end = row_ptr[n + 1];
    float erv = er[n];

    float m = -1e30f, s = 0.f;
    for (int i = start + v * 64 + l; i < end; i += 128) {
        float e = el[src[i]] + erv;
        e = e > 0.f ? e : NEG_SLOPE * e;
        float nm = fmaxf(m, e);
        s = s * __expf(m - nm) + __expf(e - nm);
        m = nm;
    }
    for (int off = 32; off > 0; off >>= 1) {
        float mo = __shfl_xor(m, off), so = __shfl_xor(s, off);
        float nm = fmaxf(m, mo);
        s = s * __expf(m - nm) + so * __expf(mo - nm);
        m = nm;
    }
    if (l == 0) { sm[nd][v][0] = m; sm[nd][v][1] = s; }
    __syncthreads();

    float m0 = sm[nd][0][0], m1 = sm[nd][1][0];
    float M = fmaxf(m0, m1);
    float S = sm[nd][0][1] * __expf(m0 - M) + sm[nd][1][1] * __expf(m1 - M);

    int lc = l < 47 ? l : 46;   // clamp so all lanes load in-bounds rows
    float acc = 0.f;
    for (int i = start + v; i < end; i += 2) {
        int sv = src[i];
        float e = el[sv] + erv;
        e = e > 0.f ? e : NEG_SLOPE * e;
        float we = __expf(e - M);
        acc += we * fs2[(long)sv * 47 + lc];
    }
    red[nd][v][l] = acc;
    __syncthreads();

    if (v == 0 && l < 47) {
        float tot = red[nd][0][l] + red[nd][1][l];
        float val = (end > start) ? tot / S : 0.f;
        out[(long)n * 47 + l] = val + b2[l];
    }
}

// ---------------------------------------------------------------------------
// Launch. Inputs: 0:x 1:W1 2:al1 3:ar1 4:b1 5:W2 6:al2 7:ar2 8:b2 9:src 10:dst
// ---------------------------------------------------------------------------
extern "C" void kernel_launch(void* const* d_in, const int* in_sizes, int n_in,
                              void* d_out, int out_size, void* d_ws, size_t ws_size,
                              hipStream_t stream) {
    const float* x   = (const float*)d_in[0];
    const float* W1  = (const float*)d_in[1];
    const float* al1 = (const float*)d_in[2];
    const float* ar1 = (const float*)d_in[3];
    const float* b1  = (const float*)d_in[4];
    const float* W2  = (const float*)d_in[5];
    const float* al2 = (const float*)d_in[6];
    const float* ar2 = (const float*)d_in[7];
    const float* b2  = (const float*)d_in[8];
    const int*   src = (const int*)d_in[9];
    const int*   dst = (const int*)d_in[10];
    float* out = (float*)d_out;

    char* ws = (char*)d_ws;
    size_t off = 0;
    auto alloc = [&](size_t bytes) {
        void* p = ws + off;
        off += (bytes + 255) & ~(size_t)255;
        return p;
    };
    int*            row_ptr = (int*)alloc((NNODES + 1) * sizeof(int));
    unsigned short* xb      = (unsigned short*)alloc((size_t)MPAD * 256 * 2);
    unsigned short* bfrag   = (unsigned short*)alloc(16 * 8 * 64 * 8 * 2);
    unsigned short* fs1b    = (unsigned short*)alloc((size_t)NNODES * 256 * 2);
    float*          el1     = (float*)alloc((size_t)NNODES * 4 * sizeof(float));
    float*          er1     = (float*)alloc((size_t)NNODES * 4 * sizeof(float));
    float*          h1      = (float*)alloc((size_t)NNODES * 256 * sizeof(float));
    float*          fs2     = (float*)alloc((size_t)NNODES * 47 * sizeof(float));
    float*          el2     = (float*)alloc((size_t)NNODES * sizeof(float));
    float*          er2     = (float*)alloc((size_t)NNODES * sizeof(float));
    (void)ws_size; (void)n_in; (void)in_sizes; (void)out_size;

    build_row_ptr<<<(NNODES + 256) / 256, 256, 0, stream>>>(dst, row_ptr);
    convert_x<<<(MPAD * 256 / 4 + 255) / 256, 256, 0, stream>>>(x, xb);
    build_bfrag<<<(16 * 8 * 64 + 255) / 256, 256, 0, stream>>>(W1, bfrag);

    // Layer 1 (bf16 MFMA GEMM + bf16 gather)
    mfma_gemm1<<<dim3(MPAD / 128, 4), 256, 0, stream>>>(xb, bfrag, fs1b);
    logits1<<<NNODES, 256, 0, stream>>>(fs1b, al1, ar1, el1, er1);
    agg1<<<NNODES, 256, 0, stream>>>(row_ptr, src, el1, er1, fs1b, b1, h1);

    // Layer 2 (fp32)
    sgemm<<<dim3((NNODES + BM - 1) / BM, 1), 256, 0, stream>>>(h1, W2, fs2, NNODES, 47, 256);
    logits2<<<(NNODES + 3) / 4, 256, 0, stream>>>(fs2, al2, ar2, el2, er2);
    agg2<<<NNODES / 2, 256, 0, stream>>>(row_ptr, src, el2, er2, fs2, b2, out);
}

// Round 3
// 408.238 us; speedup vs baseline: 1.4824x; 1.1337x over previous
//
#include <hip/hip_runtime.h>
#include <math.h>

#define NNODES 50000
#define NEDGES 800000
#define NEG_SLOPE 0.2f
#define MPAD 50048   // 391 * 128, padded M for the 128-row GEMM tiles
#define CAP1 192     // LDS weight-cache per head (layer 1); fallback recompute past it
#define CAP2 192

typedef __attribute__((ext_vector_type(8))) short short8;
typedef __attribute__((ext_vector_type(4))) float floatx4;

// bf16 helpers (RNE)
__device__ __forceinline__ unsigned short f2bf(float f) {
    union { float f; unsigned int u; } v; v.f = f;
    unsigned int r = v.u + 0x7FFFu + ((v.u >> 16) & 1u);
    return (unsigned short)(r >> 16);
}
__device__ __forceinline__ float bf2f(unsigned int s) {
    union { unsigned int u; float f; } v; v.u = s << 16; return v.f;
}

// ---------------------------------------------------------------------------
// CSR build: dst sorted ascending; row_ptr[n] = lower_bound(dst, n).
// ---------------------------------------------------------------------------
__global__ __launch_bounds__(256) void build_row_ptr(const int* __restrict__ dst,
                                                     int* __restrict__ row_ptr) {
    int n = blockIdx.x * blockDim.x + threadIdx.x;
    if (n > NNODES) return;
    int lo = 0, hi = NEDGES;
    while (lo < hi) {
        int mid = (lo + hi) >> 1;
        if (dst[mid] < n) lo = mid + 1; else hi = mid;
    }
    row_ptr[n] = lo;
}

// ---------------------------------------------------------------------------
// x (fp32 [50000,256]) -> xb (bf16 [MPAD,256]); pad rows zeroed.
// ---------------------------------------------------------------------------
__global__ __launch_bounds__(256) void convert_x(const float* __restrict__ x,
                                                 unsigned short* __restrict__ xb) {
    long e = ((long)blockIdx.x * 256 + threadIdx.x) * 4;
    const long NE = (long)NNODES * 256;
    ushort4 o;
    o.x = (e + 0 < NE) ? f2bf(x[e + 0]) : 0;
    o.y = (e + 1 < NE) ? f2bf(x[e + 1]) : 0;
    o.z = (e + 2 < NE) ? f2bf(x[e + 2]) : 0;
    o.w = (e + 3 < NE) ? f2bf(x[e + 3]) : 0;
    *(ushort4*)(xb + e) = o;
}

// ---------------------------------------------------------------------------
// Zero the padded rows of h1b [MPAD,256] so GEMM2's tail tiles are clean.
// ---------------------------------------------------------------------------
__global__ __launch_bounds__(256) void zero_pad_h1(unsigned short* __restrict__ h1b) {
    h1b[(size_t)(NNODES + blockIdx.x) * 256 + threadIdx.x] = 0;
}

// ---------------------------------------------------------------------------
// W1 (fp32 [K=256][N=256]) -> bf16 B-fragment table (wave-contiguous chunks):
// chunk c = (t*8+kk)*64+lane; lane: n = t*16+(l&15), k = kk*32+(l>>4)*8+j.
// ---------------------------------------------------------------------------
__global__ __launch_bounds__(256) void build_bfrag(const float* __restrict__ W1,
                                                   unsigned short* __restrict__ bfrag) {
    int c = blockIdx.x * 256 + threadIdx.x;   // 8192 chunks
    if (c >= 16 * 8 * 64) return;
    int l = c & 63, kk = (c >> 6) & 7, t = c >> 9;
    int n = t * 16 + (l & 15);
    int kbase = kk * 32 + (l >> 4) * 8;
#pragma unroll
    for (int j = 0; j < 8; j++)
        bfrag[c * 8 + j] = f2bf(W1[(kbase + j) * 256 + n]);
}

// ---------------------------------------------------------------------------
// W2 (fp32 [256][47]) -> bf16 B-fragment table, N padded to 48 (3 tiles).
// ---------------------------------------------------------------------------
__global__ __launch_bounds__(256) void build_bfrag2(const float* __restrict__ W2,
                                                    unsigned short* __restrict__ bfrag) {
    int c = blockIdx.x * 256 + threadIdx.x;   // 1536 chunks
    if (c >= 3 * 8 * 64) return;
    int l = c & 63, kk = (c >> 6) & 7, t = c >> 9;
    int n = t * 16 + (l & 15);
    int kbase = kk * 32 + (l >> 4) * 8;
#pragma unroll
    for (int j = 0; j < 8; j++)
        bfrag[c * 8 + j] = (n < 47) ? f2bf(W2[(kbase + j) * 47 + n]) : 0;
}

// ---------------------------------------------------------------------------
// GEMM1: fs1b[M,256] = xb @ W1 (bf16 MFMA). Block = 4 waves, BM=128, BN=64.
// MFMA 16x16x32 layouts (measured): A lane l -> m=l&15, k=(l>>4)*8+j;
// D: col=l&15, row=(l>>4)*4+reg.
// ---------------------------------------------------------------------------
__global__ __launch_bounds__(256) void mfma_gemm1(const unsigned short* __restrict__ xb,
                                                  const unsigned short* __restrict__ bfrag,
                                                  unsigned short* __restrict__ fs1b) {
    const int w = threadIdx.x >> 6;
    const int l = threadIdx.x & 63;
    const int bm = blockIdx.x * 128;
    const int n0 = blockIdx.y * 64;
    const int lm = l & 15, lk = l >> 4;

    floatx4 acc[2][4];
#pragma unroll
    for (int i = 0; i < 2; i++)
#pragma unroll
        for (int j = 0; j < 4; j++) acc[i][j] = (floatx4){0.f, 0.f, 0.f, 0.f};

    const int t0 = n0 >> 4;
#pragma unroll
    for (int kk = 0; kk < 8; kk++) {
        const unsigned short* abase = xb + (size_t)(bm + w * 32 + lm) * 256 + kk * 32 + lk * 8;
        short8 a0 = *(const short8*)(abase);
        short8 a1 = *(const short8*)(abase + 16 * 256);
        const unsigned short* bbase = bfrag + ((t0 * 8 + kk) * 64 + l) * 8;
        short8 b[4];
#pragma unroll
        for (int j = 0; j < 4; j++) b[j] = *(const short8*)(bbase + j * 8 * 64 * 8);
#pragma unroll
        for (int j = 0; j < 4; j++) {
            acc[0][j] = __builtin_amdgcn_mfma_f32_16x16x32_bf16(a0, b[j], acc[0][j], 0, 0, 0);
            acc[1][j] = __builtin_amdgcn_mfma_f32_16x16x32_bf16(a1, b[j], acc[1][j], 0, 0, 0);
        }
    }
#pragma unroll
    for (int i = 0; i < 2; i++) {
        int row0 = bm + w * 32 + i * 16 + lk * 4;
#pragma unroll
        for (int r = 0; r < 4; r++) {
            int row = row0 + r;
            if (row >= NNODES) continue;
#pragma unroll
            for (int j = 0; j < 4; j++) {
                int col = n0 + j * 16 + lm;
                fs1b[(size_t)row * 256 + col] = f2bf(acc[i][j][r]);
            }
        }
    }
}

// ---------------------------------------------------------------------------
// GEMM2: fs2b[M,48] = h1b @ W2pad (bf16 MFMA). One block-col (48 = 3 tiles).
// ---------------------------------------------------------------------------
__global__ __launch_bounds__(256) void mfma_gemm2(const unsigned short* __restrict__ h1b,
                                                  const unsigned short* __restrict__ bfrag,
                                                  unsigned short* __restrict__ fs2b) {
    const int w = threadIdx.x >> 6;
    const int l = threadIdx.x & 63;
    const int bm = blockIdx.x * 128;
    const int lm = l & 15, lk = l >> 4;

    floatx4 acc[2][3];
#pragma unroll
    for (int i = 0; i < 2; i++)
#pragma unroll
        for (int j = 0; j < 3; j++) acc[i][j] = (floatx4){0.f, 0.f, 0.f, 0.f};

#pragma unroll
    for (int kk = 0; kk < 8; kk++) {
        const unsigned short* abase = h1b + (size_t)(bm + w * 32 + lm) * 256 + kk * 32 + lk * 8;
        short8 a0 = *(const short8*)(abase);
        short8 a1 = *(const short8*)(abase + 16 * 256);
        const unsigned short* bbase = bfrag + (size_t)(kk * 64 + l) * 8;
        short8 b[3];
#pragma unroll
        for (int j = 0; j < 3; j++) b[j] = *(const short8*)(bbase + j * (8 * 64 * 8));
#pragma unroll
        for (int j = 0; j < 3; j++) {
            acc[0][j] = __builtin_amdgcn_mfma_f32_16x16x32_bf16(a0, b[j], acc[0][j], 0, 0, 0);
            acc[1][j] = __builtin_amdgcn_mfma_f32_16x16x32_bf16(a1, b[j], acc[1][j], 0, 0, 0);
        }
    }
#pragma unroll
    for (int i = 0; i < 2; i++) {
        int row0 = bm + w * 32 + i * 16 + lk * 4;
#pragma unroll
        for (int r = 0; r < 4; r++) {
            int row = row0 + r;
            if (row >= NNODES) continue;
#pragma unroll
            for (int j = 0; j < 3; j++) {
                int col = j * 16 + lm;
                fs2b[(size_t)row * 48 + col] = f2bf(acc[i][j][r]);
            }
        }
    }
}

// ---------------------------------------------------------------------------
// Layer-1 logits. One block per node, wave = head.
// ---------------------------------------------------------------------------
__global__ __launch_bounds__(256) void logits1(const unsigned short* __restrict__ fs1b,
                                               const float* __restrict__ al,
                                               const float* __restrict__ ar,
                                               float* __restrict__ el,
                                               float* __restrict__ er) {
    int n = blockIdx.x;
    int tid = threadIdx.x;
    int h = tid >> 6, d = tid & 63;
    float v = bf2f(fs1b[(size_t)n * 256 + tid]);
    float pa = v * al[h * 64 + d];
    float pb = v * ar[h * 64 + d];
    for (int off = 32; off > 0; off >>= 1) {
        pa += __shfl_down(pa, off);
        pb += __shfl_down(pb, off);
    }
    if (d == 0) { el[n * 4 + h] = pa; er[n * 4 + h] = pb; }
}

// ---------------------------------------------------------------------------
// Layer-1 softmax + aggregate. Block = node.
// Phase 1: wave w = head w -> exact max + exp-sum.
// Phase 2: normalized weights exp(e-m)/s -> LDS (cap CAP1, fallback inline).
// Pass B: wave w takes edges start+2w+{0,1} step 8; lane sub=l>>5 picks edge,
// channel-group c=l&31 owns channels 8c..8c+7 (head = c>>3); uint4 gathers.
// ---------------------------------------------------------------------------
__global__ __launch_bounds__(256) void agg1(const int* __restrict__ row_ptr,
                                            const int* __restrict__ src,
                                            const float* __restrict__ el,
                                            const float* __restrict__ er,
                                            const unsigned short* __restrict__ fs1b,
                                            const float* __restrict__ b1,
                                            unsigned short* __restrict__ h1b) {
    __shared__ float sm_m[4], sm_rs[4];
    __shared__ float wbuf[4][CAP1];
    __shared__ float red[4][256];
    const int n = blockIdx.x;
    const int tid = threadIdx.x;
    const int w = tid >> 6, l = tid & 63;
    const int start = row_ptr[n], end = row_ptr[n + 1];
    const int deg = end - start;

    {   // Phase 1
        float erv = er[n * 4 + w];
        float m = -1e30f, s = 0.f;
        for (int i = start + l; i < end; i += 64) {
            float e = el[src[i] * 4 + w] + erv;
            e = e > 0.f ? e : NEG_SLOPE * e;
            float nm = fmaxf(m, e);
            s = s * __expf(m - nm) + __expf(e - nm);
            m = nm;
        }
        for (int off = 32; off > 0; off >>= 1) {
            float mo = __shfl_xor(m, off), so = __shfl_xor(s, off);
            float nm = fmaxf(m, mo);
            s = s * __expf(m - nm) + so * __expf(mo - nm);
            m = nm;
        }
        if (l == 0) { sm_m[w] = m; sm_rs[w] = (deg > 0) ? 1.f / s : 0.f; }
    }
    __syncthreads();

    {   // Phase 2
        const int h = tid & 3, j = tid >> 2;
        const float mh = sm_m[h], rsh = sm_rs[h];
        const float erv = er[n * 4 + h];
        const int lim = deg < CAP1 ? deg : CAP1;
        for (int k = j; k < lim; k += 64) {
            float e = el[src[start + k] * 4 + h] + erv;
            e = e > 0.f ? e : NEG_SLOPE * e;
            wbuf[h][k] = __expf(e - mh) * rsh;
        }
    }
    __syncthreads();

    const int sub = l >> 5, c = l & 31, hl = c >> 3;
    float a[8] = {};
    {
        const float mh = sm_m[hl], rsh = sm_rs[hl];
        const float erv = er[n * 4 + hl];
        for (int i0 = start + w * 2; i0 < end; i0 += 8) {
            int i = i0 + sub;
            bool ok = i < end;
            int ii = ok ? i : start;
            int sv = src[ii];
            int k = ii - start;
            float wv;
            if (k < CAP1) wv = wbuf[hl][k];
            else {
                float e = el[sv * 4 + hl] + erv;
                e = e > 0.f ? e : NEG_SLOPE * e;
                wv = __expf(e - mh) * rsh;
            }
            if (!ok) wv = 0.f;
            uint4 q = *(const uint4*)(fs1b + (size_t)sv * 256 + c * 8);
            a[0] += wv * bf2f(q.x & 0xFFFFu); a[1] += wv * bf2f(q.x >> 16);
            a[2] += wv * bf2f(q.y & 0xFFFFu); a[3] += wv * bf2f(q.y >> 16);
            a[4] += wv * bf2f(q.z & 0xFFFFu); a[5] += wv * bf2f(q.z >> 16);
            a[6] += wv * bf2f(q.w & 0xFFFFu); a[7] += wv * bf2f(q.w >> 16);
        }
    }
#pragma unroll
    for (int j = 0; j < 8; j++) a[j] += __shfl_xor(a[j], 32);
    if (sub == 0) {
#pragma unroll
        for (int j = 0; j < 8; j++) red[w][c * 8 + j] = a[j];
    }
    __syncthreads();
    float tot = red[0][tid] + red[1][tid] + red[2][tid] + red[3][tid];
    float val = fmaxf(tot + b1[tid], 0.f);
    h1b[(size_t)n * 256 + tid] = f2bf(val);
}

// ---------------------------------------------------------------------------
// Layer-2 logits from padded bf16 fs2b. Wave per node (4 nodes/block);
// lane c<24 owns channel pair (2c, 2c+1); fs2b[...,47] == 0.
// ---------------------------------------------------------------------------
__global__ __launch_bounds__(256) void logits2(const unsigned short* __restrict__ fs2b,
                                               const float* __restrict__ al,
                                               const float* __restrict__ ar,
                                               float* __restrict__ el,
                                               float* __restrict__ er) {
    int l = threadIdx.x & 63;
    int n = blockIdx.x * 4 + (threadIdx.x >> 6);
    if (n >= NNODES) return;
    float pa = 0.f, pb = 0.f;
    if (l < 24) {
        unsigned int q = *(const unsigned int*)(fs2b + (size_t)n * 48 + l * 2);
        float v0 = bf2f(q & 0xFFFFu), v1 = bf2f(q >> 16);
        float a1 = (l * 2 + 1 < 47) ? al[l * 2 + 1] : 0.f;
        float r1 = (l * 2 + 1 < 47) ? ar[l * 2 + 1] : 0.f;
        pa = v0 * al[l * 2] + v1 * a1;
        pb = v0 * ar[l * 2] + v1 * r1;
    }
    for (int off = 32; off > 0; off >>= 1) {
        pa += __shfl_down(pa, off);
        pb += __shfl_down(pb, off);
    }
    if (l == 0) { el[n] = pa; er[n] = pb; }
}

// ---------------------------------------------------------------------------
// Layer-2 softmax + aggregate. Block = node; same structure as agg1 but
// single head, 48-ch padded bf16 rows, lane c<24 owns a channel pair.
// ---------------------------------------------------------------------------
__global__ __launch_bounds__(256) void agg2(const int* __restrict__ row_ptr,
                                            const int* __restrict__ src,
                                            const float* __restrict__ el,
                                            const float* __restrict__ er,
                                            const unsigned short* __restrict__ fs2b,
                                            const float* __restrict__ b2,
                                            float* __restrict__ out) {
    __shared__ float s_m, s_rs;
    __shared__ float wbuf[CAP2];
    __shared__ float red[4][48];
    const int n = blockIdx.x;
    const int tid = threadIdx.x;
    const int w = tid >> 6, l = tid & 63;
    const int start = row_ptr[n], end = row_ptr[n + 1];
    const int deg = end - start;
    const float erv = er[n];

    if (w == 0) {
        float m = -1e30f, s = 0.f;
        for (int i = start + l; i < end; i += 64) {
            float e = el[src[i]] + erv;
            e = e > 0.f ? e : NEG_SLOPE * e;
            float nm = fmaxf(m, e);
            s = s * __expf(m - nm) + __expf(e - nm);
            m = nm;
        }
        for (int off = 32; off > 0; off >>= 1) {
            float mo = __shfl_xor(m, off), so = __shfl_xor(s, off);
            float nm = fmaxf(m, mo);
            s = s * __expf(m - nm) + so * __expf(mo - nm);
            m = nm;
        }
        if (l == 0) { s_m = m; s_rs = (deg > 0) ? 1.f / s : 0.f; }
    }
    __syncthreads();

    {
        const float mh = s_m, rsh = s_rs;
        const int lim = deg < CAP2 ? deg : CAP2;
        for (int k = tid; k < lim; k += 256) {
            float e = el[src[start + k]] + erv;
            e = e > 0.f ? e : NEG_SLOPE * e;
            wbuf[k] = __expf(e - mh) * rsh;
        }
    }
    __syncthreads();

    const int sub = l >> 5, c = l & 31;
    const float mh = s_m, rsh = s_rs;
    float a0 = 0.f, a1 = 0.f;
    for (int i0 = start + w * 2; i0 < end; i0 += 8) {
        int i = i0 + sub;
        bool ok = i < end;
        int ii = ok ? i : start;
        int sv = src[ii];
        int k = ii - start;
        float wv;
        if (k < CAP2) wv = wbuf[k];
        else {
            float e = el[sv] + erv;
            e = e > 0.f ? e : NEG_SLOPE * e;
            wv = __expf(e - mh) * rsh;
        }
        if (!ok) wv = 0.f;
        if (c < 24) {
            unsigned int q = *(const unsigned int*)(fs2b + (size_t)sv * 48 + c * 2);
            a0 += wv * bf2f(q & 0xFFFFu);
            a1 += wv * bf2f(q >> 16);
        }
    }
    a0 += __shfl_xor(a0, 32);
    a1 += __shfl_xor(a1, 32);
    if (sub == 0 && c < 24) { red[w][c * 2] = a0; red[w][c * 2 + 1] = a1; }
    __syncthreads();
    if (tid < 47) {
        float tot = red[0][tid] + red[1][tid] + red[2][tid] + red[3][tid];
        out[(size_t)n * 47 + tid] = tot + b2[tid];
    }
}

// ---------------------------------------------------------------------------
// Launch. Inputs: 0:x 1:W1 2:al1 3:ar1 4:b1 5:W2 6:al2 7:ar2 8:b2 9:src 10:dst
// ---------------------------------------------------------------------------
extern "C" void kernel_launch(void* const* d_in, const int* in_sizes, int n_in,
                              void* d_out, int out_size, void* d_ws, size_t ws_size,
                              hipStream_t stream) {
    const float* x   = (const float*)d_in[0];
    const float* W1  = (const float*)d_in[1];
    const float* al1 = (const float*)d_in[2];
    const float* ar1 = (const float*)d_in[3];
    const float* b1  = (const float*)d_in[4];
    const float* W2  = (const float*)d_in[5];
    const float* al2 = (const float*)d_in[6];
    const float* ar2 = (const float*)d_in[7];
    const float* b2  = (const float*)d_in[8];
    const int*   src = (const int*)d_in[9];
    const int*   dst = (const int*)d_in[10];
    float* out = (float*)d_out;

    char* ws = (char*)d_ws;
    size_t off = 0;
    auto alloc = [&](size_t bytes) {
        void* p = ws + off;
        off += (bytes + 255) & ~(size_t)255;
        return p;
    };
    int*            row_ptr = (int*)alloc((NNODES + 1) * sizeof(int));
    unsigned short* xb      = (unsigned short*)alloc((size_t)MPAD * 256 * 2);
    unsigned short* bfrag1  = (unsigned short*)alloc(16 * 8 * 64 * 8 * 2);
    unsigned short* bfrag2  = (unsigned short*)alloc(3 * 8 * 64 * 8 * 2);
    unsigned short* fs1b    = (unsigned short*)alloc((size_t)NNODES * 256 * 2);
    unsigned short* h1b     = (unsigned short*)alloc((size_t)MPAD * 256 * 2);
    unsigned short* fs2b    = (unsigned short*)alloc((size_t)NNODES * 48 * 2);
    float*          el1     = (float*)alloc((size_t)NNODES * 4 * sizeof(float));
    float*          er1     = (float*)alloc((size_t)NNODES * 4 * sizeof(float));
    float*          el2     = (float*)alloc((size_t)NNODES * sizeof(float));
    float*          er2     = (float*)alloc((size_t)NNODES * sizeof(float));
    (void)ws_size; (void)n_in; (void)in_sizes; (void)out_size;

    build_row_ptr<<<(NNODES + 256) / 256, 256, 0, stream>>>(dst, row_ptr);
    convert_x<<<(MPAD * 256 / 4 + 255) / 256, 256, 0, stream>>>(x, xb);
    build_bfrag<<<(16 * 8 * 64 + 255) / 256, 256, 0, stream>>>(W1, bfrag1);
    build_bfrag2<<<(3 * 8 * 64 + 255) / 256, 256, 0, stream>>>(W2, bfrag2);
    zero_pad_h1<<<MPAD - NNODES, 256, 0, stream>>>(h1b);

    // Layer 1
    mfma_gemm1<<<dim3(MPAD / 128, 4), 256, 0, stream>>>(xb, bfrag1, fs1b);
    logits1<<<NNODES, 256, 0, stream>>>(fs1b, al1, ar1, el1, er1);
    agg1<<<NNODES, 256, 0, stream>>>(row_ptr, src, el1, er1, fs1b, b1, h1b);

    // Layer 2
    mfma_gemm2<<<MPAD / 128, 256, 0, stream>>>(h1b, bfrag2, fs2b);
    logits2<<<(NNODES + 3) / 4, 256, 0, stream>>>(fs2b, al2, ar2, el2, er2);
    agg2<<<NNODES, 256, 0, stream>>>(row_ptr, src, el2, er2, fs2b, b2, out);
}

// Round 7
// 395.533 us; speedup vs baseline: 1.5300x; 1.0321x over previous
//
#include <hip/hip_runtime.h>
#include <math.h>

#define NNODES 50000
#define NEDGES 800000
#define NEG_SLOPE 0.2f
#define MPAD 50048   // 391 * 128
#define CAP1 192     // LDS weight-cache per head (layer 1); fallback recompute past it
#define CAP2 192

typedef __attribute__((ext_vector_type(8))) short short8;
typedef __attribute__((ext_vector_type(4))) float floatx4;

// bf16 helpers (RNE)
__device__ __forceinline__ unsigned short f2bf(float f) {
    union { float f; unsigned int u; } v; v.f = f;
    unsigned int r = v.u + 0x7FFFu + ((v.u >> 16) & 1u);
    return (unsigned short)(r >> 16);
}
__device__ __forceinline__ float bf2f(unsigned int s) {
    union { unsigned int u; float f; } v; v.u = s << 16; return v.f;
}

// ---------------------------------------------------------------------------
// prep: merged prologue (the ONLY change vs the round-3 passing kernel).
// Block ranges:
//   [0,12512)            convert x -> bf16 xb (pad rows zero)
//   [12512,12708)        row_ptr via binary search on sorted dst
//   [12708,12740)        W1 -> bfrag1 (wave-contiguous MFMA B-fragment chunks)
//   [12740,12746)        W2 -> bfrag2 (N padded to 48)
//   [12746,12794)        zero h1b pad rows
// ---------------------------------------------------------------------------
__global__ __launch_bounds__(256) void prep(const float* __restrict__ x,
                                            const float* __restrict__ W1,
                                            const float* __restrict__ W2,
                                            const int* __restrict__ dst,
                                            unsigned short* __restrict__ xb,
                                            unsigned short* __restrict__ bfrag1,
                                            unsigned short* __restrict__ bfrag2,
                                            unsigned short* __restrict__ h1b,
                                            int* __restrict__ row_ptr) {
    int b = blockIdx.x;
    if (b < 12512) {
        long e = ((long)b * 256 + threadIdx.x) * 4;
        const long NE = (long)NNODES * 256;
        ushort4 o;
        o.x = (e + 0 < NE) ? f2bf(x[e + 0]) : 0;
        o.y = (e + 1 < NE) ? f2bf(x[e + 1]) : 0;
        o.z = (e + 2 < NE) ? f2bf(x[e + 2]) : 0;
        o.w = (e + 3 < NE) ? f2bf(x[e + 3]) : 0;
        *(ushort4*)(xb + e) = o;
    } else if (b < 12708) {
        int n = (b - 12512) * 256 + threadIdx.x;
        if (n > NNODES) return;
        int lo = 0, hi = NEDGES;
        while (lo < hi) {
            int mid = (lo + hi) >> 1;
            if (dst[mid] < n) lo = mid + 1; else hi = mid;
        }
        row_ptr[n] = lo;
    } else if (b < 12740) {
        int c = (b - 12708) * 256 + threadIdx.x;   // 8192 chunks exactly
        int l = c & 63, kk = (c >> 6) & 7, t = c >> 9;
        int n = t * 16 + (l & 15);
        int kbase = kk * 32 + (l >> 4) * 8;
#pragma unroll
        for (int j = 0; j < 8; j++)
            bfrag1[c * 8 + j] = f2bf(W1[(kbase + j) * 256 + n]);
    } else if (b < 12746) {
        int c = (b - 12740) * 256 + threadIdx.x;   // 1536 chunks exactly
        int l = c & 63, kk = (c >> 6) & 7, t = c >> 9;
        int n = t * 16 + (l & 15);
        int kbase = kk * 32 + (l >> 4) * 8;
#pragma unroll
        for (int j = 0; j < 8; j++)
            bfrag2[c * 8 + j] = (n < 47) ? f2bf(W2[(kbase + j) * 47 + n]) : 0;
    } else {
        int row = NNODES + (b - 12746);
        h1b[(size_t)row * 256 + threadIdx.x] = 0;
    }
}

// ---------------------------------------------------------------------------
// GEMM1 (round-3 verbatim): fs1b[M,256] = xb @ W1 (bf16 MFMA).
// ---------------------------------------------------------------------------
__global__ __launch_bounds__(256) void mfma_gemm1(const unsigned short* __restrict__ xb,
                                                  const unsigned short* __restrict__ bfrag,
                                                  unsigned short* __restrict__ fs1b) {
    const int w = threadIdx.x >> 6;
    const int l = threadIdx.x & 63;
    const int bm = blockIdx.x * 128;
    const int n0 = blockIdx.y * 64;
    const int lm = l & 15, lk = l >> 4;

    floatx4 acc[2][4];
#pragma unroll
    for (int i = 0; i < 2; i++)
#pragma unroll
        for (int j = 0; j < 4; j++) acc[i][j] = (floatx4){0.f, 0.f, 0.f, 0.f};

    const int t0 = n0 >> 4;
#pragma unroll
    for (int kk = 0; kk < 8; kk++) {
        const unsigned short* abase = xb + (size_t)(bm + w * 32 + lm) * 256 + kk * 32 + lk * 8;
        short8 a0 = *(const short8*)(abase);
        short8 a1 = *(const short8*)(abase + 16 * 256);
        const unsigned short* bbase = bfrag + ((t0 * 8 + kk) * 64 + l) * 8;
        short8 b[4];
#pragma unroll
        for (int j = 0; j < 4; j++) b[j] = *(const short8*)(bbase + j * 8 * 64 * 8);
#pragma unroll
        for (int j = 0; j < 4; j++) {
            acc[0][j] = __builtin_amdgcn_mfma_f32_16x16x32_bf16(a0, b[j], acc[0][j], 0, 0, 0);
            acc[1][j] = __builtin_amdgcn_mfma_f32_16x16x32_bf16(a1, b[j], acc[1][j], 0, 0, 0);
        }
    }
#pragma unroll
    for (int i = 0; i < 2; i++) {
        int row0 = bm + w * 32 + i * 16 + lk * 4;
#pragma unroll
        for (int r = 0; r < 4; r++) {
            int row = row0 + r;
            if (row >= NNODES) continue;
#pragma unroll
            for (int j = 0; j < 4; j++) {
                int col = n0 + j * 16 + lm;
                fs1b[(size_t)row * 256 + col] = f2bf(acc[i][j][r]);
            }
        }
    }
}

// ---------------------------------------------------------------------------
// GEMM2 (round-3 verbatim): fs2b[M,48] = h1b @ W2pad.
// ---------------------------------------------------------------------------
__global__ __launch_bounds__(256) void mfma_gemm2(const unsigned short* __restrict__ h1b,
                                                  const unsigned short* __restrict__ bfrag,
                                                  unsigned short* __restrict__ fs2b) {
    const int w = threadIdx.x >> 6;
    const int l = threadIdx.x & 63;
    const int bm = blockIdx.x * 128;
    const int lm = l & 15, lk = l >> 4;

    floatx4 acc[2][3];
#pragma unroll
    for (int i = 0; i < 2; i++)
#pragma unroll
        for (int j = 0; j < 3; j++) acc[i][j] = (floatx4){0.f, 0.f, 0.f, 0.f};

#pragma unroll
    for (int kk = 0; kk < 8; kk++) {
        const unsigned short* abase = h1b + (size_t)(bm + w * 32 + lm) * 256 + kk * 32 + lk * 8;
        short8 a0 = *(const short8*)(abase);
        short8 a1 = *(const short8*)(abase + 16 * 256);
        const unsigned short* bbase = bfrag + (size_t)(kk * 64 + l) * 8;
        short8 b[3];
#pragma unroll
        for (int j = 0; j < 3; j++) b[j] = *(const short8*)(bbase + j * (8 * 64 * 8));
#pragma unroll
        for (int j = 0; j < 3; j++) {
            acc[0][j] = __builtin_amdgcn_mfma_f32_16x16x32_bf16(a0, b[j], acc[0][j], 0, 0, 0);
            acc[1][j] = __builtin_amdgcn_mfma_f32_16x16x32_bf16(a1, b[j], acc[1][j], 0, 0, 0);
        }
    }
#pragma unroll
    for (int i = 0; i < 2; i++) {
        int row0 = bm + w * 32 + i * 16 + lk * 4;
#pragma unroll
        for (int r = 0; r < 4; r++) {
            int row = row0 + r;
            if (row >= NNODES) continue;
#pragma unroll
            for (int j = 0; j < 3; j++) {
                int col = j * 16 + lm;
                fs2b[(size_t)row * 48 + col] = f2bf(acc[i][j][r]);
            }
        }
    }
}

// ---------------------------------------------------------------------------
// Layer-1 logits (round-3 verbatim). One block per node, wave = head.
// ---------------------------------------------------------------------------
__global__ __launch_bounds__(256) void logits1(const unsigned short* __restrict__ fs1b,
                                               const float* __restrict__ al,
                                               const float* __restrict__ ar,
                                               float* __restrict__ el,
                                               float* __restrict__ er) {
    int n = blockIdx.x;
    int tid = threadIdx.x;
    int h = tid >> 6, d = tid & 63;
    float v = bf2f(fs1b[(size_t)n * 256 + tid]);
    float pa = v * al[h * 64 + d];
    float pb = v * ar[h * 64 + d];
    for (int off = 32; off > 0; off >>= 1) {
        pa += __shfl_down(pa, off);
        pb += __shfl_down(pb, off);
    }
    if (d == 0) { el[n * 4 + h] = pa; er[n * 4 + h] = pb; }
}

// ---------------------------------------------------------------------------
// Layer-1 softmax + aggregate (round-3 verbatim). Block = node.
// ---------------------------------------------------------------------------
__global__ __launch_bounds__(256) void agg1(const int* __restrict__ row_ptr,
                                            const int* __restrict__ src,
                                            const float* __restrict__ el,
                                            const float* __restrict__ er,
                                            const unsigned short* __restrict__ fs1b,
                                            const float* __restrict__ b1,
                                            unsigned short* __restrict__ h1b) {
    __shared__ float sm_m[4], sm_rs[4];
    __shared__ float wbuf[4][CAP1];
    __shared__ float red[4][256];
    const int n = blockIdx.x;
    const int tid = threadIdx.x;
    const int w = tid >> 6, l = tid & 63;
    const int start = row_ptr[n], end = row_ptr[n + 1];
    const int deg = end - start;

    {   // Phase 1
        float erv = er[n * 4 + w];
        float m = -1e30f, s = 0.f;
        for (int i = start + l; i < end; i += 64) {
            float e = el[src[i] * 4 + w] + erv;
            e = e > 0.f ? e : NEG_SLOPE * e;
            float nm = fmaxf(m, e);
            s = s * __expf(m - nm) + __expf(e - nm);
            m = nm;
        }
        for (int off = 32; off > 0; off >>= 1) {
            float mo = __shfl_xor(m, off), so = __shfl_xor(s, off);
            float nm = fmaxf(m, mo);
            s = s * __expf(m - nm) + so * __expf(mo - nm);
            m = nm;
        }
        if (l == 0) { sm_m[w] = m; sm_rs[w] = (deg > 0) ? 1.f / s : 0.f; }
    }
    __syncthreads();

    {   // Phase 2
        const int h = tid & 3, j = tid >> 2;
        const float mh = sm_m[h], rsh = sm_rs[h];
        const float erv = er[n * 4 + h];
        const int lim = deg < CAP1 ? deg : CAP1;
        for (int k = j; k < lim; k += 64) {
            float e = el[src[start + k] * 4 + h] + erv;
            e = e > 0.f ? e : NEG_SLOPE * e;
            wbuf[h][k] = __expf(e - mh) * rsh;
        }
    }
    __syncthreads();

    const int sub = l >> 5, c = l & 31, hl = c >> 3;
    float a[8] = {};
    {
        const float mh = sm_m[hl], rsh = sm_rs[hl];
        const float erv = er[n * 4 + hl];
        for (int i0 = start + w * 2; i0 < end; i0 += 8) {
            int i = i0 + sub;
            bool ok = i < end;
            int ii = ok ? i : start;
            int sv = src[ii];
            int k = ii - start;
            float wv;
            if (k < CAP1) wv = wbuf[hl][k];
            else {
                float e = el[sv * 4 + hl] + erv;
                e = e > 0.f ? e : NEG_SLOPE * e;
                wv = __expf(e - mh) * rsh;
            }
            if (!ok) wv = 0.f;
            uint4 g = *(const uint4*)(fs1b + (size_t)sv * 256 + c * 8);
            a[0] += wv * bf2f(g.x & 0xFFFFu); a[1] += wv * bf2f(g.x >> 16);
            a[2] += wv * bf2f(g.y & 0xFFFFu); a[3] += wv * bf2f(g.y >> 16);
            a[4] += wv * bf2f(g.z & 0xFFFFu); a[5] += wv * bf2f(g.z >> 16);
            a[6] += wv * bf2f(g.w & 0xFFFFu); a[7] += wv * bf2f(g.w >> 16);
        }
    }
#pragma unroll
    for (int j = 0; j < 8; j++) a[j] += __shfl_xor(a[j], 32);
    if (sub == 0) {
#pragma unroll
        for (int j = 0; j < 8; j++) red[w][c * 8 + j] = a[j];
    }
    __syncthreads();
    int cc = tid;
    float tot = red[0][cc] + red[1][cc] + red[2][cc] + red[3][cc];
    float val = fmaxf(tot + b1[cc], 0.f);
    h1b[(size_t)n * 256 + cc] = f2bf(val);
}

// ---------------------------------------------------------------------------
// Layer-2 logits (round-3 verbatim). Wave per node (4 nodes/block).
// ---------------------------------------------------------------------------
__global__ __launch_bounds__(256) void logits2(const unsigned short* __restrict__ fs2b,
                                               const float* __restrict__ al,
                                               const float* __restrict__ ar,
                                               float* __restrict__ el,
                                               float* __restrict__ er) {
    int l = threadIdx.x & 63;
    int n = blockIdx.x * 4 + (threadIdx.x >> 6);
    if (n >= NNODES) return;
    float pa = 0.f, pb = 0.f;
    if (l < 24) {
        unsigned int q = *(const unsigned int*)(fs2b + (size_t)n * 48 + l * 2);
        float v0 = bf2f(q & 0xFFFFu), v1 = bf2f(q >> 16);
        float a1 = (l * 2 + 1 < 47) ? al[l * 2 + 1] : 0.f;
        float r1 = (l * 2 + 1 < 47) ? ar[l * 2 + 1] : 0.f;
        pa = v0 * al[l * 2] + v1 * a1;
        pb = v0 * ar[l * 2] + v1 * r1;
    }
    for (int off = 32; off > 0; off >>= 1) {
        pa += __shfl_down(pa, off);
        pb += __shfl_down(pb, off);
    }
    if (l == 0) { el[n] = pa; er[n] = pb; }
}

// ---------------------------------------------------------------------------
// Layer-2 softmax + aggregate (round-3 verbatim). Block = node.
// ---------------------------------------------------------------------------
__global__ __launch_bounds__(256) void agg2(const int* __restrict__ row_ptr,
                                            const int* __restrict__ src,
                                            const float* __restrict__ el,
                                            const float* __restrict__ er,
                                            const unsigned short* __restrict__ fs2b,
                                            const float* __restrict__ b2,
                                            float* __restrict__ out) {
    __shared__ float s_m, s_rs;
    __shared__ float wbuf[CAP2];
    __shared__ float red[4][48];
    const int n = blockIdx.x;
    const int tid = threadIdx.x;
    const int w = tid >> 6, l = tid & 63;
    const int start = row_ptr[n], end = row_ptr[n + 1];
    const int deg = end - start;
    const float erv = er[n];

    if (w == 0) {
        float m = -1e30f, s = 0.f;
        for (int i = start + l; i < end; i += 64) {
            float e = el[src[i]] + erv;
            e = e > 0.f ? e : NEG_SLOPE * e;
            float nm = fmaxf(m, e);
            s = s * __expf(m - nm) + __expf(e - nm);
            m = nm;
        }
        for (int off = 32; off > 0; off >>= 1) {
            float mo = __shfl_xor(m, off), so = __shfl_xor(s, off);
            float nm = fmaxf(m, mo);
            s = s * __expf(m - nm) + so * __expf(mo - nm);
            m = nm;
        }
        if (l == 0) { s_m = m; s_rs = (deg > 0) ? 1.f / s : 0.f; }
    }
    __syncthreads();

    {
        const float mh = s_m, rsh = s_rs;
        const int lim = deg < CAP2 ? deg : CAP2;
        for (int k = tid; k < lim; k += 256) {
            float e = el[src[start + k]] + erv;
            e = e > 0.f ? e : NEG_SLOPE * e;
            wbuf[k] = __expf(e - mh) * rsh;
        }
    }
    __syncthreads();

    const int sub = l >> 5, c = l & 31;
    const float mh = s_m, rsh = s_rs;
    float a0 = 0.f, a1 = 0.f;
    for (int i0 = start + w * 2; i0 < end; i0 += 8) {
        int i = i0 + sub;
        bool ok = i < end;
        int ii = ok ? i : start;
        int sv = src[ii];
        int k = ii - start;
        float wv;
        if (k < CAP2) wv = wbuf[k];
        else {
            float e = el[sv] + erv;
            e = e > 0.f ? e : NEG_SLOPE * e;
            wv = __expf(e - mh) * rsh;
        }
        if (!ok) wv = 0.f;
        if (c < 24) {
            unsigned int g = *(const unsigned int*)(fs2b + (size_t)sv * 48 + c * 2);
            a0 += wv * bf2f(g & 0xFFFFu);
            a1 += wv * bf2f(g >> 16);
        }
    }
    a0 += __shfl_xor(a0, 32);
    a1 += __shfl_xor(a1, 32);
    if (sub == 0 && c < 24) { red[w][c * 2] = a0; red[w][c * 2 + 1] = a1; }
    __syncthreads();
    if (tid < 47) {
        float tot = red[0][tid] + red[1][tid] + red[2][tid] + red[3][tid];
        float val = (end > start) ? tot : 0.f;
        out[(size_t)n * 47 + tid] = val + b2[tid];
    }
}

// ---------------------------------------------------------------------------
// Launch. Inputs: 0:x 1:W1 2:al1 3:ar1 4:b1 5:W2 6:al2 7:ar2 8:b2 9:src 10:dst
// ---------------------------------------------------------------------------
extern "C" void kernel_launch(void* const* d_in, const int* in_sizes, int n_in,
                              void* d_out, int out_size, void* d_ws, size_t ws_size,
                              hipStream_t stream) {
    const float* x   = (const float*)d_in[0];
    const float* W1  = (const float*)d_in[1];
    const float* al1 = (const float*)d_in[2];
    const float* ar1 = (const float*)d_in[3];
    const float* b1  = (const float*)d_in[4];
    const float* W2  = (const float*)d_in[5];
    const float* al2 = (const float*)d_in[6];
    const float* ar2 = (const float*)d_in[7];
    const float* b2  = (const float*)d_in[8];
    const int*   src = (const int*)d_in[9];
    const int*   dst = (const int*)d_in[10];
    float* out = (float*)d_out;

    char* ws = (char*)d_ws;
    size_t off = 0;
    auto alloc = [&](size_t bytes) {
        void* p = ws + off;
        off += (bytes + 255) & ~(size_t)255;
        return p;
    };
    int*            row_ptr = (int*)alloc((NNODES + 1) * sizeof(int));
    unsigned short* xb      = (unsigned short*)alloc((size_t)MPAD * 256 * 2);
    unsigned short* bfrag1  = (unsigned short*)alloc(16 * 8 * 64 * 8 * 2);
    unsigned short* bfrag2  = (unsigned short*)alloc(3 * 8 * 64 * 8 * 2);
    unsigned short* fs1b    = (unsigned short*)alloc((size_t)NNODES * 256 * 2);
    unsigned short* h1b     = (unsigned short*)alloc((size_t)MPAD * 256 * 2);
    unsigned short* fs2b    = (unsigned short*)alloc((size_t)NNODES * 48 * 2);
    float*          el1     = (float*)alloc((size_t)NNODES * 4 * sizeof(float));
    float*          er1     = (float*)alloc((size_t)NNODES * 4 * sizeof(float));
    float*          el2     = (float*)alloc((size_t)NNODES * sizeof(float));
    float*          er2     = (float*)alloc((size_t)NNODES * sizeof(float));
    (void)ws_size; (void)n_in; (void)in_sizes; (void)out_size;

    prep<<<12794, 256, 0, stream>>>(x, W1, W2, dst, xb, bfrag1, bfrag2, h1b, row_ptr);

    // Layer 1 (round-3 structure)
    mfma_gemm1<<<dim3(MPAD / 128, 4), 256, 0, stream>>>(xb, bfrag1, fs1b);
    logits1<<<NNODES, 256, 0, stream>>>(fs1b, al1, ar1, el1, er1);
    agg1<<<NNODES, 256, 0, stream>>>(row_ptr, src, el1, er1, fs1b, b1, h1b);

    // Layer 2 (round-3 structure)
    mfma_gemm2<<<MPAD / 128, 256, 0, stream>>>(h1b, bfrag2, fs2b);
    logits2<<<(NNODES + 3) / 4, 256, 0, stream>>>(fs2b, al2, ar2, el2, er2);
    agg2<<<NNODES, 256, 0, stream>>>(row_ptr, src, el2, er2, fs2b, b2, out);
}

// Round 8
// 346.105 us; speedup vs baseline: 1.7485x; 1.1428x over previous
//
#include <hip/hip_runtime.h>
#include <math.h>

#define NNODES 50000
#define NEDGES 800000
#define NEG_SLOPE 0.2f
#define MPAD 50048   // 391 * 128
#define CAP1 192     // LDS weight-cache per head (block-agg kernels)
#define CAP2 192
#define CAPW 128     // per-wave LDS edge cache (wave-agg1); deg>CAPW -> slow path

typedef __attribute__((ext_vector_type(8))) short short8;
typedef __attribute__((ext_vector_type(4))) float floatx4;

// bf16 helpers (RNE)
__device__ __forceinline__ unsigned short f2bf(float f) {
    union { float f; unsigned int u; } v; v.f = f;
    unsigned int r = v.u + 0x7FFFu + ((v.u >> 16) & 1u);
    return (unsigned short)(r >> 16);
}
__device__ __forceinline__ float bf2f(unsigned int s) {
    union { unsigned int u; float f; } v; v.u = s << 16; return v.f;
}
__device__ __forceinline__ float lrelu(float e) { return e > 0.f ? e : NEG_SLOPE * e; }

// ---------------------------------------------------------------------------
// prep: merged prologue (verified passing in R7).
// ---------------------------------------------------------------------------
__global__ __launch_bounds__(256) void prep(const float* __restrict__ x,
                                            const float* __restrict__ W1,
                                            const float* __restrict__ W2,
                                            const int* __restrict__ dst,
                                            unsigned short* __restrict__ xb,
                                            unsigned short* __restrict__ bfrag1,
                                            unsigned short* __restrict__ bfrag2,
                                            unsigned short* __restrict__ h1b,
                                            int* __restrict__ row_ptr) {
    int b = blockIdx.x;
    if (b < 12512) {
        long e = ((long)b * 256 + threadIdx.x) * 4;
        const long NE = (long)NNODES * 256;
        ushort4 o;
        o.x = (e + 0 < NE) ? f2bf(x[e + 0]) : 0;
        o.y = (e + 1 < NE) ? f2bf(x[e + 1]) : 0;
        o.z = (e + 2 < NE) ? f2bf(x[e + 2]) : 0;
        o.w = (e + 3 < NE) ? f2bf(x[e + 3]) : 0;
        *(ushort4*)(xb + e) = o;
    } else if (b < 12708) {
        int n = (b - 12512) * 256 + threadIdx.x;
        if (n > NNODES) return;
        int lo = 0, hi = NEDGES;
        while (lo < hi) {
            int mid = (lo + hi) >> 1;
            if (dst[mid] < n) lo = mid + 1; else hi = mid;
        }
        row_ptr[n] = lo;
    } else if (b < 12740) {
        int c = (b - 12708) * 256 + threadIdx.x;   // 8192 chunks
        int l = c & 63, kk = (c >> 6) & 7, t = c >> 9;
        int n = t * 16 + (l & 15);
        int kbase = kk * 32 + (l >> 4) * 8;
#pragma unroll
        for (int j = 0; j < 8; j++)
            bfrag1[c * 8 + j] = f2bf(W1[(kbase + j) * 256 + n]);
    } else if (b < 12746) {
        int c = (b - 12740) * 256 + threadIdx.x;   // 1536 chunks
        int l = c & 63, kk = (c >> 6) & 7, t = c >> 9;
        int n = t * 16 + (l & 15);
        int kbase = kk * 32 + (l >> 4) * 8;
#pragma unroll
        for (int j = 0; j < 8; j++)
            bfrag2[c * 8 + j] = (n < 47) ? f2bf(W2[(kbase + j) * 47 + n]) : 0;
    } else {
        int row = NNODES + (b - 12746);
        h1b[(size_t)row * 256 + threadIdx.x] = 0;
    }
}

// ---------------------------------------------------------------------------
// GEMM1 (R7 verbatim): fs1b[M,256] = xb @ W1 (bf16 MFMA).
// ---------------------------------------------------------------------------
__global__ __launch_bounds__(256) void mfma_gemm1(const unsigned short* __restrict__ xb,
                                                  const unsigned short* __restrict__ bfrag,
                                                  unsigned short* __restrict__ fs1b) {
    const int w = threadIdx.x >> 6;
    const int l = threadIdx.x & 63;
    const int bm = blockIdx.x * 128;
    const int n0 = blockIdx.y * 64;
    const int lm = l & 15, lk = l >> 4;

    floatx4 acc[2][4];
#pragma unroll
    for (int i = 0; i < 2; i++)
#pragma unroll
        for (int j = 0; j < 4; j++) acc[i][j] = (floatx4){0.f, 0.f, 0.f, 0.f};

    const int t0 = n0 >> 4;
#pragma unroll
    for (int kk = 0; kk < 8; kk++) {
        const unsigned short* abase = xb + (size_t)(bm + w * 32 + lm) * 256 + kk * 32 + lk * 8;
        short8 a0 = *(const short8*)(abase);
        short8 a1 = *(const short8*)(abase + 16 * 256);
        const unsigned short* bbase = bfrag + ((t0 * 8 + kk) * 64 + l) * 8;
        short8 b[4];
#pragma unroll
        for (int j = 0; j < 4; j++) b[j] = *(const short8*)(bbase + j * 8 * 64 * 8);
#pragma unroll
        for (int j = 0; j < 4; j++) {
            acc[0][j] = __builtin_amdgcn_mfma_f32_16x16x32_bf16(a0, b[j], acc[0][j], 0, 0, 0);
            acc[1][j] = __builtin_amdgcn_mfma_f32_16x16x32_bf16(a1, b[j], acc[1][j], 0, 0, 0);
        }
    }
#pragma unroll
    for (int i = 0; i < 2; i++) {
        int row0 = bm + w * 32 + i * 16 + lk * 4;
#pragma unroll
        for (int r = 0; r < 4; r++) {
            int row = row0 + r;
            if (row >= NNODES) continue;
#pragma unroll
            for (int j = 0; j < 4; j++) {
                int col = n0 + j * 16 + lm;
                fs1b[(size_t)row * 256 + col] = f2bf(acc[i][j][r]);
            }
        }
    }
}

// ---------------------------------------------------------------------------
// GEMM2 (R7 verbatim): fs2b[M,48] = h1b @ W2pad.
// ---------------------------------------------------------------------------
__global__ __launch_bounds__(256) void mfma_gemm2(const unsigned short* __restrict__ h1b,
                                                  const unsigned short* __restrict__ bfrag,
                                                  unsigned short* __restrict__ fs2b) {
    const int w = threadIdx.x >> 6;
    const int l = threadIdx.x & 63;
    const int bm = blockIdx.x * 128;
    const int lm = l & 15, lk = l >> 4;

    floatx4 acc[2][3];
#pragma unroll
    for (int i = 0; i < 2; i++)
#pragma unroll
        for (int j = 0; j < 3; j++) acc[i][j] = (floatx4){0.f, 0.f, 0.f, 0.f};

#pragma unroll
    for (int kk = 0; kk < 8; kk++) {
        const unsigned short* abase = h1b + (size_t)(bm + w * 32 + lm) * 256 + kk * 32 + lk * 8;
        short8 a0 = *(const short8*)(abase);
        short8 a1 = *(const short8*)(abase + 16 * 256);
        const unsigned short* bbase = bfrag + (size_t)(kk * 64 + l) * 8;
        short8 b[3];
#pragma unroll
        for (int j = 0; j < 3; j++) b[j] = *(const short8*)(bbase + j * (8 * 64 * 8));
#pragma unroll
        for (int j = 0; j < 3; j++) {
            acc[0][j] = __builtin_amdgcn_mfma_f32_16x16x32_bf16(a0, b[j], acc[0][j], 0, 0, 0);
            acc[1][j] = __builtin_amdgcn_mfma_f32_16x16x32_bf16(a1, b[j], acc[1][j], 0, 0, 0);
        }
    }
#pragma unroll
    for (int i = 0; i < 2; i++) {
        int row0 = bm + w * 32 + i * 16 + lk * 4;
#pragma unroll
        for (int r = 0; r < 4; r++) {
            int row = row0 + r;
            if (row >= NNODES) continue;
#pragma unroll
            for (int j = 0; j < 3; j++) {
                int col = j * 16 + lm;
                fs2b[(size_t)row * 48 + col] = f2bf(acc[i][j][r]);
            }
        }
    }
}

// ---------------------------------------------------------------------------
// Layer-1 logits (R7 verbatim). One block per node, wave = head.
// ---------------------------------------------------------------------------
__global__ __launch_bounds__(256) void logits1(const unsigned short* __restrict__ fs1b,
                                               const float* __restrict__ al,
                                               const float* __restrict__ ar,
                                               float* __restrict__ el,
                                               float* __restrict__ er) {
    int n = blockIdx.x;
    int tid = threadIdx.x;
    int h = tid >> 6, d = tid & 63;
    float v = bf2f(fs1b[(size_t)n * 256 + tid]);
    float pa = v * al[h * 64 + d];
    float pb = v * ar[h * 64 + d];
    for (int off = 32; off > 0; off >>= 1) {
        pa += __shfl_down(pa, off);
        pb += __shfl_down(pb, off);
    }
    if (d == 0) { el[n * 4 + h] = pa; er[n * 4 + h] = pb; }
}

// ---------------------------------------------------------------------------
// Layer-1 softmax + aggregate — WAVE PER NODE (the ONE change vs R7).
// Wave q -> node n = blockIdx.x*4 + q. No barriers, no cross-wave reduce.
// Phase 1: lane l strides edges by 64, online (m,s) for all 4 heads
//   (edge->lane assignment identical to R7's per-head phase 1, so m/s/weights
//    are bit-identical to the passing kernel).
// Phase 2: src idx + normalized weights -> per-wave LDS (scache/wcache).
// Pass B: sub=l>>5 picks even/odd edge, c=l&31 owns channels 8c..8c+7
//   (head hl=c>>3); uint4 bf16 gathers; combine subs via shfl_xor(32).
// ---------------------------------------------------------------------------
__global__ __launch_bounds__(256) void agg1(const int* __restrict__ row_ptr,
                                            const int* __restrict__ src,
                                            const float* __restrict__ el,
                                            const float* __restrict__ er,
                                            const unsigned short* __restrict__ fs1b,
                                            const float* __restrict__ b1,
                                            unsigned short* __restrict__ h1b) {
    __shared__ float wcache[4][CAPW * 4];
    __shared__ int   scache[4][CAPW];
    const int q = threadIdx.x >> 6;
    const int l = threadIdx.x & 63;
    const int n = blockIdx.x * 4 + q;          // 12500*4 == NNODES exactly
    const int start = row_ptr[n], end = row_ptr[n + 1];
    const int deg = end - start;

    const float4 erv = *(const float4*)(er + n * 4);

    // Phase 1
    float m0 = -1e30f, m1 = -1e30f, m2 = -1e30f, m3 = -1e30f;
    float s0 = 0.f, s1 = 0.f, s2 = 0.f, s3 = 0.f;
    for (int i = start + l; i < end; i += 64) {
        float4 e4 = *(const float4*)(el + src[i] * 4);
        float e;
        e = lrelu(e4.x + erv.x); { float nm = fmaxf(m0, e); s0 = s0 * __expf(m0 - nm) + __expf(e - nm); m0 = nm; }
        e = lrelu(e4.y + erv.y); { float nm = fmaxf(m1, e); s1 = s1 * __expf(m1 - nm) + __expf(e - nm); m1 = nm; }
        e = lrelu(e4.z + erv.z); { float nm = fmaxf(m2, e); s2 = s2 * __expf(m2 - nm) + __expf(e - nm); m2 = nm; }
        e = lrelu(e4.w + erv.w); { float nm = fmaxf(m3, e); s3 = s3 * __expf(m3 - nm) + __expf(e - nm); m3 = nm; }
    }
    // butterfly combine (same as R7's phase-1 wave combine, per head)
    for (int off = 32; off > 0; off >>= 1) {
        float mo, so, nm;
        mo = __shfl_xor(m0, off); so = __shfl_xor(s0, off);
        nm = fmaxf(m0, mo); s0 = s0 * __expf(m0 - nm) + so * __expf(mo - nm); m0 = nm;
        mo = __shfl_xor(m1, off); so = __shfl_xor(s1, off);
        nm = fmaxf(m1, mo); s1 = s1 * __expf(m1 - nm) + so * __expf(mo - nm); m1 = nm;
        mo = __shfl_xor(m2, off); so = __shfl_xor(s2, off);
        nm = fmaxf(m2, mo); s2 = s2 * __expf(m2 - nm) + so * __expf(mo - nm); m2 = nm;
        mo = __shfl_xor(m3, off); so = __shfl_xor(s3, off);
        nm = fmaxf(m3, mo); s3 = s3 * __expf(m3 - nm) + so * __expf(mo - nm); m3 = nm;
    }
    const float rs0 = deg > 0 ? 1.f / s0 : 0.f;
    const float rs1 = deg > 0 ? 1.f / s1 : 0.f;
    const float rs2 = deg > 0 ? 1.f / s2 : 0.f;
    const float rs3 = deg > 0 ? 1.f / s3 : 0.f;

    const int sub = l >> 5, c = l & 31, hl = c >> 3;
    float a[8] = {};

    if (deg <= CAPW) {
        // Phase 2: src + normalized weights to per-wave LDS (same wave ->
        // DS ops are in-order, no barrier needed)
        for (int k = l; k < deg; k += 64) {
            int sv = src[start + k];
            scache[q][k] = sv;
            float4 e4 = *(const float4*)(el + sv * 4);
            float w0 = __expf(lrelu(e4.x + erv.x) - m0) * rs0;
            float w1 = __expf(lrelu(e4.y + erv.y) - m1) * rs1;
            float w2 = __expf(lrelu(e4.z + erv.z) - m2) * rs2;
            float w3 = __expf(lrelu(e4.w + erv.w) - m3) * rs3;
            *(float4*)(&wcache[q][k * 4]) = make_float4(w0, w1, w2, w3);
        }
        for (int j = sub; j < deg; j += 2) {
            int sv = scache[q][j];
            float wv = wcache[q][j * 4 + hl];
            uint4 g = *(const uint4*)(fs1b + (size_t)sv * 256 + c * 8);
            a[0] += wv * bf2f(g.x & 0xFFFFu); a[1] += wv * bf2f(g.x >> 16);
            a[2] += wv * bf2f(g.y & 0xFFFFu); a[3] += wv * bf2f(g.y >> 16);
            a[4] += wv * bf2f(g.z & 0xFFFFu); a[5] += wv * bf2f(g.z >> 16);
            a[6] += wv * bf2f(g.w & 0xFFFFu); a[7] += wv * bf2f(g.w >> 16);
        }
    } else {
        // slow path (deg > CAPW: ~never for this graph). Per-edge recompute.
        const float Mh  = hl == 0 ? m0  : hl == 1 ? m1  : hl == 2 ? m2  : m3;
        const float rsh = hl == 0 ? rs0 : hl == 1 ? rs1 : hl == 2 ? rs2 : rs3;
        const float ervh = hl == 0 ? erv.x : hl == 1 ? erv.y : hl == 2 ? erv.z : erv.w;
        for (int j = sub; j < deg; j += 2) {
            int sv = src[start + j];
            float e = lrelu(el[sv * 4 + hl] + ervh);
            float wv = __expf(e - Mh) * rsh;
            uint4 g = *(const uint4*)(fs1b + (size_t)sv * 256 + c * 8);
            a[0] += wv * bf2f(g.x & 0xFFFFu); a[1] += wv * bf2f(g.x >> 16);
            a[2] += wv * bf2f(g.y & 0xFFFFu); a[3] += wv * bf2f(g.y >> 16);
            a[4] += wv * bf2f(g.z & 0xFFFFu); a[5] += wv * bf2f(g.z >> 16);
            a[6] += wv * bf2f(g.w & 0xFFFFu); a[7] += wv * bf2f(g.w >> 16);
        }
    }
#pragma unroll
    for (int j = 0; j < 8; j++) a[j] += __shfl_xor(a[j], 32);
    if (sub == 0) {
        float4 bA = *(const float4*)(b1 + c * 8);
        float4 bB = *(const float4*)(b1 + c * 8 + 4);
        float v0 = fmaxf(a[0] + bA.x, 0.f), v1 = fmaxf(a[1] + bA.y, 0.f);
        float v2 = fmaxf(a[2] + bA.z, 0.f), v3 = fmaxf(a[3] + bA.w, 0.f);
        float v4 = fmaxf(a[4] + bB.x, 0.f), v5 = fmaxf(a[5] + bB.y, 0.f);
        float v6 = fmaxf(a[6] + bB.z, 0.f), v7 = fmaxf(a[7] + bB.w, 0.f);
        uint4 o;
        o.x = (unsigned)f2bf(v0) | ((unsigned)f2bf(v1) << 16);
        o.y = (unsigned)f2bf(v2) | ((unsigned)f2bf(v3) << 16);
        o.z = (unsigned)f2bf(v4) | ((unsigned)f2bf(v5) << 16);
        o.w = (unsigned)f2bf(v6) | ((unsigned)f2bf(v7) << 16);
        *(uint4*)(h1b + (size_t)n * 256 + c * 8) = o;
    }
}

// ---------------------------------------------------------------------------
// Layer-2 logits (R7 verbatim). Wave per node (4 nodes/block).
// ---------------------------------------------------------------------------
__global__ __launch_bounds__(256) void logits2(const unsigned short* __restrict__ fs2b,
                                               const float* __restrict__ al,
                                               const float* __restrict__ ar,
                                               float* __restrict__ el,
                                               float* __restrict__ er) {
    int l = threadIdx.x & 63;
    int n = blockIdx.x * 4 + (threadIdx.x >> 6);
    if (n >= NNODES) return;
    float pa = 0.f, pb = 0.f;
    if (l < 24) {
        unsigned int q = *(const unsigned int*)(fs2b + (size_t)n * 48 + l * 2);
        float v0 = bf2f(q & 0xFFFFu), v1 = bf2f(q >> 16);
        float a1 = (l * 2 + 1 < 47) ? al[l * 2 + 1] : 0.f;
        float r1 = (l * 2 + 1 < 47) ? ar[l * 2 + 1] : 0.f;
        pa = v0 * al[l * 2] + v1 * a1;
        pb = v0 * ar[l * 2] + v1 * r1;
    }
    for (int off = 32; off > 0; off >>= 1) {
        pa += __shfl_down(pa, off);
        pb += __shfl_down(pb, off);
    }
    if (l == 0) { el[n] = pa; er[n] = pb; }
}

// ---------------------------------------------------------------------------
// Layer-2 softmax + aggregate (R7 verbatim). Block = node.
// ---------------------------------------------------------------------------
__global__ __launch_bounds__(256) void agg2(const int* __restrict__ row_ptr,
                                            const int* __restrict__ src,
                                            const float* __restrict__ el,
                                            const float* __restrict__ er,
                                            const unsigned short* __restrict__ fs2b,
                                            const float* __restrict__ b2,
                                            float* __restrict__ out) {
    __shared__ float s_m, s_rs;
    __shared__ float wbuf[CAP2];
    __shared__ float red[4][48];
    const int n = blockIdx.x;
    const int tid = threadIdx.x;
    const int w = tid >> 6, l = tid & 63;
    const int start = row_ptr[n], end = row_ptr[n + 1];
    const int deg = end - start;
    const float erv = er[n];

    if (w == 0) {
        float m = -1e30f, s = 0.f;
        for (int i = start + l; i < end; i += 64) {
            float e = el[src[i]] + erv;
            e = e > 0.f ? e : NEG_SLOPE * e;
            float nm = fmaxf(m, e);
            s = s * __expf(m - nm) + __expf(e - nm);
            m = nm;
        }
        for (int off = 32; off > 0; off >>= 1) {
            float mo = __shfl_xor(m, off), so = __shfl_xor(s, off);
            float nm = fmaxf(m, mo);
            s = s * __expf(m - nm) + so * __expf(mo - nm);
            m = nm;
        }
        if (l == 0) { s_m = m; s_rs = (deg > 0) ? 1.f / s : 0.f; }
    }
    __syncthreads();

    {
        const float mh = s_m, rsh = s_rs;
        const int lim = deg < CAP2 ? deg : CAP2;
        for (int k = tid; k < lim; k += 256) {
            float e = el[src[start + k]] + erv;
            e = e > 0.f ? e : NEG_SLOPE * e;
            wbuf[k] = __expf(e - mh) * rsh;
        }
    }
    __syncthreads();

    const int sub = l >> 5, c = l & 31;
    const float mh = s_m, rsh = s_rs;
    float a0 = 0.f, a1 = 0.f;
    for (int i0 = start + w * 2; i0 < end; i0 += 8) {
        int i = i0 + sub;
        bool ok = i < end;
        int ii = ok ? i : start;
        int sv = src[ii];
        int k = ii - start;
        float wv;
        if (k < CAP2) wv = wbuf[k];
        else {
            float e = el[sv] + erv;
            e = e > 0.f ? e : NEG_SLOPE * e;
            wv = __expf(e - mh) * rsh;
        }
        if (!ok) wv = 0.f;
        if (c < 24) {
            unsigned int g = *(const unsigned int*)(fs2b + (size_t)sv * 48 + c * 2);
            a0 += wv * bf2f(g & 0xFFFFu);
            a1 += wv * bf2f(g >> 16);
        }
    }
    a0 += __shfl_xor(a0, 32);
    a1 += __shfl_xor(a1, 32);
    if (sub == 0 && c < 24) { red[w][c * 2] = a0; red[w][c * 2 + 1] = a1; }
    __syncthreads();
    if (tid < 47) {
        float tot = red[0][tid] + red[1][tid] + red[2][tid] + red[3][tid];
        float val = (end > start) ? tot : 0.f;
        out[(size_t)n * 47 + tid] = val + b2[tid];
    }
}

// ---------------------------------------------------------------------------
// Launch. Inputs: 0:x 1:W1 2:al1 3:ar1 4:b1 5:W2 6:al2 7:ar2 8:b2 9:src 10:dst
// ---------------------------------------------------------------------------
extern "C" void kernel_launch(void* const* d_in, const int* in_sizes, int n_in,
                              void* d_out, int out_size, void* d_ws, size_t ws_size,
                              hipStream_t stream) {
    const float* x   = (const float*)d_in[0];
    const float* W1  = (const float*)d_in[1];
    const float* al1 = (const float*)d_in[2];
    const float* ar1 = (const float*)d_in[3];
    const float* b1  = (const float*)d_in[4];
    const float* W2  = (const float*)d_in[5];
    const float* al2 = (const float*)d_in[6];
    const float* ar2 = (const float*)d_in[7];
    const float* b2  = (const float*)d_in[8];
    const int*   src = (const int*)d_in[9];
    const int*   dst = (const int*)d_in[10];
    float* out = (float*)d_out;

    char* ws = (char*)d_ws;
    size_t off = 0;
    auto alloc = [&](size_t bytes) {
        void* p = ws + off;
        off += (bytes + 255) & ~(size_t)255;
        return p;
    };
    int*            row_ptr = (int*)alloc((NNODES + 1) * sizeof(int));
    unsigned short* xb      = (unsigned short*)alloc((size_t)MPAD * 256 * 2);
    unsigned short* bfrag1  = (unsigned short*)alloc(16 * 8 * 64 * 8 * 2);
    unsigned short* bfrag2  = (unsigned short*)alloc(3 * 8 * 64 * 8 * 2);
    unsigned short* fs1b    = (unsigned short*)alloc((size_t)NNODES * 256 * 2);
    unsigned short* h1b     = (unsigned short*)alloc((size_t)MPAD * 256 * 2);
    unsigned short* fs2b    = (unsigned short*)alloc((size_t)NNODES * 48 * 2);
    float*          el1     = (float*)alloc((size_t)NNODES * 4 * sizeof(float));
    float*          er1     = (float*)alloc((size_t)NNODES * 4 * sizeof(float));
    float*          el2     = (float*)alloc((size_t)NNODES * sizeof(float));
    float*          er2     = (float*)alloc((size_t)NNODES * sizeof(float));
    (void)ws_size; (void)n_in; (void)in_sizes; (void)out_size;

    prep<<<12794, 256, 0, stream>>>(x, W1, W2, dst, xb, bfrag1, bfrag2, h1b, row_ptr);

    // Layer 1
    mfma_gemm1<<<dim3(MPAD / 128, 4), 256, 0, stream>>>(xb, bfrag1, fs1b);
    logits1<<<NNODES, 256, 0, stream>>>(fs1b, al1, ar1, el1, er1);
    agg1<<<NNODES / 4, 256, 0, stream>>>(row_ptr, src, el1, er1, fs1b, b1, h1b);

    // Layer 2
    mfma_gemm2<<<MPAD / 128, 256, 0, stream>>>(h1b, bfrag2, fs2b);
    logits2<<<(NNODES + 3) / 4, 256, 0, stream>>>(fs2b, al2, ar2, el2, er2);
    agg2<<<NNODES, 256, 0, stream>>>(row_ptr, src, el2, er2, fs2b, b2, out);
}

// Round 9
// 298.918 us; speedup vs baseline: 2.0246x; 1.1579x over previous
//
#include <hip/hip_runtime.h>
#include <math.h>

#define NNODES 50000
#define NEDGES 800000
#define NEG_SLOPE 0.2f
#define MPAD 50048   // 391 * 128
#define CAPW 128     // per-wave LDS edge cache; deg>CAPW -> slow path

typedef __attribute__((ext_vector_type(8))) short short8;
typedef __attribute__((ext_vector_type(4))) float floatx4;

// bf16 helpers (RNE)
__device__ __forceinline__ unsigned short f2bf(float f) {
    union { float f; unsigned int u; } v; v.f = f;
    unsigned int r = v.u + 0x7FFFu + ((v.u >> 16) & 1u);
    return (unsigned short)(r >> 16);
}
__device__ __forceinline__ float bf2f(unsigned int s) {
    union { unsigned int u; float f; } v; v.u = s << 16; return v.f;
}
__device__ __forceinline__ float lrelu(float e) { return e > 0.f ? e : NEG_SLOPE * e; }

// ---------------------------------------------------------------------------
// prep: merged prologue (verified R7/R8).
// ---------------------------------------------------------------------------
__global__ __launch_bounds__(256) void prep(const float* __restrict__ x,
                                            const float* __restrict__ W1,
                                            const float* __restrict__ W2,
                                            const int* __restrict__ dst,
                                            unsigned short* __restrict__ xb,
                                            unsigned short* __restrict__ bfrag1,
                                            unsigned short* __restrict__ bfrag2,
                                            unsigned short* __restrict__ h1b,
                                            int* __restrict__ row_ptr) {
    int b = blockIdx.x;
    if (b < 12512) {
        long e = ((long)b * 256 + threadIdx.x) * 4;
        const long NE = (long)NNODES * 256;
        ushort4 o;
        o.x = (e + 0 < NE) ? f2bf(x[e + 0]) : 0;
        o.y = (e + 1 < NE) ? f2bf(x[e + 1]) : 0;
        o.z = (e + 2 < NE) ? f2bf(x[e + 2]) : 0;
        o.w = (e + 3 < NE) ? f2bf(x[e + 3]) : 0;
        *(ushort4*)(xb + e) = o;
    } else if (b < 12708) {
        int n = (b - 12512) * 256 + threadIdx.x;
        if (n > NNODES) return;
        int lo = 0, hi = NEDGES;
        while (lo < hi) {
            int mid = (lo + hi) >> 1;
            if (dst[mid] < n) lo = mid + 1; else hi = mid;
        }
        row_ptr[n] = lo;
    } else if (b < 12740) {
        int c = (b - 12708) * 256 + threadIdx.x;   // 8192 chunks
        int l = c & 63, kk = (c >> 6) & 7, t = c >> 9;
        int n = t * 16 + (l & 15);
        int kbase = kk * 32 + (l >> 4) * 8;
#pragma unroll
        for (int j = 0; j < 8; j++)
            bfrag1[c * 8 + j] = f2bf(W1[(kbase + j) * 256 + n]);
    } else if (b < 12746) {
        int c = (b - 12740) * 256 + threadIdx.x;   // 1536 chunks
        int l = c & 63, kk = (c >> 6) & 7, t = c >> 9;
        int n = t * 16 + (l & 15);
        int kbase = kk * 32 + (l >> 4) * 8;
#pragma unroll
        for (int j = 0; j < 8; j++)
            bfrag2[c * 8 + j] = (n < 47) ? f2bf(W2[(kbase + j) * 47 + n]) : 0;
    } else {
        int row = NNODES + (b - 12746);
        h1b[(size_t)row * 256 + threadIdx.x] = 0;
    }
}

// ---------------------------------------------------------------------------
// GEMM1 (verbatim): fs1b[M,256] = xb @ W1 (bf16 MFMA).
// ---------------------------------------------------------------------------
__global__ __launch_bounds__(256) void mfma_gemm1(const unsigned short* __restrict__ xb,
                                                  const unsigned short* __restrict__ bfrag,
                                                  unsigned short* __restrict__ fs1b) {
    const int w = threadIdx.x >> 6;
    const int l = threadIdx.x & 63;
    const int bm = blockIdx.x * 128;
    const int n0 = blockIdx.y * 64;
    const int lm = l & 15, lk = l >> 4;

    floatx4 acc[2][4];
#pragma unroll
    for (int i = 0; i < 2; i++)
#pragma unroll
        for (int j = 0; j < 4; j++) acc[i][j] = (floatx4){0.f, 0.f, 0.f, 0.f};

    const int t0 = n0 >> 4;
#pragma unroll
    for (int kk = 0; kk < 8; kk++) {
        const unsigned short* abase = xb + (size_t)(bm + w * 32 + lm) * 256 + kk * 32 + lk * 8;
        short8 a0 = *(const short8*)(abase);
        short8 a1 = *(const short8*)(abase + 16 * 256);
        const unsigned short* bbase = bfrag + ((t0 * 8 + kk) * 64 + l) * 8;
        short8 b[4];
#pragma unroll
        for (int j = 0; j < 4; j++) b[j] = *(const short8*)(bbase + j * 8 * 64 * 8);
#pragma unroll
        for (int j = 0; j < 4; j++) {
            acc[0][j] = __builtin_amdgcn_mfma_f32_16x16x32_bf16(a0, b[j], acc[0][j], 0, 0, 0);
            acc[1][j] = __builtin_amdgcn_mfma_f32_16x16x32_bf16(a1, b[j], acc[1][j], 0, 0, 0);
        }
    }
#pragma unroll
    for (int i = 0; i < 2; i++) {
        int row0 = bm + w * 32 + i * 16 + lk * 4;
#pragma unroll
        for (int r = 0; r < 4; r++) {
            int row = row0 + r;
            if (row >= NNODES) continue;
#pragma unroll
            for (int j = 0; j < 4; j++) {
                int col = n0 + j * 16 + lm;
                fs1b[(size_t)row * 256 + col] = f2bf(acc[i][j][r]);
            }
        }
    }
}

// ---------------------------------------------------------------------------
// GEMM2 (verbatim): fs2b[M,48] = h1b @ W2pad.
// ---------------------------------------------------------------------------
__global__ __launch_bounds__(256) void mfma_gemm2(const unsigned short* __restrict__ h1b,
                                                  const unsigned short* __restrict__ bfrag,
                                                  unsigned short* __restrict__ fs2b) {
    const int w = threadIdx.x >> 6;
    const int l = threadIdx.x & 63;
    const int bm = blockIdx.x * 128;
    const int lm = l & 15, lk = l >> 4;

    floatx4 acc[2][3];
#pragma unroll
    for (int i = 0; i < 2; i++)
#pragma unroll
        for (int j = 0; j < 3; j++) acc[i][j] = (floatx4){0.f, 0.f, 0.f, 0.f};

#pragma unroll
    for (int kk = 0; kk < 8; kk++) {
        const unsigned short* abase = h1b + (size_t)(bm + w * 32 + lm) * 256 + kk * 32 + lk * 8;
        short8 a0 = *(const short8*)(abase);
        short8 a1 = *(const short8*)(abase + 16 * 256);
        const unsigned short* bbase = bfrag + (size_t)(kk * 64 + l) * 8;
        short8 b[3];
#pragma unroll
        for (int j = 0; j < 3; j++) b[j] = *(const short8*)(bbase + j * (8 * 64 * 8));
#pragma unroll
        for (int j = 0; j < 3; j++) {
            acc[0][j] = __builtin_amdgcn_mfma_f32_16x16x32_bf16(a0, b[j], acc[0][j], 0, 0, 0);
            acc[1][j] = __builtin_amdgcn_mfma_f32_16x16x32_bf16(a1, b[j], acc[1][j], 0, 0, 0);
        }
    }
#pragma unroll
    for (int i = 0; i < 2; i++) {
        int row0 = bm + w * 32 + i * 16 + lk * 4;
#pragma unroll
        for (int r = 0; r < 4; r++) {
            int row = row0 + r;
            if (row >= NNODES) continue;
#pragma unroll
            for (int j = 0; j < 3; j++) {
                int col = j * 16 + lm;
                fs2b[(size_t)row * 48 + col] = f2bf(acc[i][j][r]);
            }
        }
    }
}

// ---------------------------------------------------------------------------
// Layer-1 logits (verbatim). One block per node, wave = head.
// ---------------------------------------------------------------------------
__global__ __launch_bounds__(256) void logits1(const unsigned short* __restrict__ fs1b,
                                               const float* __restrict__ al,
                                               const float* __restrict__ ar,
                                               float* __restrict__ el,
                                               float* __restrict__ er) {
    int n = blockIdx.x;
    int tid = threadIdx.x;
    int h = tid >> 6, d = tid & 63;
    float v = bf2f(fs1b[(size_t)n * 256 + tid]);
    float pa = v * al[h * 64 + d];
    float pb = v * ar[h * 64 + d];
    for (int off = 32; off > 0; off >>= 1) {
        pa += __shfl_down(pa, off);
        pb += __shfl_down(pb, off);
    }
    if (d == 0) { el[n * 4 + h] = pa; er[n * 4 + h] = pb; }
}

// ---------------------------------------------------------------------------
// Layer-1 softmax + aggregate — wave per node (verified R8).
// ---------------------------------------------------------------------------
__global__ __launch_bounds__(256) void agg1(const int* __restrict__ row_ptr,
                                            const int* __restrict__ src,
                                            const float* __restrict__ el,
                                            const float* __restrict__ er,
                                            const unsigned short* __restrict__ fs1b,
                                            const float* __restrict__ b1,
                                            unsigned short* __restrict__ h1b) {
    __shared__ float wcache[4][CAPW * 4];
    __shared__ int   scache[4][CAPW];
    const int q = threadIdx.x >> 6;
    const int l = threadIdx.x & 63;
    const int n = blockIdx.x * 4 + q;          // 12500*4 == NNODES exactly
    const int start = row_ptr[n], end = row_ptr[n + 1];
    const int deg = end - start;

    const float4 erv = *(const float4*)(er + n * 4);

    // Phase 1
    float m0 = -1e30f, m1 = -1e30f, m2 = -1e30f, m3 = -1e30f;
    float s0 = 0.f, s1 = 0.f, s2 = 0.f, s3 = 0.f;
    for (int i = start + l; i < end; i += 64) {
        float4 e4 = *(const float4*)(el + src[i] * 4);
        float e;
        e = lrelu(e4.x + erv.x); { float nm = fmaxf(m0, e); s0 = s0 * __expf(m0 - nm) + __expf(e - nm); m0 = nm; }
        e = lrelu(e4.y + erv.y); { float nm = fmaxf(m1, e); s1 = s1 * __expf(m1 - nm) + __expf(e - nm); m1 = nm; }
        e = lrelu(e4.z + erv.z); { float nm = fmaxf(m2, e); s2 = s2 * __expf(m2 - nm) + __expf(e - nm); m2 = nm; }
        e = lrelu(e4.w + erv.w); { float nm = fmaxf(m3, e); s3 = s3 * __expf(m3 - nm) + __expf(e - nm); m3 = nm; }
    }
    for (int off = 32; off > 0; off >>= 1) {
        float mo, so, nm;
        mo = __shfl_xor(m0, off); so = __shfl_xor(s0, off);
        nm = fmaxf(m0, mo); s0 = s0 * __expf(m0 - nm) + so * __expf(mo - nm); m0 = nm;
        mo = __shfl_xor(m1, off); so = __shfl_xor(s1, off);
        nm = fmaxf(m1, mo); s1 = s1 * __expf(m1 - nm) + so * __expf(mo - nm); m1 = nm;
        mo = __shfl_xor(m2, off); so = __shfl_xor(s2, off);
        nm = fmaxf(m2, mo); s2 = s2 * __expf(m2 - nm) + so * __expf(mo - nm); m2 = nm;
        mo = __shfl_xor(m3, off); so = __shfl_xor(s3, off);
        nm = fmaxf(m3, mo); s3 = s3 * __expf(m3 - nm) + so * __expf(mo - nm); m3 = nm;
    }
    const float rs0 = deg > 0 ? 1.f / s0 : 0.f;
    const float rs1 = deg > 0 ? 1.f / s1 : 0.f;
    const float rs2 = deg > 0 ? 1.f / s2 : 0.f;
    const float rs3 = deg > 0 ? 1.f / s3 : 0.f;

    const int sub = l >> 5, c = l & 31, hl = c >> 3;
    float a[8] = {};

    if (deg <= CAPW) {
        for (int k = l; k < deg; k += 64) {
            int sv = src[start + k];
            scache[q][k] = sv;
            float4 e4 = *(const float4*)(el + sv * 4);
            float w0 = __expf(lrelu(e4.x + erv.x) - m0) * rs0;
            float w1 = __expf(lrelu(e4.y + erv.y) - m1) * rs1;
            float w2 = __expf(lrelu(e4.z + erv.z) - m2) * rs2;
            float w3 = __expf(lrelu(e4.w + erv.w) - m3) * rs3;
            *(float4*)(&wcache[q][k * 4]) = make_float4(w0, w1, w2, w3);
        }
        for (int j = sub; j < deg; j += 2) {
            int sv = scache[q][j];
            float wv = wcache[q][j * 4 + hl];
            uint4 g = *(const uint4*)(fs1b + (size_t)sv * 256 + c * 8);
            a[0] += wv * bf2f(g.x & 0xFFFFu); a[1] += wv * bf2f(g.x >> 16);
            a[2] += wv * bf2f(g.y & 0xFFFFu); a[3] += wv * bf2f(g.y >> 16);
            a[4] += wv * bf2f(g.z & 0xFFFFu); a[5] += wv * bf2f(g.z >> 16);
            a[6] += wv * bf2f(g.w & 0xFFFFu); a[7] += wv * bf2f(g.w >> 16);
        }
    } else {
        const float Mh  = hl == 0 ? m0  : hl == 1 ? m1  : hl == 2 ? m2  : m3;
        const float rsh = hl == 0 ? rs0 : hl == 1 ? rs1 : hl == 2 ? rs2 : rs3;
        const float ervh = hl == 0 ? erv.x : hl == 1 ? erv.y : hl == 2 ? erv.z : erv.w;
        for (int j = sub; j < deg; j += 2) {
            int sv = src[start + j];
            float e = lrelu(el[sv * 4 + hl] + ervh);
            float wv = __expf(e - Mh) * rsh;
            uint4 g = *(const uint4*)(fs1b + (size_t)sv * 256 + c * 8);
            a[0] += wv * bf2f(g.x & 0xFFFFu); a[1] += wv * bf2f(g.x >> 16);
            a[2] += wv * bf2f(g.y & 0xFFFFu); a[3] += wv * bf2f(g.y >> 16);
            a[4] += wv * bf2f(g.z & 0xFFFFu); a[5] += wv * bf2f(g.z >> 16);
            a[6] += wv * bf2f(g.w & 0xFFFFu); a[7] += wv * bf2f(g.w >> 16);
        }
    }
#pragma unroll
    for (int j = 0; j < 8; j++) a[j] += __shfl_xor(a[j], 32);
    if (sub == 0) {
        float4 bA = *(const float4*)(b1 + c * 8);
        float4 bB = *(const float4*)(b1 + c * 8 + 4);
        float v0 = fmaxf(a[0] + bA.x, 0.f), v1 = fmaxf(a[1] + bA.y, 0.f);
        float v2 = fmaxf(a[2] + bA.z, 0.f), v3 = fmaxf(a[3] + bA.w, 0.f);
        float v4 = fmaxf(a[4] + bB.x, 0.f), v5 = fmaxf(a[5] + bB.y, 0.f);
        float v6 = fmaxf(a[6] + bB.z, 0.f), v7 = fmaxf(a[7] + bB.w, 0.f);
        uint4 o;
        o.x = (unsigned)f2bf(v0) | ((unsigned)f2bf(v1) << 16);
        o.y = (unsigned)f2bf(v2) | ((unsigned)f2bf(v3) << 16);
        o.z = (unsigned)f2bf(v4) | ((unsigned)f2bf(v5) << 16);
        o.w = (unsigned)f2bf(v6) | ((unsigned)f2bf(v7) << 16);
        *(uint4*)(h1b + (size_t)n * 256 + c * 8) = o;
    }
}

// ---------------------------------------------------------------------------
// Layer-2 logits (verbatim). Wave per node (4 nodes/block).
// ---------------------------------------------------------------------------
__global__ __launch_bounds__(256) void logits2(const unsigned short* __restrict__ fs2b,
                                               const float* __restrict__ al,
                                               const float* __restrict__ ar,
                                               float* __restrict__ el,
                                               float* __restrict__ er) {
    int l = threadIdx.x & 63;
    int n = blockIdx.x * 4 + (threadIdx.x >> 6);
    if (n >= NNODES) return;
    float pa = 0.f, pb = 0.f;
    if (l < 24) {
        unsigned int q = *(const unsigned int*)(fs2b + (size_t)n * 48 + l * 2);
        float v0 = bf2f(q & 0xFFFFu), v1 = bf2f(q >> 16);
        float a1 = (l * 2 + 1 < 47) ? al[l * 2 + 1] : 0.f;
        float r1 = (l * 2 + 1 < 47) ? ar[l * 2 + 1] : 0.f;
        pa = v0 * al[l * 2] + v1 * a1;
        pb = v0 * ar[l * 2] + v1 * r1;
    }
    for (int off = 32; off > 0; off >>= 1) {
        pa += __shfl_down(pa, off);
        pb += __shfl_down(pb, off);
    }
    if (l == 0) { el[n] = pa; er[n] = pb; }
}

// ---------------------------------------------------------------------------
// Layer-2 softmax + aggregate — WAVE PER NODE (the ONE change vs R8).
// Mirror of R8's agg1 pattern: 4 nodes/block, no barriers; phase-1 butterfly;
// scache/wcache per-wave LDS; sub=l>>5 edge parity; c=l&31 (c<24) owns
// channel pair 2c; per-lane strided slow path for deg>CAPW.
// ---------------------------------------------------------------------------
__global__ __launch_bounds__(256) void agg2(const int* __restrict__ row_ptr,
                                            const int* __restrict__ src,
                                            const float* __restrict__ el,
                                            const float* __restrict__ er,
                                            const unsigned short* __restrict__ fs2b,
                                            const float* __restrict__ b2,
                                            float* __restrict__ out) {
    __shared__ float wcache[4][CAPW];
    __shared__ int   scache[4][CAPW];
    const int q = threadIdx.x >> 6;
    const int l = threadIdx.x & 63;
    const int n = blockIdx.x * 4 + q;          // 12500*4 == NNODES exactly
    const int start = row_ptr[n], end = row_ptr[n + 1];
    const int deg = end - start;
    const float erv = er[n];

    // Phase 1: online (m,s), butterfly combine
    float m = -1e30f, s = 0.f;
    for (int i = start + l; i < end; i += 64) {
        float e = lrelu(el[src[i]] + erv);
        float nm = fmaxf(m, e);
        s = s * __expf(m - nm) + __expf(e - nm);
        m = nm;
    }
    for (int off = 32; off > 0; off >>= 1) {
        float mo = __shfl_xor(m, off), so = __shfl_xor(s, off);
        float nm = fmaxf(m, mo);
        s = s * __expf(m - nm) + so * __expf(mo - nm);
        m = nm;
    }
    const float rs = deg > 0 ? 1.f / s : 0.f;

    const int sub = l >> 5, c = l & 31;
    float a0 = 0.f, a1 = 0.f;

    if (deg <= CAPW) {
        // Phase 2: src + normalized weight -> per-wave LDS (no barrier)
        for (int k = l; k < deg; k += 64) {
            int sv = src[start + k];
            scache[q][k] = sv;
            wcache[q][k] = __expf(lrelu(el[sv] + erv) - m) * rs;
        }
        for (int j = sub; j < deg; j += 2) {
            int sv = scache[q][j];
            float wv = wcache[q][j];
            if (c < 24) {
                unsigned int g = *(const unsigned int*)(fs2b + (size_t)sv * 48 + c * 2);
                a0 += wv * bf2f(g & 0xFFFFu);
                a1 += wv * bf2f(g >> 16);
            }
        }
    } else {
        // slow path: per-edge recompute
        for (int j = sub; j < deg; j += 2) {
            int sv = src[start + j];
            float wv = __expf(lrelu(el[sv] + erv) - m) * rs;
            if (c < 24) {
                unsigned int g = *(const unsigned int*)(fs2b + (size_t)sv * 48 + c * 2);
                a0 += wv * bf2f(g & 0xFFFFu);
                a1 += wv * bf2f(g >> 16);
            }
        }
    }
    a0 += __shfl_xor(a0, 32);
    a1 += __shfl_xor(a1, 32);
    if (sub == 0 && c < 24) {
        int ch = c * 2;
        out[(size_t)n * 47 + ch] = a0 + b2[ch];
        if (ch + 1 < 47) out[(size_t)n * 47 + ch + 1] = a1 + b2[ch + 1];
    }
}

// ---------------------------------------------------------------------------
// Launch. Inputs: 0:x 1:W1 2:al1 3:ar1 4:b1 5:W2 6:al2 7:ar2 8:b2 9:src 10:dst
// ---------------------------------------------------------------------------
extern "C" void kernel_launch(void* const* d_in, const int* in_sizes, int n_in,
                              void* d_out, int out_size, void* d_ws, size_t ws_size,
                              hipStream_t stream) {
    const float* x   = (const float*)d_in[0];
    const float* W1  = (const float*)d_in[1];
    const float* al1 = (const float*)d_in[2];
    const float* ar1 = (const float*)d_in[3];
    const float* b1  = (const float*)d_in[4];
    const float* W2  = (const float*)d_in[5];
    const float* al2 = (const float*)d_in[6];
    const float* ar2 = (const float*)d_in[7];
    const float* b2  = (const float*)d_in[8];
    const int*   src = (const int*)d_in[9];
    const int*   dst = (const int*)d_in[10];
    float* out = (float*)d_out;

    char* ws = (char*)d_ws;
    size_t off = 0;
    auto alloc = [&](size_t bytes) {
        void* p = ws + off;
        off += (bytes + 255) & ~(size_t)255;
        return p;
    };
    int*            row_ptr = (int*)alloc((NNODES + 1) * sizeof(int));
    unsigned short* xb      = (unsigned short*)alloc((size_t)MPAD * 256 * 2);
    unsigned short* bfrag1  = (unsigned short*)alloc(16 * 8 * 64 * 8 * 2);
    unsigned short* bfrag2  = (unsigned short*)alloc(3 * 8 * 64 * 8 * 2);
    unsigned short* fs1b    = (unsigned short*)alloc((size_t)NNODES * 256 * 2);
    unsigned short* h1b     = (unsigned short*)alloc((size_t)MPAD * 256 * 2);
    unsigned short* fs2b    = (unsigned short*)alloc((size_t)NNODES * 48 * 2);
    float*          el1     = (float*)alloc((size_t)NNODES * 4 * sizeof(float));
    float*          er1     = (float*)alloc((size_t)NNODES * 4 * sizeof(float));
    float*          el2     = (float*)alloc((size_t)NNODES * sizeof(float));
    float*          er2     = (float*)alloc((size_t)NNODES * sizeof(float));
    (void)ws_size; (void)n_in; (void)in_sizes; (void)out_size;

    prep<<<12794, 256, 0, stream>>>(x, W1, W2, dst, xb, bfrag1, bfrag2, h1b, row_ptr);

    // Layer 1
    mfma_gemm1<<<dim3(MPAD / 128, 4), 256, 0, stream>>>(xb, bfrag1, fs1b);
    logits1<<<NNODES, 256, 0, stream>>>(fs1b, al1, ar1, el1, er1);
    agg1<<<NNODES / 4, 256, 0, stream>>>(row_ptr, src, el1, er1, fs1b, b1, h1b);

    // Layer 2
    mfma_gemm2<<<MPAD / 128, 256, 0, stream>>>(h1b, bfrag2, fs2b);
    logits2<<<(NNODES + 3) / 4, 256, 0, stream>>>(fs2b, al2, ar2, el2, er2);
    agg2<<<NNODES / 4, 256, 0, stream>>>(row_ptr, src, el2, er2, fs2b, b2, out);
}

// Round 10
// 294.717 us; speedup vs baseline: 2.0534x; 1.0143x over previous
//
#include <hip/hip_runtime.h>
#include <math.h>

#define NNODES 50000
#define NEDGES 800000
#define NEG_SLOPE 0.2f
#define MPAD 50048   // 391 * 128
#define CAPW 64      // fast path: deg <= 64, one edge per lane

typedef __attribute__((ext_vector_type(8))) short short8;
typedef __attribute__((ext_vector_type(4))) float floatx4;

// bf16 helpers (RNE)
__device__ __forceinline__ unsigned short f2bf(float f) {
    union { float f; unsigned int u; } v; v.f = f;
    unsigned int r = v.u + 0x7FFFu + ((v.u >> 16) & 1u);
    return (unsigned short)(r >> 16);
}
__device__ __forceinline__ float bf2f(unsigned int s) {
    union { unsigned int u; float f; } v; v.u = s << 16; return v.f;
}
__device__ __forceinline__ float lrelu(float e) { return e > 0.f ? e : NEG_SLOPE * e; }

// ---------------------------------------------------------------------------
// prep: merged prologue (verified R7-R9).
// ---------------------------------------------------------------------------
__global__ __launch_bounds__(256) void prep(const float* __restrict__ x,
                                            const float* __restrict__ W1,
                                            const float* __restrict__ W2,
                                            const int* __restrict__ dst,
                                            unsigned short* __restrict__ xb,
                                            unsigned short* __restrict__ bfrag1,
                                            unsigned short* __restrict__ bfrag2,
                                            unsigned short* __restrict__ h1b,
                                            int* __restrict__ row_ptr) {
    int b = blockIdx.x;
    if (b < 12512) {
        long e = ((long)b * 256 + threadIdx.x) * 4;
        const long NE = (long)NNODES * 256;
        ushort4 o;
        o.x = (e + 0 < NE) ? f2bf(x[e + 0]) : 0;
        o.y = (e + 1 < NE) ? f2bf(x[e + 1]) : 0;
        o.z = (e + 2 < NE) ? f2bf(x[e + 2]) : 0;
        o.w = (e + 3 < NE) ? f2bf(x[e + 3]) : 0;
        *(ushort4*)(xb + e) = o;
    } else if (b < 12708) {
        int n = (b - 12512) * 256 + threadIdx.x;
        if (n > NNODES) return;
        int lo = 0, hi = NEDGES;
        while (lo < hi) {
            int mid = (lo + hi) >> 1;
            if (dst[mid] < n) lo = mid + 1; else hi = mid;
        }
        row_ptr[n] = lo;
    } else if (b < 12740) {
        int c = (b - 12708) * 256 + threadIdx.x;   // 8192 chunks
        int l = c & 63, kk = (c >> 6) & 7, t = c >> 9;
        int n = t * 16 + (l & 15);
        int kbase = kk * 32 + (l >> 4) * 8;
#pragma unroll
        for (int j = 0; j < 8; j++)
            bfrag1[c * 8 + j] = f2bf(W1[(kbase + j) * 256 + n]);
    } else if (b < 12746) {
        int c = (b - 12740) * 256 + threadIdx.x;   // 1536 chunks
        int l = c & 63, kk = (c >> 6) & 7, t = c >> 9;
        int n = t * 16 + (l & 15);
        int kbase = kk * 32 + (l >> 4) * 8;
#pragma unroll
        for (int j = 0; j < 8; j++)
            bfrag2[c * 8 + j] = (n < 47) ? f2bf(W2[(kbase + j) * 47 + n]) : 0;
    } else {
        int row = NNODES + (b - 12746);
        h1b[(size_t)row * 256 + threadIdx.x] = 0;
    }
}

// ---------------------------------------------------------------------------
// GEMM1 (verbatim): fs1b[M,256] = xb @ W1 (bf16 MFMA).
// ---------------------------------------------------------------------------
__global__ __launch_bounds__(256) void mfma_gemm1(const unsigned short* __restrict__ xb,
                                                  const unsigned short* __restrict__ bfrag,
                                                  unsigned short* __restrict__ fs1b) {
    const int w = threadIdx.x >> 6;
    const int l = threadIdx.x & 63;
    const int bm = blockIdx.x * 128;
    const int n0 = blockIdx.y * 64;
    const int lm = l & 15, lk = l >> 4;

    floatx4 acc[2][4];
#pragma unroll
    for (int i = 0; i < 2; i++)
#pragma unroll
        for (int j = 0; j < 4; j++) acc[i][j] = (floatx4){0.f, 0.f, 0.f, 0.f};

    const int t0 = n0 >> 4;
#pragma unroll
    for (int kk = 0; kk < 8; kk++) {
        const unsigned short* abase = xb + (size_t)(bm + w * 32 + lm) * 256 + kk * 32 + lk * 8;
        short8 a0 = *(const short8*)(abase);
        short8 a1 = *(const short8*)(abase + 16 * 256);
        const unsigned short* bbase = bfrag + ((t0 * 8 + kk) * 64 + l) * 8;
        short8 b[4];
#pragma unroll
        for (int j = 0; j < 4; j++) b[j] = *(const short8*)(bbase + j * 8 * 64 * 8);
#pragma unroll
        for (int j = 0; j < 4; j++) {
            acc[0][j] = __builtin_amdgcn_mfma_f32_16x16x32_bf16(a0, b[j], acc[0][j], 0, 0, 0);
            acc[1][j] = __builtin_amdgcn_mfma_f32_16x16x32_bf16(a1, b[j], acc[1][j], 0, 0, 0);
        }
    }
#pragma unroll
    for (int i = 0; i < 2; i++) {
        int row0 = bm + w * 32 + i * 16 + lk * 4;
#pragma unroll
        for (int r = 0; r < 4; r++) {
            int row = row0 + r;
            if (row >= NNODES) continue;
#pragma unroll
            for (int j = 0; j < 4; j++) {
                int col = n0 + j * 16 + lm;
                fs1b[(size_t)row * 256 + col] = f2bf(acc[i][j][r]);
            }
        }
    }
}

// ---------------------------------------------------------------------------
// GEMM2 (verbatim): fs2b[M,48] = h1b @ W2pad.
// ---------------------------------------------------------------------------
__global__ __launch_bounds__(256) void mfma_gemm2(const unsigned short* __restrict__ h1b,
                                                  const unsigned short* __restrict__ bfrag,
                                                  unsigned short* __restrict__ fs2b) {
    const int w = threadIdx.x >> 6;
    const int l = threadIdx.x & 63;
    const int bm = blockIdx.x * 128;
    const int lm = l & 15, lk = l >> 4;

    floatx4 acc[2][3];
#pragma unroll
    for (int i = 0; i < 2; i++)
#pragma unroll
        for (int j = 0; j < 3; j++) acc[i][j] = (floatx4){0.f, 0.f, 0.f, 0.f};

#pragma unroll
    for (int kk = 0; kk < 8; kk++) {
        const unsigned short* abase = h1b + (size_t)(bm + w * 32 + lm) * 256 + kk * 32 + lk * 8;
        short8 a0 = *(const short8*)(abase);
        short8 a1 = *(const short8*)(abase + 16 * 256);
        const unsigned short* bbase = bfrag + (size_t)(kk * 64 + l) * 8;
        short8 b[3];
#pragma unroll
        for (int j = 0; j < 3; j++) b[j] = *(const short8*)(bbase + j * (8 * 64 * 8));
#pragma unroll
        for (int j = 0; j < 3; j++) {
            acc[0][j] = __builtin_amdgcn_mfma_f32_16x16x32_bf16(a0, b[j], acc[0][j], 0, 0, 0);
            acc[1][j] = __builtin_amdgcn_mfma_f32_16x16x32_bf16(a1, b[j], acc[1][j], 0, 0, 0);
        }
    }
#pragma unroll
    for (int i = 0; i < 2; i++) {
        int row0 = bm + w * 32 + i * 16 + lk * 4;
#pragma unroll
        for (int r = 0; r < 4; r++) {
            int row = row0 + r;
            if (row >= NNODES) continue;
#pragma unroll
            for (int j = 0; j < 3; j++) {
                int col = j * 16 + lm;
                fs2b[(size_t)row * 48 + col] = f2bf(acc[i][j][r]);
            }
        }
    }
}

// ---------------------------------------------------------------------------
// Layer-1 logits (verbatim). One block per node, wave = head.
// ---------------------------------------------------------------------------
__global__ __launch_bounds__(256) void logits1(const unsigned short* __restrict__ fs1b,
                                               const float* __restrict__ al,
                                               const float* __restrict__ ar,
                                               float* __restrict__ el,
                                               float* __restrict__ er) {
    int n = blockIdx.x;
    int tid = threadIdx.x;
    int h = tid >> 6, d = tid & 63;
    float v = bf2f(fs1b[(size_t)n * 256 + tid]);
    float pa = v * al[h * 64 + d];
    float pb = v * ar[h * 64 + d];
    for (int off = 32; off > 0; off >>= 1) {
        pa += __shfl_down(pa, off);
        pb += __shfl_down(pb, off);
    }
    if (d == 0) { el[n * 4 + h] = pa; er[n * 4 + h] = pb; }
}

// ---------------------------------------------------------------------------
// Layer-1 softmax + aggregate — wave per node. CHANGE vs R9: deg<=64 fast
// path uses single-exp softmax (lane owns one edge: butterfly-max -> one
// exp/lane/head -> butterfly-sum; weights in-register, no phase-2 regather,
// no online-merge exps). deg>64 falls back to R9's online+butterfly + per-
// edge recompute (correct for any deg). Pass B identical to R9.
// ---------------------------------------------------------------------------
__global__ __launch_bounds__(256) void agg1(const int* __restrict__ row_ptr,
                                            const int* __restrict__ src,
                                            const float* __restrict__ el,
                                            const float* __restrict__ er,
                                            const unsigned short* __restrict__ fs1b,
                                            const float* __restrict__ b1,
                                            unsigned short* __restrict__ h1b) {
    __shared__ float wcache[4][CAPW * 4];
    __shared__ int   scache[4][CAPW];
    const int q = threadIdx.x >> 6;
    const int l = threadIdx.x & 63;
    const int n = blockIdx.x * 4 + q;          // 12500*4 == NNODES exactly
    const int start = row_ptr[n], end = row_ptr[n + 1];
    const int deg = end - start;

    const float4 erv = *(const float4*)(er + n * 4);
    const int sub = l >> 5, c = l & 31, hl = c >> 3;
    float a[8] = {};

    if (deg <= CAPW) {
        // ---- fast path: one edge per lane, single exp per head ----
        const bool act = l < deg;
        int sv = 0;
        float e0 = -1e30f, e1 = -1e30f, e2 = -1e30f, e3 = -1e30f;
        if (act) {
            sv = src[start + l];
            float4 e4 = *(const float4*)(el + sv * 4);
            e0 = lrelu(e4.x + erv.x);
            e1 = lrelu(e4.y + erv.y);
            e2 = lrelu(e4.z + erv.z);
            e3 = lrelu(e4.w + erv.w);
        }
        float M0 = e0, M1 = e1, M2 = e2, M3 = e3;
#pragma unroll
        for (int off = 32; off > 0; off >>= 1) {
            M0 = fmaxf(M0, __shfl_xor(M0, off));
            M1 = fmaxf(M1, __shfl_xor(M1, off));
            M2 = fmaxf(M2, __shfl_xor(M2, off));
            M3 = fmaxf(M3, __shfl_xor(M3, off));
        }
        float w0 = act ? __expf(e0 - M0) : 0.f;
        float w1 = act ? __expf(e1 - M1) : 0.f;
        float w2 = act ? __expf(e2 - M2) : 0.f;
        float w3 = act ? __expf(e3 - M3) : 0.f;
        float S0 = w0, S1 = w1, S2 = w2, S3 = w3;
#pragma unroll
        for (int off = 32; off > 0; off >>= 1) {
            S0 += __shfl_xor(S0, off);
            S1 += __shfl_xor(S1, off);
            S2 += __shfl_xor(S2, off);
            S3 += __shfl_xor(S3, off);
        }
        const float rs0 = deg > 0 ? 1.f / S0 : 0.f;
        const float rs1 = deg > 0 ? 1.f / S1 : 0.f;
        const float rs2 = deg > 0 ? 1.f / S2 : 0.f;
        const float rs3 = deg > 0 ? 1.f / S3 : 0.f;
        if (act) {
            scache[q][l] = sv;
            *(float4*)(&wcache[q][l * 4]) =
                make_float4(w0 * rs0, w1 * rs1, w2 * rs2, w3 * rs3);
        }
        for (int j = sub; j < deg; j += 2) {
            int svj = scache[q][j];
            float wv = wcache[q][j * 4 + hl];
            uint4 g = *(const uint4*)(fs1b + (size_t)svj * 256 + c * 8);
            a[0] += wv * bf2f(g.x & 0xFFFFu); a[1] += wv * bf2f(g.x >> 16);
            a[2] += wv * bf2f(g.y & 0xFFFFu); a[3] += wv * bf2f(g.y >> 16);
            a[4] += wv * bf2f(g.z & 0xFFFFu); a[5] += wv * bf2f(g.z >> 16);
            a[6] += wv * bf2f(g.w & 0xFFFFu); a[7] += wv * bf2f(g.w >> 16);
        }
    } else {
        // ---- slow path (deg > 64): R9's online phase 1 + per-edge recompute ----
        float m0 = -1e30f, m1 = -1e30f, m2 = -1e30f, m3 = -1e30f;
        float s0 = 0.f, s1 = 0.f, s2 = 0.f, s3 = 0.f;
        for (int i = start + l; i < end; i += 64) {
            float4 e4 = *(const float4*)(el + src[i] * 4);
            float e;
            e = lrelu(e4.x + erv.x); { float nm = fmaxf(m0, e); s0 = s0 * __expf(m0 - nm) + __expf(e - nm); m0 = nm; }
            e = lrelu(e4.y + erv.y); { float nm = fmaxf(m1, e); s1 = s1 * __expf(m1 - nm) + __expf(e - nm); m1 = nm; }
            e = lrelu(e4.z + erv.z); { float nm = fmaxf(m2, e); s2 = s2 * __expf(m2 - nm) + __expf(e - nm); m2 = nm; }
            e = lrelu(e4.w + erv.w); { float nm = fmaxf(m3, e); s3 = s3 * __expf(m3 - nm) + __expf(e - nm); m3 = nm; }
        }
        for (int off = 32; off > 0; off >>= 1) {
            float mo, so, nm;
            mo = __shfl_xor(m0, off); so = __shfl_xor(s0, off);
            nm = fmaxf(m0, mo); s0 = s0 * __expf(m0 - nm) + so * __expf(mo - nm); m0 = nm;
            mo = __shfl_xor(m1, off); so = __shfl_xor(s1, off);
            nm = fmaxf(m1, mo); s1 = s1 * __expf(m1 - nm) + so * __expf(mo - nm); m1 = nm;
            mo = __shfl_xor(m2, off); so = __shfl_xor(s2, off);
            nm = fmaxf(m2, mo); s2 = s2 * __expf(m2 - nm) + so * __expf(mo - nm); m2 = nm;
            mo = __shfl_xor(m3, off); so = __shfl_xor(s3, off);
            nm = fmaxf(m3, mo); s3 = s3 * __expf(m3 - nm) + so * __expf(mo - nm); m3 = nm;
        }
        const float Mh  = hl == 0 ? m0 : hl == 1 ? m1 : hl == 2 ? m2 : m3;
        const float Sh  = hl == 0 ? s0 : hl == 1 ? s1 : hl == 2 ? s2 : s3;
        const float rsh = deg > 0 ? 1.f / Sh : 0.f;
        const float ervh = hl == 0 ? erv.x : hl == 1 ? erv.y : hl == 2 ? erv.z : erv.w;
        for (int j = sub; j < deg; j += 2) {
            int svj = src[start + j];
            float e = lrelu(el[svj * 4 + hl] + ervh);
            float wv = __expf(e - Mh) * rsh;
            uint4 g = *(const uint4*)(fs1b + (size_t)svj * 256 + c * 8);
            a[0] += wv * bf2f(g.x & 0xFFFFu); a[1] += wv * bf2f(g.x >> 16);
            a[2] += wv * bf2f(g.y & 0xFFFFu); a[3] += wv * bf2f(g.y >> 16);
            a[4] += wv * bf2f(g.z & 0xFFFFu); a[5] += wv * bf2f(g.z >> 16);
            a[6] += wv * bf2f(g.w & 0xFFFFu); a[7] += wv * bf2f(g.w >> 16);
        }
    }
#pragma unroll
    for (int j = 0; j < 8; j++) a[j] += __shfl_xor(a[j], 32);
    if (sub == 0) {
        float4 bA = *(const float4*)(b1 + c * 8);
        float4 bB = *(const float4*)(b1 + c * 8 + 4);
        float v0 = fmaxf(a[0] + bA.x, 0.f), v1 = fmaxf(a[1] + bA.y, 0.f);
        float v2 = fmaxf(a[2] + bA.z, 0.f), v3 = fmaxf(a[3] + bA.w, 0.f);
        float v4 = fmaxf(a[4] + bB.x, 0.f), v5 = fmaxf(a[5] + bB.y, 0.f);
        float v6 = fmaxf(a[6] + bB.z, 0.f), v7 = fmaxf(a[7] + bB.w, 0.f);
        uint4 o;
        o.x = (unsigned)f2bf(v0) | ((unsigned)f2bf(v1) << 16);
        o.y = (unsigned)f2bf(v2) | ((unsigned)f2bf(v3) << 16);
        o.z = (unsigned)f2bf(v4) | ((unsigned)f2bf(v5) << 16);
        o.w = (unsigned)f2bf(v6) | ((unsigned)f2bf(v7) << 16);
        *(uint4*)(h1b + (size_t)n * 256 + c * 8) = o;
    }
}

// ---------------------------------------------------------------------------
// Layer-2 logits (verbatim). Wave per node (4 nodes/block).
// ---------------------------------------------------------------------------
__global__ __launch_bounds__(256) void logits2(const unsigned short* __restrict__ fs2b,
                                               const float* __restrict__ al,
                                               const float* __restrict__ ar,
                                               float* __restrict__ el,
                                               float* __restrict__ er) {
    int l = threadIdx.x & 63;
    int n = blockIdx.x * 4 + (threadIdx.x >> 6);
    if (n >= NNODES) return;
    float pa = 0.f, pb = 0.f;
    if (l < 24) {
        unsigned int q = *(const unsigned int*)(fs2b + (size_t)n * 48 + l * 2);
        float v0 = bf2f(q & 0xFFFFu), v1 = bf2f(q >> 16);
        float a1 = (l * 2 + 1 < 47) ? al[l * 2 + 1] : 0.f;
        float r1 = (l * 2 + 1 < 47) ? ar[l * 2 + 1] : 0.f;
        pa = v0 * al[l * 2] + v1 * a1;
        pb = v0 * ar[l * 2] + v1 * r1;
    }
    for (int off = 32; off > 0; off >>= 1) {
        pa += __shfl_down(pa, off);
        pb += __shfl_down(pb, off);
    }
    if (l == 0) { el[n] = pa; er[n] = pb; }
}

// ---------------------------------------------------------------------------
// Layer-2 softmax + aggregate — wave per node, single-exp fast path
// (mirror of agg1's change). Pass B identical to R9.
// ---------------------------------------------------------------------------
__global__ __launch_bounds__(256) void agg2(const int* __restrict__ row_ptr,
                                            const int* __restrict__ src,
                                            const float* __restrict__ el,
                                            const float* __restrict__ er,
                                            const unsigned short* __restrict__ fs2b,
                                            const float* __restrict__ b2,
                                            float* __restrict__ out) {
    __shared__ float wcache[4][CAPW];
    __shared__ int   scache[4][CAPW];
    const int q = threadIdx.x >> 6;
    const int l = threadIdx.x & 63;
    const int n = blockIdx.x * 4 + q;
    const int start = row_ptr[n], end = row_ptr[n + 1];
    const int deg = end - start;
    const float erv = er[n];

    const int sub = l >> 5, c = l & 31;
    float a0 = 0.f, a1 = 0.f;

    if (deg <= CAPW) {
        // ---- fast path: one edge per lane, single exp ----
        const bool act = l < deg;
        int sv = 0;
        float e = -1e30f;
        if (act) {
            sv = src[start + l];
            e = lrelu(el[sv] + erv);
        }
        float M = e;
#pragma unroll
        for (int off = 32; off > 0; off >>= 1) M = fmaxf(M, __shfl_xor(M, off));
        float w = act ? __expf(e - M) : 0.f;
        float S = w;
#pragma unroll
        for (int off = 32; off > 0; off >>= 1) S += __shfl_xor(S, off);
        const float rs = deg > 0 ? 1.f / S : 0.f;
        if (act) {
            scache[q][l] = sv;
            wcache[q][l] = w * rs;
        }
        for (int j = sub; j < deg; j += 2) {
            int svj = scache[q][j];
            float wv = wcache[q][j];
            if (c < 24) {
                unsigned int g = *(const unsigned int*)(fs2b + (size_t)svj * 48 + c * 2);
                a0 += wv * bf2f(g & 0xFFFFu);
                a1 += wv * bf2f(g >> 16);
            }
        }
    } else {
        // ---- slow path (deg > 64): online phase 1 + per-edge recompute ----
        float m = -1e30f, s = 0.f;
        for (int i = start + l; i < end; i += 64) {
            float e = lrelu(el[src[i]] + erv);
            float nm = fmaxf(m, e);
            s = s * __expf(m - nm) + __expf(e - nm);
            m = nm;
        }
        for (int off = 32; off > 0; off >>= 1) {
            float mo = __shfl_xor(m, off), so = __shfl_xor(s, off);
            float nm = fmaxf(m, mo);
            s = s * __expf(m - nm) + so * __expf(mo - nm);
            m = nm;
        }
        const float rs = deg > 0 ? 1.f / s : 0.f;
        for (int j = sub; j < deg; j += 2) {
            int svj = src[start + j];
            float wv = __expf(lrelu(el[svj] + erv) - m) * rs;
            if (c < 24) {
                unsigned int g = *(const unsigned int*)(fs2b + (size_t)svj * 48 + c * 2);
                a0 += wv * bf2f(g & 0xFFFFu);
                a1 += wv * bf2f(g >> 16);
            }
        }
    }
    a0 += __shfl_xor(a0, 32);
    a1 += __shfl_xor(a1, 32);
    if (sub == 0 && c < 24) {
        int ch = c * 2;
        out[(size_t)n * 47 + ch] = a0 + b2[ch];
        if (ch + 1 < 47) out[(size_t)n * 47 + ch + 1] = a1 + b2[ch + 1];
    }
}

// ---------------------------------------------------------------------------
// Launch. Inputs: 0:x 1:W1 2:al1 3:ar1 4:b1 5:W2 6:al2 7:ar2 8:b2 9:src 10:dst
// ---------------------------------------------------------------------------
extern "C" void kernel_launch(void* const* d_in, const int* in_sizes, int n_in,
                              void* d_out, int out_size, void* d_ws, size_t ws_size,
                              hipStream_t stream) {
    const float* x   = (const float*)d_in[0];
    const float* W1  = (const float*)d_in[1];
    const float* al1 = (const float*)d_in[2];
    const float* ar1 = (const float*)d_in[3];
    const float* b1  = (const float*)d_in[4];
    const float* W2  = (const float*)d_in[5];
    const float* al2 = (const float*)d_in[6];
    const float* ar2 = (const float*)d_in[7];
    const float* b2  = (const float*)d_in[8];
    const int*   src = (const int*)d_in[9];
    const int*   dst = (const int*)d_in[10];
    float* out = (float*)d_out;

    char* ws = (char*)d_ws;
    size_t off = 0;
    auto alloc = [&](size_t bytes) {
        void* p = ws + off;
        off += (bytes + 255) & ~(size_t)255;
        return p;
    };
    int*            row_ptr = (int*)alloc((NNODES + 1) * sizeof(int));
    unsigned short* xb      = (unsigned short*)alloc((size_t)MPAD * 256 * 2);
    unsigned short* bfrag1  = (unsigned short*)alloc(16 * 8 * 64 * 8 * 2);
    unsigned short* bfrag2  = (unsigned short*)alloc(3 * 8 * 64 * 8 * 2);
    unsigned short* fs1b    = (unsigned short*)alloc((size_t)NNODES * 256 * 2);
    unsigned short* h1b     = (unsigned short*)alloc((size_t)MPAD * 256 * 2);
    unsigned short* fs2b    = (unsigned short*)alloc((size_t)NNODES * 48 * 2);
    float*          el1     = (float*)alloc((size_t)NNODES * 4 * sizeof(float));
    float*          er1     = (float*)alloc((size_t)NNODES * 4 * sizeof(float));
    float*          el2     = (float*)alloc((size_t)NNODES * sizeof(float));
    float*          er2     = (float*)alloc((size_t)NNODES * sizeof(float));
    (void)ws_size; (void)n_in; (void)in_sizes; (void)out_size;

    prep<<<12794, 256, 0, stream>>>(x, W1, W2, dst, xb, bfrag1, bfrag2, h1b, row_ptr);

    // Layer 1
    mfma_gemm1<<<dim3(MPAD / 128, 4), 256, 0, stream>>>(xb, bfrag1, fs1b);
    logits1<<<NNODES, 256, 0, stream>>>(fs1b, al1, ar1, el1, er1);
    agg1<<<NNODES / 4, 256, 0, stream>>>(row_ptr, src, el1, er1, fs1b, b1, h1b);

    // Layer 2
    mfma_gemm2<<<MPAD / 128, 256, 0, stream>>>(h1b, bfrag2, fs2b);
    logits2<<<(NNODES + 3) / 4, 256, 0, stream>>>(fs2b, al2, ar2, el2, er2);
    agg2<<<NNODES / 4, 256, 0, stream>>>(row_ptr, src, el2, er2, fs2b, b2, out);
}

// Round 11
// 265.714 us; speedup vs baseline: 2.2776x; 1.1092x over previous
//
#include <hip/hip_runtime.h>
#include <math.h>

#define NNODES 50000
#define NEDGES 800000
#define NEG_SLOPE 0.2f
#define MPAD 50048   // 391 * 128
#define CAPW 64      // fast path: deg <= 64, one edge per lane

typedef __attribute__((ext_vector_type(8))) short short8;
typedef __attribute__((ext_vector_type(4))) float floatx4;

// bf16 helpers (RNE)
__device__ __forceinline__ unsigned short f2bf(float f) {
    union { float f; unsigned int u; } v; v.f = f;
    unsigned int r = v.u + 0x7FFFu + ((v.u >> 16) & 1u);
    return (unsigned short)(r >> 16);
}
__device__ __forceinline__ float bf2f(unsigned int s) {
    union { unsigned int u; float f; } v; v.u = s << 16; return v.f;
}
__device__ __forceinline__ float lrelu(float e) { return e > 0.f ? e : NEG_SLOPE * e; }

// ---------------------------------------------------------------------------
// prep: merged prologue (verified R7-R10).
// ---------------------------------------------------------------------------
__global__ __launch_bounds__(256) void prep(const float* __restrict__ x,
                                            const float* __restrict__ W1,
                                            const float* __restrict__ W2,
                                            const int* __restrict__ dst,
                                            unsigned short* __restrict__ xb,
                                            unsigned short* __restrict__ bfrag1,
                                            unsigned short* __restrict__ bfrag2,
                                            unsigned short* __restrict__ h1b,
                                            int* __restrict__ row_ptr) {
    int b = blockIdx.x;
    if (b < 12512) {
        long e = ((long)b * 256 + threadIdx.x) * 4;
        const long NE = (long)NNODES * 256;
        ushort4 o;
        o.x = (e + 0 < NE) ? f2bf(x[e + 0]) : 0;
        o.y = (e + 1 < NE) ? f2bf(x[e + 1]) : 0;
        o.z = (e + 2 < NE) ? f2bf(x[e + 2]) : 0;
        o.w = (e + 3 < NE) ? f2bf(x[e + 3]) : 0;
        *(ushort4*)(xb + e) = o;
    } else if (b < 12708) {
        int n = (b - 12512) * 256 + threadIdx.x;
        if (n > NNODES) return;
        int lo = 0, hi = NEDGES;
        while (lo < hi) {
            int mid = (lo + hi) >> 1;
            if (dst[mid] < n) lo = mid + 1; else hi = mid;
        }
        row_ptr[n] = lo;
    } else if (b < 12740) {
        int c = (b - 12708) * 256 + threadIdx.x;   // 8192 chunks
        int l = c & 63, kk = (c >> 6) & 7, t = c >> 9;
        int n = t * 16 + (l & 15);
        int kbase = kk * 32 + (l >> 4) * 8;
#pragma unroll
        for (int j = 0; j < 8; j++)
            bfrag1[c * 8 + j] = f2bf(W1[(kbase + j) * 256 + n]);
    } else if (b < 12746) {
        int c = (b - 12740) * 256 + threadIdx.x;   // 1536 chunks
        int l = c & 63, kk = (c >> 6) & 7, t = c >> 9;
        int n = t * 16 + (l & 15);
        int kbase = kk * 32 + (l >> 4) * 8;
#pragma unroll
        for (int j = 0; j < 8; j++)
            bfrag2[c * 8 + j] = (n < 47) ? f2bf(W2[(kbase + j) * 47 + n]) : 0;
    } else {
        int row = NNODES + (b - 12746);
        h1b[(size_t)row * 256 + threadIdx.x] = 0;
    }
}

// ---------------------------------------------------------------------------
// GEMM1 + FUSED logits1 (the change vs R10). fs1b[M,256] = xb @ W1; then
// el/er for head = blockIdx.y from the bf16-ROUNDED accumulators, so el/er
// match a separate read-back of fs1b except for fp32 summation order (~1e-6).
// D layout: col = j*16 + lm, row = lk*4 + r  (lm=l&15, lk=l>>4).
// ---------------------------------------------------------------------------
__global__ __launch_bounds__(256) void mfma_gemm1(const unsigned short* __restrict__ xb,
                                                  const unsigned short* __restrict__ bfrag,
                                                  const float* __restrict__ al1,
                                                  const float* __restrict__ ar1,
                                                  unsigned short* __restrict__ fs1b,
                                                  float* __restrict__ el,
                                                  float* __restrict__ er) {
    const int w = threadIdx.x >> 6;
    const int l = threadIdx.x & 63;
    const int bm = blockIdx.x * 128;
    const int head = blockIdx.y;
    const int n0 = head * 64;
    const int lm = l & 15, lk = l >> 4;

    floatx4 acc[2][4];
#pragma unroll
    for (int i = 0; i < 2; i++)
#pragma unroll
        for (int j = 0; j < 4; j++) acc[i][j] = (floatx4){0.f, 0.f, 0.f, 0.f};

    const int t0 = n0 >> 4;
#pragma unroll
    for (int kk = 0; kk < 8; kk++) {
        const unsigned short* abase = xb + (size_t)(bm + w * 32 + lm) * 256 + kk * 32 + lk * 8;
        short8 a0 = *(const short8*)(abase);
        short8 a1 = *(const short8*)(abase + 16 * 256);
        const unsigned short* bbase = bfrag + ((t0 * 8 + kk) * 64 + l) * 8;
        short8 b[4];
#pragma unroll
        for (int j = 0; j < 4; j++) b[j] = *(const short8*)(bbase + j * 8 * 64 * 8);
#pragma unroll
        for (int j = 0; j < 4; j++) {
            acc[0][j] = __builtin_amdgcn_mfma_f32_16x16x32_bf16(a0, b[j], acc[0][j], 0, 0, 0);
            acc[1][j] = __builtin_amdgcn_mfma_f32_16x16x32_bf16(a1, b[j], acc[1][j], 0, 0, 0);
        }
    }
    // store fs1b (bf16-rounded)
#pragma unroll
    for (int i = 0; i < 2; i++) {
        int row0 = bm + w * 32 + i * 16 + lk * 4;
#pragma unroll
        for (int r = 0; r < 4; r++) {
            int row = row0 + r;
            if (row >= NNODES) continue;
#pragma unroll
            for (int j = 0; j < 4; j++) {
                int col = n0 + j * 16 + lm;
                fs1b[(size_t)row * 256 + col] = f2bf(acc[i][j][r]);
            }
        }
    }
    // fused logits from the ROUNDED values
    float alv[4], arv[4];
#pragma unroll
    for (int j = 0; j < 4; j++) {
        alv[j] = al1[head * 64 + j * 16 + lm];
        arv[j] = ar1[head * 64 + j * 16 + lm];
    }
#pragma unroll
    for (int i = 0; i < 2; i++) {
#pragma unroll
        for (int r = 0; r < 4; r++) {
            float pe = 0.f, pr = 0.f;
#pragma unroll
            for (int j = 0; j < 4; j++) {
                float fr = bf2f(f2bf(acc[i][j][r]));
                pe += fr * alv[j];
                pr += fr * arv[j];
            }
#pragma unroll
            for (int off = 1; off < 16; off <<= 1) {
                pe += __shfl_xor(pe, off);
                pr += __shfl_xor(pr, off);
            }
            int row = bm + w * 32 + i * 16 + lk * 4 + r;
            if (lm == 0 && row < NNODES) {
                el[row * 4 + head] = pe;
                er[row * 4 + head] = pr;
            }
        }
    }
}

// ---------------------------------------------------------------------------
// GEMM2 + FUSED logits2 (the change vs R10). fs2b[M,48] = h1b @ W2pad;
// single-head logits from bf16-rounded accumulators.
// ---------------------------------------------------------------------------
__global__ __launch_bounds__(256) void mfma_gemm2(const unsigned short* __restrict__ h1b,
                                                  const unsigned short* __restrict__ bfrag,
                                                  const float* __restrict__ al2,
                                                  const float* __restrict__ ar2,
                                                  unsigned short* __restrict__ fs2b,
                                                  float* __restrict__ el,
                                                  float* __restrict__ er) {
    const int w = threadIdx.x >> 6;
    const int l = threadIdx.x & 63;
    const int bm = blockIdx.x * 128;
    const int lm = l & 15, lk = l >> 4;

    floatx4 acc[2][3];
#pragma unroll
    for (int i = 0; i < 2; i++)
#pragma unroll
        for (int j = 0; j < 3; j++) acc[i][j] = (floatx4){0.f, 0.f, 0.f, 0.f};

#pragma unroll
    for (int kk = 0; kk < 8; kk++) {
        const unsigned short* abase = h1b + (size_t)(bm + w * 32 + lm) * 256 + kk * 32 + lk * 8;
        short8 a0 = *(const short8*)(abase);
        short8 a1 = *(const short8*)(abase + 16 * 256);
        const unsigned short* bbase = bfrag + (size_t)(kk * 64 + l) * 8;
        short8 b[3];
#pragma unroll
        for (int j = 0; j < 3; j++) b[j] = *(const short8*)(bbase + j * (8 * 64 * 8));
#pragma unroll
        for (int j = 0; j < 3; j++) {
            acc[0][j] = __builtin_amdgcn_mfma_f32_16x16x32_bf16(a0, b[j], acc[0][j], 0, 0, 0);
            acc[1][j] = __builtin_amdgcn_mfma_f32_16x16x32_bf16(a1, b[j], acc[1][j], 0, 0, 0);
        }
    }
#pragma unroll
    for (int i = 0; i < 2; i++) {
        int row0 = bm + w * 32 + i * 16 + lk * 4;
#pragma unroll
        for (int r = 0; r < 4; r++) {
            int row = row0 + r;
            if (row >= NNODES) continue;
#pragma unroll
            for (int j = 0; j < 3; j++) {
                int col = j * 16 + lm;
                fs2b[(size_t)row * 48 + col] = f2bf(acc[i][j][r]);
            }
        }
    }
    float alv[3], arv[3];
#pragma unroll
    for (int j = 0; j < 3; j++) {
        int col = j * 16 + lm;
        alv[j] = (col < 47) ? al2[col] : 0.f;
        arv[j] = (col < 47) ? ar2[col] : 0.f;
    }
#pragma unroll
    for (int i = 0; i < 2; i++) {
#pragma unroll
        for (int r = 0; r < 4; r++) {
            float pe = 0.f, pr = 0.f;
#pragma unroll
            for (int j = 0; j < 3; j++) {
                float fr = bf2f(f2bf(acc[i][j][r]));
                pe += fr * alv[j];
                pr += fr * arv[j];
            }
#pragma unroll
            for (int off = 1; off < 16; off <<= 1) {
                pe += __shfl_xor(pe, off);
                pr += __shfl_xor(pr, off);
            }
            int row = bm + w * 32 + i * 16 + lk * 4 + r;
            if (lm == 0 && row < NNODES) {
                el[row] = pe;
                er[row] = pr;
            }
        }
    }
}

// ---------------------------------------------------------------------------
// Layer-1 softmax + aggregate — wave per node, single-exp fast path
// (verbatim from R10, verified).
// ---------------------------------------------------------------------------
__global__ __launch_bounds__(256) void agg1(const int* __restrict__ row_ptr,
                                            const int* __restrict__ src,
                                            const float* __restrict__ el,
                                            const float* __restrict__ er,
                                            const unsigned short* __restrict__ fs1b,
                                            const float* __restrict__ b1,
                                            unsigned short* __restrict__ h1b) {
    __shared__ float wcache[4][CAPW * 4];
    __shared__ int   scache[4][CAPW];
    const int q = threadIdx.x >> 6;
    const int l = threadIdx.x & 63;
    const int n = blockIdx.x * 4 + q;          // 12500*4 == NNODES exactly
    const int start = row_ptr[n], end = row_ptr[n + 1];
    const int deg = end - start;

    const float4 erv = *(const float4*)(er + n * 4);
    const int sub = l >> 5, c = l & 31, hl = c >> 3;
    float a[8] = {};

    if (deg <= CAPW) {
        const bool act = l < deg;
        int sv = 0;
        float e0 = -1e30f, e1 = -1e30f, e2 = -1e30f, e3 = -1e30f;
        if (act) {
            sv = src[start + l];
            float4 e4 = *(const float4*)(el + sv * 4);
            e0 = lrelu(e4.x + erv.x);
            e1 = lrelu(e4.y + erv.y);
            e2 = lrelu(e4.z + erv.z);
            e3 = lrelu(e4.w + erv.w);
        }
        float M0 = e0, M1 = e1, M2 = e2, M3 = e3;
#pragma unroll
        for (int off = 32; off > 0; off >>= 1) {
            M0 = fmaxf(M0, __shfl_xor(M0, off));
            M1 = fmaxf(M1, __shfl_xor(M1, off));
            M2 = fmaxf(M2, __shfl_xor(M2, off));
            M3 = fmaxf(M3, __shfl_xor(M3, off));
        }
        float w0 = act ? __expf(e0 - M0) : 0.f;
        float w1 = act ? __expf(e1 - M1) : 0.f;
        float w2 = act ? __expf(e2 - M2) : 0.f;
        float w3 = act ? __expf(e3 - M3) : 0.f;
        float S0 = w0, S1 = w1, S2 = w2, S3 = w3;
#pragma unroll
        for (int off = 32; off > 0; off >>= 1) {
            S0 += __shfl_xor(S0, off);
            S1 += __shfl_xor(S1, off);
            S2 += __shfl_xor(S2, off);
            S3 += __shfl_xor(S3, off);
        }
        const float rs0 = deg > 0 ? 1.f / S0 : 0.f;
        const float rs1 = deg > 0 ? 1.f / S1 : 0.f;
        const float rs2 = deg > 0 ? 1.f / S2 : 0.f;
        const float rs3 = deg > 0 ? 1.f / S3 : 0.f;
        if (act) {
            scache[q][l] = sv;
            *(float4*)(&wcache[q][l * 4]) =
                make_float4(w0 * rs0, w1 * rs1, w2 * rs2, w3 * rs3);
        }
        for (int j = sub; j < deg; j += 2) {
            int svj = scache[q][j];
            float wv = wcache[q][j * 4 + hl];
            uint4 g = *(const uint4*)(fs1b + (size_t)svj * 256 + c * 8);
            a[0] += wv * bf2f(g.x & 0xFFFFu); a[1] += wv * bf2f(g.x >> 16);
            a[2] += wv * bf2f(g.y & 0xFFFFu); a[3] += wv * bf2f(g.y >> 16);
            a[4] += wv * bf2f(g.z & 0xFFFFu); a[5] += wv * bf2f(g.z >> 16);
            a[6] += wv * bf2f(g.w & 0xFFFFu); a[7] += wv * bf2f(g.w >> 16);
        }
    } else {
        float m0 = -1e30f, m1 = -1e30f, m2 = -1e30f, m3 = -1e30f;
        float s0 = 0.f, s1 = 0.f, s2 = 0.f, s3 = 0.f;
        for (int i = start + l; i < end; i += 64) {
            float4 e4 = *(const float4*)(el + src[i] * 4);
            float e;
            e = lrelu(e4.x + erv.x); { float nm = fmaxf(m0, e); s0 = s0 * __expf(m0 - nm) + __expf(e - nm); m0 = nm; }
            e = lrelu(e4.y + erv.y); { float nm = fmaxf(m1, e); s1 = s1 * __expf(m1 - nm) + __expf(e - nm); m1 = nm; }
            e = lrelu(e4.z + erv.z); { float nm = fmaxf(m2, e); s2 = s2 * __expf(m2 - nm) + __expf(e - nm); m2 = nm; }
            e = lrelu(e4.w + erv.w); { float nm = fmaxf(m3, e); s3 = s3 * __expf(m3 - nm) + __expf(e - nm); m3 = nm; }
        }
        for (int off = 32; off > 0; off >>= 1) {
            float mo, so, nm;
            mo = __shfl_xor(m0, off); so = __shfl_xor(s0, off);
            nm = fmaxf(m0, mo); s0 = s0 * __expf(m0 - nm) + so * __expf(mo - nm); m0 = nm;
            mo = __shfl_xor(m1, off); so = __shfl_xor(s1, off);
            nm = fmaxf(m1, mo); s1 = s1 * __expf(m1 - nm) + so * __expf(mo - nm); m1 = nm;
            mo = __shfl_xor(m2, off); so = __shfl_xor(s2, off);
            nm = fmaxf(m2, mo); s2 = s2 * __expf(m2 - nm) + so * __expf(mo - nm); m2 = nm;
            mo = __shfl_xor(m3, off); so = __shfl_xor(s3, off);
            nm = fmaxf(m3, mo); s3 = s3 * __expf(m3 - nm) + so * __expf(mo - nm); m3 = nm;
        }
        const float Mh  = hl == 0 ? m0 : hl == 1 ? m1 : hl == 2 ? m2 : m3;
        const float Sh  = hl == 0 ? s0 : hl == 1 ? s1 : hl == 2 ? s2 : s3;
        const float rsh = deg > 0 ? 1.f / Sh : 0.f;
        const float ervh = hl == 0 ? erv.x : hl == 1 ? erv.y : hl == 2 ? erv.z : erv.w;
        for (int j = sub; j < deg; j += 2) {
            int svj = src[start + j];
            float e = lrelu(el[svj * 4 + hl] + ervh);
            float wv = __expf(e - Mh) * rsh;
            uint4 g = *(const uint4*)(fs1b + (size_t)svj * 256 + c * 8);
            a[0] += wv * bf2f(g.x & 0xFFFFu); a[1] += wv * bf2f(g.x >> 16);
            a[2] += wv * bf2f(g.y & 0xFFFFu); a[3] += wv * bf2f(g.y >> 16);
            a[4] += wv * bf2f(g.z & 0xFFFFu); a[5] += wv * bf2f(g.z >> 16);
            a[6] += wv * bf2f(g.w & 0xFFFFu); a[7] += wv * bf2f(g.w >> 16);
        }
    }
#pragma unroll
    for (int j = 0; j < 8; j++) a[j] += __shfl_xor(a[j], 32);
    if (sub == 0) {
        float4 bA = *(const float4*)(b1 + c * 8);
        float4 bB = *(const float4*)(b1 + c * 8 + 4);
        float v0 = fmaxf(a[0] + bA.x, 0.f), v1 = fmaxf(a[1] + bA.y, 0.f);
        float v2 = fmaxf(a[2] + bA.z, 0.f), v3 = fmaxf(a[3] + bA.w, 0.f);
        float v4 = fmaxf(a[4] + bB.x, 0.f), v5 = fmaxf(a[5] + bB.y, 0.f);
        float v6 = fmaxf(a[6] + bB.z, 0.f), v7 = fmaxf(a[7] + bB.w, 0.f);
        uint4 o;
        o.x = (unsigned)f2bf(v0) | ((unsigned)f2bf(v1) << 16);
        o.y = (unsigned)f2bf(v2) | ((unsigned)f2bf(v3) << 16);
        o.z = (unsigned)f2bf(v4) | ((unsigned)f2bf(v5) << 16);
        o.w = (unsigned)f2bf(v6) | ((unsigned)f2bf(v7) << 16);
        *(uint4*)(h1b + (size_t)n * 256 + c * 8) = o;
    }
}

// ---------------------------------------------------------------------------
// Layer-2 softmax + aggregate — wave per node, single-exp fast path
// (verbatim from R10, verified).
// ---------------------------------------------------------------------------
__global__ __launch_bounds__(256) void agg2(const int* __restrict__ row_ptr,
                                            const int* __restrict__ src,
                                            const float* __restrict__ el,
                                            const float* __restrict__ er,
                                            const unsigned short* __restrict__ fs2b,
                                            const float* __restrict__ b2,
                                            float* __restrict__ out) {
    __shared__ float wcache[4][CAPW];
    __shared__ int   scache[4][CAPW];
    const int q = threadIdx.x >> 6;
    const int l = threadIdx.x & 63;
    const int n = blockIdx.x * 4 + q;
    const int start = row_ptr[n], end = row_ptr[n + 1];
    const int deg = end - start;
    const float erv = er[n];

    const int sub = l >> 5, c = l & 31;
    float a0 = 0.f, a1 = 0.f;

    if (deg <= CAPW) {
        const bool act = l < deg;
        int sv = 0;
        float e = -1e30f;
        if (act) {
            sv = src[start + l];
            e = lrelu(el[sv] + erv);
        }
        float M = e;
#pragma unroll
        for (int off = 32; off > 0; off >>= 1) M = fmaxf(M, __shfl_xor(M, off));
        float w = act ? __expf(e - M) : 0.f;
        float S = w;
#pragma unroll
        for (int off = 32; off > 0; off >>= 1) S += __shfl_xor(S, off);
        const float rs = deg > 0 ? 1.f / S : 0.f;
        if (act) {
            scache[q][l] = sv;
            wcache[q][l] = w * rs;
        }
        for (int j = sub; j < deg; j += 2) {
            int svj = scache[q][j];
            float wv = wcache[q][j];
            if (c < 24) {
                unsigned int g = *(const unsigned int*)(fs2b + (size_t)svj * 48 + c * 2);
                a0 += wv * bf2f(g & 0xFFFFu);
                a1 += wv * bf2f(g >> 16);
            }
        }
    } else {
        float m = -1e30f, s = 0.f;
        for (int i = start + l; i < end; i += 64) {
            float e = lrelu(el[src[i]] + erv);
            float nm = fmaxf(m, e);
            s = s * __expf(m - nm) + __expf(e - nm);
            m = nm;
        }
        for (int off = 32; off > 0; off >>= 1) {
            float mo = __shfl_xor(m, off), so = __shfl_xor(s, off);
            float nm = fmaxf(m, mo);
            s = s * __expf(m - nm) + so * __expf(mo - nm);
            m = nm;
        }
        const float rs = deg > 0 ? 1.f / s : 0.f;
        for (int j = sub; j < deg; j += 2) {
            int svj = src[start + j];
            float wv = __expf(lrelu(el[svj] + erv) - m) * rs;
            if (c < 24) {
                unsigned int g = *(const unsigned int*)(fs2b + (size_t)svj * 48 + c * 2);
                a0 += wv * bf2f(g & 0xFFFFu);
                a1 += wv * bf2f(g >> 16);
            }
        }
    }
    a0 += __shfl_xor(a0, 32);
    a1 += __shfl_xor(a1, 32);
    if (sub == 0 && c < 24) {
        int ch = c * 2;
        out[(size_t)n * 47 + ch] = a0 + b2[ch];
        if (ch + 1 < 47) out[(size_t)n * 47 + ch + 1] = a1 + b2[ch + 1];
    }
}

// ---------------------------------------------------------------------------
// Launch. Inputs: 0:x 1:W1 2:al1 3:ar1 4:b1 5:W2 6:al2 7:ar2 8:b2 9:src 10:dst
// ---------------------------------------------------------------------------
extern "C" void kernel_launch(void* const* d_in, const int* in_sizes, int n_in,
                              void* d_out, int out_size, void* d_ws, size_t ws_size,
                              hipStream_t stream) {
    const float* x   = (const float*)d_in[0];
    const float* W1  = (const float*)d_in[1];
    const float* al1 = (const float*)d_in[2];
    const float* ar1 = (const float*)d_in[3];
    const float* b1  = (const float*)d_in[4];
    const float* W2  = (const float*)d_in[5];
    const float* al2 = (const float*)d_in[6];
    const float* ar2 = (const float*)d_in[7];
    const float* b2  = (const float*)d_in[8];
    const int*   src = (const int*)d_in[9];
    const int*   dst = (const int*)d_in[10];
    float* out = (float*)d_out;

    char* ws = (char*)d_ws;
    size_t off = 0;
    auto alloc = [&](size_t bytes) {
        void* p = ws + off;
        off += (bytes + 255) & ~(size_t)255;
        return p;
    };
    int*            row_ptr = (int*)alloc((NNODES + 1) * sizeof(int));
    unsigned short* xb      = (unsigned short*)alloc((size_t)MPAD * 256 * 2);
    unsigned short* bfrag1  = (unsigned short*)alloc(16 * 8 * 64 * 8 * 2);
    unsigned short* bfrag2  = (unsigned short*)alloc(3 * 8 * 64 * 8 * 2);
    unsigned short* fs1b    = (unsigned short*)alloc((size_t)NNODES * 256 * 2);
    unsigned short* h1b     = (unsigned short*)alloc((size_t)MPAD * 256 * 2);
    unsigned short* fs2b    = (unsigned short*)alloc((size_t)NNODES * 48 * 2);
    float*          el1     = (float*)alloc((size_t)NNODES * 4 * sizeof(float));
    float*          er1     = (float*)alloc((size_t)NNODES * 4 * sizeof(float));
    float*          el2     = (float*)alloc((size_t)NNODES * sizeof(float));
    float*          er2     = (float*)alloc((size_t)NNODES * sizeof(float));
    (void)ws_size; (void)n_in; (void)in_sizes; (void)out_size;

    prep<<<12794, 256, 0, stream>>>(x, W1, W2, dst, xb, bfrag1, bfrag2, h1b, row_ptr);

    // Layer 1 (logits fused into gemm1 epilogue)
    mfma_gemm1<<<dim3(MPAD / 128, 4), 256, 0, stream>>>(xb, bfrag1, al1, ar1, fs1b, el1, er1);
    agg1<<<NNODES / 4, 256, 0, stream>>>(row_ptr, src, el1, er1, fs1b, b1, h1b);

    // Layer 2 (logits fused into gemm2 epilogue)
    mfma_gemm2<<<MPAD / 128, 256, 0, stream>>>(h1b, bfrag2, al2, ar2, fs2b, el2, er2);
    agg2<<<NNODES / 4, 256, 0, stream>>>(row_ptr, src, el2, er2, fs2b, b2, out);
}

// Round 12
// 265.643 us; speedup vs baseline: 2.2782x; 1.0003x over previous
//
#include <hip/hip_runtime.h>
#include <math.h>

#define NNODES 50000
#define NEDGES 800000
#define NEG_SLOPE 0.2f
#define MPAD 50048   // 391 * 128
#define CAPW 64      // fast path: deg <= 64, one edge per lane

typedef __attribute__((ext_vector_type(8))) short short8;
typedef __attribute__((ext_vector_type(4))) float floatx4;

// bf16 helpers (RNE)
__device__ __forceinline__ unsigned short f2bf(float f) {
    union { float f; unsigned int u; } v; v.f = f;
    unsigned int r = v.u + 0x7FFFu + ((v.u >> 16) & 1u);
    return (unsigned short)(r >> 16);
}
__device__ __forceinline__ float bf2f(unsigned int s) {
    union { unsigned int u; float f; } v; v.u = s << 16; return v.f;
}
__device__ __forceinline__ float lrelu(float e) { return e > 0.f ? e : NEG_SLOPE * e; }

// ---------------------------------------------------------------------------
// prep: merged prologue (verified R7-R11).
// ---------------------------------------------------------------------------
__global__ __launch_bounds__(256) void prep(const float* __restrict__ x,
                                            const float* __restrict__ W1,
                                            const float* __restrict__ W2,
                                            const int* __restrict__ dst,
                                            unsigned short* __restrict__ xb,
                                            unsigned short* __restrict__ bfrag1,
                                            unsigned short* __restrict__ bfrag2,
                                            unsigned short* __restrict__ h1b,
                                            int* __restrict__ row_ptr) {
    int b = blockIdx.x;
    if (b < 12512) {
        long e = ((long)b * 256 + threadIdx.x) * 4;
        const long NE = (long)NNODES * 256;
        ushort4 o;
        o.x = (e + 0 < NE) ? f2bf(x[e + 0]) : 0;
        o.y = (e + 1 < NE) ? f2bf(x[e + 1]) : 0;
        o.z = (e + 2 < NE) ? f2bf(x[e + 2]) : 0;
        o.w = (e + 3 < NE) ? f2bf(x[e + 3]) : 0;
        *(ushort4*)(xb + e) = o;
    } else if (b < 12708) {
        int n = (b - 12512) * 256 + threadIdx.x;
        if (n > NNODES) return;
        int lo = 0, hi = NEDGES;
        while (lo < hi) {
            int mid = (lo + hi) >> 1;
            if (dst[mid] < n) lo = mid + 1; else hi = mid;
        }
        row_ptr[n] = lo;
    } else if (b < 12740) {
        int c = (b - 12708) * 256 + threadIdx.x;   // 8192 chunks
        int l = c & 63, kk = (c >> 6) & 7, t = c >> 9;
        int n = t * 16 + (l & 15);
        int kbase = kk * 32 + (l >> 4) * 8;
#pragma unroll
        for (int j = 0; j < 8; j++)
            bfrag1[c * 8 + j] = f2bf(W1[(kbase + j) * 256 + n]);
    } else if (b < 12746) {
        int c = (b - 12740) * 256 + threadIdx.x;   // 1536 chunks
        int l = c & 63, kk = (c >> 6) & 7, t = c >> 9;
        int n = t * 16 + (l & 15);
        int kbase = kk * 32 + (l >> 4) * 8;
#pragma unroll
        for (int j = 0; j < 8; j++)
            bfrag2[c * 8 + j] = (n < 47) ? f2bf(W2[(kbase + j) * 47 + n]) : 0;
    } else {
        int row = NNODES + (b - 12746);
        h1b[(size_t)row * 256 + threadIdx.x] = 0;
    }
}

// ---------------------------------------------------------------------------
// GEMM1 + fused logits1 (verified R11). el/er from bf16-rounded accumulators.
// ---------------------------------------------------------------------------
__global__ __launch_bounds__(256) void mfma_gemm1(const unsigned short* __restrict__ xb,
                                                  const unsigned short* __restrict__ bfrag,
                                                  const float* __restrict__ al1,
                                                  const float* __restrict__ ar1,
                                                  unsigned short* __restrict__ fs1b,
                                                  float* __restrict__ el,
                                                  float* __restrict__ er) {
    const int w = threadIdx.x >> 6;
    const int l = threadIdx.x & 63;
    const int bm = blockIdx.x * 128;
    const int head = blockIdx.y;
    const int n0 = head * 64;
    const int lm = l & 15, lk = l >> 4;

    floatx4 acc[2][4];
#pragma unroll
    for (int i = 0; i < 2; i++)
#pragma unroll
        for (int j = 0; j < 4; j++) acc[i][j] = (floatx4){0.f, 0.f, 0.f, 0.f};

    const int t0 = n0 >> 4;
#pragma unroll
    for (int kk = 0; kk < 8; kk++) {
        const unsigned short* abase = xb + (size_t)(bm + w * 32 + lm) * 256 + kk * 32 + lk * 8;
        short8 a0 = *(const short8*)(abase);
        short8 a1 = *(const short8*)(abase + 16 * 256);
        const unsigned short* bbase = bfrag + ((t0 * 8 + kk) * 64 + l) * 8;
        short8 b[4];
#pragma unroll
        for (int j = 0; j < 4; j++) b[j] = *(const short8*)(bbase + j * 8 * 64 * 8);
#pragma unroll
        for (int j = 0; j < 4; j++) {
            acc[0][j] = __builtin_amdgcn_mfma_f32_16x16x32_bf16(a0, b[j], acc[0][j], 0, 0, 0);
            acc[1][j] = __builtin_amdgcn_mfma_f32_16x16x32_bf16(a1, b[j], acc[1][j], 0, 0, 0);
        }
    }
#pragma unroll
    for (int i = 0; i < 2; i++) {
        int row0 = bm + w * 32 + i * 16 + lk * 4;
#pragma unroll
        for (int r = 0; r < 4; r++) {
            int row = row0 + r;
            if (row >= NNODES) continue;
#pragma unroll
            for (int j = 0; j < 4; j++) {
                int col = n0 + j * 16 + lm;
                fs1b[(size_t)row * 256 + col] = f2bf(acc[i][j][r]);
            }
        }
    }
    float alv[4], arv[4];
#pragma unroll
    for (int j = 0; j < 4; j++) {
        alv[j] = al1[head * 64 + j * 16 + lm];
        arv[j] = ar1[head * 64 + j * 16 + lm];
    }
#pragma unroll
    for (int i = 0; i < 2; i++) {
#pragma unroll
        for (int r = 0; r < 4; r++) {
            float pe = 0.f, pr = 0.f;
#pragma unroll
            for (int j = 0; j < 4; j++) {
                float fr = bf2f(f2bf(acc[i][j][r]));
                pe += fr * alv[j];
                pr += fr * arv[j];
            }
#pragma unroll
            for (int off = 1; off < 16; off <<= 1) {
                pe += __shfl_xor(pe, off);
                pr += __shfl_xor(pr, off);
            }
            int row = bm + w * 32 + i * 16 + lk * 4 + r;
            if (lm == 0 && row < NNODES) {
                el[row * 4 + head] = pe;
                er[row * 4 + head] = pr;
            }
        }
    }
}

// ---------------------------------------------------------------------------
// GEMM2 + fused logits2 (verified R11).
// ---------------------------------------------------------------------------
__global__ __launch_bounds__(256) void mfma_gemm2(const unsigned short* __restrict__ h1b,
                                                  const unsigned short* __restrict__ bfrag,
                                                  const float* __restrict__ al2,
                                                  const float* __restrict__ ar2,
                                                  unsigned short* __restrict__ fs2b,
                                                  float* __restrict__ el,
                                                  float* __restrict__ er) {
    const int w = threadIdx.x >> 6;
    const int l = threadIdx.x & 63;
    const int bm = blockIdx.x * 128;
    const int lm = l & 15, lk = l >> 4;

    floatx4 acc[2][3];
#pragma unroll
    for (int i = 0; i < 2; i++)
#pragma unroll
        for (int j = 0; j < 3; j++) acc[i][j] = (floatx4){0.f, 0.f, 0.f, 0.f};

#pragma unroll
    for (int kk = 0; kk < 8; kk++) {
        const unsigned short* abase = h1b + (size_t)(bm + w * 32 + lm) * 256 + kk * 32 + lk * 8;
        short8 a0 = *(const short8*)(abase);
        short8 a1 = *(const short8*)(abase + 16 * 256);
        const unsigned short* bbase = bfrag + (size_t)(kk * 64 + l) * 8;
        short8 b[3];
#pragma unroll
        for (int j = 0; j < 3; j++) b[j] = *(const short8*)(bbase + j * (8 * 64 * 8));
#pragma unroll
        for (int j = 0; j < 3; j++) {
            acc[0][j] = __builtin_amdgcn_mfma_f32_16x16x32_bf16(a0, b[j], acc[0][j], 0, 0, 0);
            acc[1][j] = __builtin_amdgcn_mfma_f32_16x16x32_bf16(a1, b[j], acc[1][j], 0, 0, 0);
        }
    }
#pragma unroll
    for (int i = 0; i < 2; i++) {
        int row0 = bm + w * 32 + i * 16 + lk * 4;
#pragma unroll
        for (int r = 0; r < 4; r++) {
            int row = row0 + r;
            if (row >= NNODES) continue;
#pragma unroll
            for (int j = 0; j < 3; j++) {
                int col = j * 16 + lm;
                fs2b[(size_t)row * 48 + col] = f2bf(acc[i][j][r]);
            }
        }
    }
    float alv[3], arv[3];
#pragma unroll
    for (int j = 0; j < 3; j++) {
        int col = j * 16 + lm;
        alv[j] = (col < 47) ? al2[col] : 0.f;
        arv[j] = (col < 47) ? ar2[col] : 0.f;
    }
#pragma unroll
    for (int i = 0; i < 2; i++) {
#pragma unroll
        for (int r = 0; r < 4; r++) {
            float pe = 0.f, pr = 0.f;
#pragma unroll
            for (int j = 0; j < 3; j++) {
                float fr = bf2f(f2bf(acc[i][j][r]));
                pe += fr * alv[j];
                pr += fr * arv[j];
            }
#pragma unroll
            for (int off = 1; off < 16; off <<= 1) {
                pe += __shfl_xor(pe, off);
                pr += __shfl_xor(pr, off);
            }
            int row = bm + w * 32 + i * 16 + lk * 4 + r;
            if (lm == 0 && row < NNODES) {
                el[row] = pe;
                er[row] = pr;
            }
        }
    }
}

// ---------------------------------------------------------------------------
// Layer-1 softmax + aggregate — wave per node. CHANGE vs R11: pass B uses
// 16 lanes per edge (group g=l>>4 takes edges j=g step 4; lane c16=l&15 owns
// 16 contiguous channels via 2 uint4 loads) -> 8 outstanding loads per wave
// (was 2). Head hl=c16>>2 is exact (16 | 64). Cross-group reduce: 2 shfl
// steps. Softmax phases unchanged (single-exp fast / online slow).
// ---------------------------------------------------------------------------
__global__ __launch_bounds__(256) void agg1(const int* __restrict__ row_ptr,
                                            const int* __restrict__ src,
                                            const float* __restrict__ el,
                                            const float* __restrict__ er,
                                            const unsigned short* __restrict__ fs1b,
                                            const float* __restrict__ b1,
                                            unsigned short* __restrict__ h1b) {
    __shared__ float wcache[4][CAPW * 4];
    __shared__ int   scache[4][CAPW];
    const int q = threadIdx.x >> 6;
    const int l = threadIdx.x & 63;
    const int n = blockIdx.x * 4 + q;          // 12500*4 == NNODES exactly
    const int start = row_ptr[n], end = row_ptr[n + 1];
    const int deg = end - start;

    const float4 erv = *(const float4*)(er + n * 4);
    const int g = l >> 4;        // edge group 0..3
    const int c16 = l & 15;      // channel lane: owns channels c16*16 .. +15
    const int hl = c16 >> 2;     // head of those channels
    float a[16] = {};

    if (deg <= CAPW) {
        // ---- softmax: one edge per lane, single exp per head ----
        const bool act = l < deg;
        int sv = 0;
        float e0 = -1e30f, e1 = -1e30f, e2 = -1e30f, e3 = -1e30f;
        if (act) {
            sv = src[start + l];
            float4 e4 = *(const float4*)(el + sv * 4);
            e0 = lrelu(e4.x + erv.x);
            e1 = lrelu(e4.y + erv.y);
            e2 = lrelu(e4.z + erv.z);
            e3 = lrelu(e4.w + erv.w);
        }
        float M0 = e0, M1 = e1, M2 = e2, M3 = e3;
#pragma unroll
        for (int off = 32; off > 0; off >>= 1) {
            M0 = fmaxf(M0, __shfl_xor(M0, off));
            M1 = fmaxf(M1, __shfl_xor(M1, off));
            M2 = fmaxf(M2, __shfl_xor(M2, off));
            M3 = fmaxf(M3, __shfl_xor(M3, off));
        }
        float w0 = act ? __expf(e0 - M0) : 0.f;
        float w1 = act ? __expf(e1 - M1) : 0.f;
        float w2 = act ? __expf(e2 - M2) : 0.f;
        float w3 = act ? __expf(e3 - M3) : 0.f;
        float S0 = w0, S1 = w1, S2 = w2, S3 = w3;
#pragma unroll
        for (int off = 32; off > 0; off >>= 1) {
            S0 += __shfl_xor(S0, off);
            S1 += __shfl_xor(S1, off);
            S2 += __shfl_xor(S2, off);
            S3 += __shfl_xor(S3, off);
        }
        const float rs0 = deg > 0 ? 1.f / S0 : 0.f;
        const float rs1 = deg > 0 ? 1.f / S1 : 0.f;
        const float rs2 = deg > 0 ? 1.f / S2 : 0.f;
        const float rs3 = deg > 0 ? 1.f / S3 : 0.f;
        if (act) {
            scache[q][l] = sv;
            *(float4*)(&wcache[q][l * 4]) =
                make_float4(w0 * rs0, w1 * rs1, w2 * rs2, w3 * rs3);
        }
        // ---- pass B: 4 edges in flight, 2 loads per lane per edge ----
        for (int j = g; j < deg; j += 4) {
            int svj = scache[q][j];
            float wv = wcache[q][j * 4 + hl];
            const unsigned short* p = fs1b + (size_t)svj * 256 + c16 * 16;
            uint4 g0 = *(const uint4*)(p);
            uint4 g1 = *(const uint4*)(p + 8);
            a[0]  += wv * bf2f(g0.x & 0xFFFFu); a[1]  += wv * bf2f(g0.x >> 16);
            a[2]  += wv * bf2f(g0.y & 0xFFFFu); a[3]  += wv * bf2f(g0.y >> 16);
            a[4]  += wv * bf2f(g0.z & 0xFFFFu); a[5]  += wv * bf2f(g0.z >> 16);
            a[6]  += wv * bf2f(g0.w & 0xFFFFu); a[7]  += wv * bf2f(g0.w >> 16);
            a[8]  += wv * bf2f(g1.x & 0xFFFFu); a[9]  += wv * bf2f(g1.x >> 16);
            a[10] += wv * bf2f(g1.y & 0xFFFFu); a[11] += wv * bf2f(g1.y >> 16);
            a[12] += wv * bf2f(g1.z & 0xFFFFu); a[13] += wv * bf2f(g1.z >> 16);
            a[14] += wv * bf2f(g1.w & 0xFFFFu); a[15] += wv * bf2f(g1.w >> 16);
        }
    } else {
        // ---- slow path (deg > 64): online phase 1, per-edge recompute ----
        float m0 = -1e30f, m1 = -1e30f, m2 = -1e30f, m3 = -1e30f;
        float s0 = 0.f, s1 = 0.f, s2 = 0.f, s3 = 0.f;
        for (int i = start + l; i < end; i += 64) {
            float4 e4 = *(const float4*)(el + src[i] * 4);
            float e;
            e = lrelu(e4.x + erv.x); { float nm = fmaxf(m0, e); s0 = s0 * __expf(m0 - nm) + __expf(e - nm); m0 = nm; }
            e = lrelu(e4.y + erv.y); { float nm = fmaxf(m1, e); s1 = s1 * __expf(m1 - nm) + __expf(e - nm); m1 = nm; }
            e = lrelu(e4.z + erv.z); { float nm = fmaxf(m2, e); s2 = s2 * __expf(m2 - nm) + __expf(e - nm); m2 = nm; }
            e = lrelu(e4.w + erv.w); { float nm = fmaxf(m3, e); s3 = s3 * __expf(m3 - nm) + __expf(e - nm); m3 = nm; }
        }
        for (int off = 32; off > 0; off >>= 1) {
            float mo, so, nm;
            mo = __shfl_xor(m0, off); so = __shfl_xor(s0, off);
            nm = fmaxf(m0, mo); s0 = s0 * __expf(m0 - nm) + so * __expf(mo - nm); m0 = nm;
            mo = __shfl_xor(m1, off); so = __shfl_xor(s1, off);
            nm = fmaxf(m1, mo); s1 = s1 * __expf(m1 - nm) + so * __expf(mo - nm); m1 = nm;
            mo = __shfl_xor(m2, off); so = __shfl_xor(s2, off);
            nm = fmaxf(m2, mo); s2 = s2 * __expf(m2 - nm) + so * __expf(mo - nm); m2 = nm;
            mo = __shfl_xor(m3, off); so = __shfl_xor(s3, off);
            nm = fmaxf(m3, mo); s3 = s3 * __expf(m3 - nm) + so * __expf(mo - nm); m3 = nm;
        }
        const float Mh  = hl == 0 ? m0 : hl == 1 ? m1 : hl == 2 ? m2 : m3;
        const float Sh  = hl == 0 ? s0 : hl == 1 ? s1 : hl == 2 ? s2 : s3;
        const float rsh = deg > 0 ? 1.f / Sh : 0.f;
        const float ervh = hl == 0 ? erv.x : hl == 1 ? erv.y : hl == 2 ? erv.z : erv.w;
        for (int j = g; j < deg; j += 4) {
            int svj = src[start + j];
            float e = lrelu(el[svj * 4 + hl] + ervh);
            float wv = __expf(e - Mh) * rsh;
            const unsigned short* p = fs1b + (size_t)svj * 256 + c16 * 16;
            uint4 g0 = *(const uint4*)(p);
            uint4 g1 = *(const uint4*)(p + 8);
            a[0]  += wv * bf2f(g0.x & 0xFFFFu); a[1]  += wv * bf2f(g0.x >> 16);
            a[2]  += wv * bf2f(g0.y & 0xFFFFu); a[3]  += wv * bf2f(g0.y >> 16);
            a[4]  += wv * bf2f(g0.z & 0xFFFFu); a[5]  += wv * bf2f(g0.z >> 16);
            a[6]  += wv * bf2f(g0.w & 0xFFFFu); a[7]  += wv * bf2f(g0.w >> 16);
            a[8]  += wv * bf2f(g1.x & 0xFFFFu); a[9]  += wv * bf2f(g1.x >> 16);
            a[10] += wv * bf2f(g1.y & 0xFFFFu); a[11] += wv * bf2f(g1.y >> 16);
            a[12] += wv * bf2f(g1.z & 0xFFFFu); a[13] += wv * bf2f(g1.z >> 16);
            a[14] += wv * bf2f(g1.w & 0xFFFFu); a[15] += wv * bf2f(g1.w >> 16);
        }
    }
    // cross-group reduce (4 groups)
#pragma unroll
    for (int k = 0; k < 16; k++) {
        a[k] += __shfl_xor(a[k], 16);
        a[k] += __shfl_xor(a[k], 32);
    }
    if (g == 0) {   // l < 16: write channels c16*16 .. +15
        const float* bb = b1 + c16 * 16;
        float4 b0 = *(const float4*)(bb);
        float4 b1v = *(const float4*)(bb + 4);
        float4 b2v = *(const float4*)(bb + 8);
        float4 b3v = *(const float4*)(bb + 12);
        float v[16];
        v[0]  = fmaxf(a[0]  + b0.x, 0.f); v[1]  = fmaxf(a[1]  + b0.y, 0.f);
        v[2]  = fmaxf(a[2]  + b0.z, 0.f); v[3]  = fmaxf(a[3]  + b0.w, 0.f);
        v[4]  = fmaxf(a[4]  + b1v.x, 0.f); v[5]  = fmaxf(a[5]  + b1v.y, 0.f);
        v[6]  = fmaxf(a[6]  + b1v.z, 0.f); v[7]  = fmaxf(a[7]  + b1v.w, 0.f);
        v[8]  = fmaxf(a[8]  + b2v.x, 0.f); v[9]  = fmaxf(a[9]  + b2v.y, 0.f);
        v[10] = fmaxf(a[10] + b2v.z, 0.f); v[11] = fmaxf(a[11] + b2v.w, 0.f);
        v[12] = fmaxf(a[12] + b3v.x, 0.f); v[13] = fmaxf(a[13] + b3v.y, 0.f);
        v[14] = fmaxf(a[14] + b3v.z, 0.f); v[15] = fmaxf(a[15] + b3v.w, 0.f);
        uint4 o0, o1;
        o0.x = (unsigned)f2bf(v[0])  | ((unsigned)f2bf(v[1])  << 16);
        o0.y = (unsigned)f2bf(v[2])  | ((unsigned)f2bf(v[3])  << 16);
        o0.z = (unsigned)f2bf(v[4])  | ((unsigned)f2bf(v[5])  << 16);
        o0.w = (unsigned)f2bf(v[6])  | ((unsigned)f2bf(v[7])  << 16);
        o1.x = (unsigned)f2bf(v[8])  | ((unsigned)f2bf(v[9])  << 16);
        o1.y = (unsigned)f2bf(v[10]) | ((unsigned)f2bf(v[11]) << 16);
        o1.z = (unsigned)f2bf(v[12]) | ((unsigned)f2bf(v[13]) << 16);
        o1.w = (unsigned)f2bf(v[14]) | ((unsigned)f2bf(v[15]) << 16);
        unsigned short* dstp = h1b + (size_t)n * 256 + c16 * 16;
        *(uint4*)(dstp) = o0;
        *(uint4*)(dstp + 8) = o1;
    }
}

// ---------------------------------------------------------------------------
// Layer-2 softmax + aggregate — wave per node, single-exp fast path
// (verbatim from R10/R11, verified).
// ---------------------------------------------------------------------------
__global__ __launch_bounds__(256) void agg2(const int* __restrict__ row_ptr,
                                            const int* __restrict__ src,
                                            const float* __restrict__ el,
                                            const float* __restrict__ er,
                                            const unsigned short* __restrict__ fs2b,
                                            const float* __restrict__ b2,
                                            float* __restrict__ out) {
    __shared__ float wcache[4][CAPW];
    __shared__ int   scache[4][CAPW];
    const int q = threadIdx.x >> 6;
    const int l = threadIdx.x & 63;
    const int n = blockIdx.x * 4 + q;
    const int start = row_ptr[n], end = row_ptr[n + 1];
    const int deg = end - start;
    const float erv = er[n];

    const int sub = l >> 5, c = l & 31;
    float a0 = 0.f, a1 = 0.f;

    if (deg <= CAPW) {
        const bool act = l < deg;
        int sv = 0;
        float e = -1e30f;
        if (act) {
            sv = src[start + l];
            e = lrelu(el[sv] + erv);
        }
        float M = e;
#pragma unroll
        for (int off = 32; off > 0; off >>= 1) M = fmaxf(M, __shfl_xor(M, off));
        float w = act ? __expf(e - M) : 0.f;
        float S = w;
#pragma unroll
        for (int off = 32; off > 0; off >>= 1) S += __shfl_xor(S, off);
        const float rs = deg > 0 ? 1.f / S : 0.f;
        if (act) {
            scache[q][l] = sv;
            wcache[q][l] = w * rs;
        }
        for (int j = sub; j < deg; j += 2) {
            int svj = scache[q][j];
            float wv = wcache[q][j];
            if (c < 24) {
                unsigned int g = *(const unsigned int*)(fs2b + (size_t)svj * 48 + c * 2);
                a0 += wv * bf2f(g & 0xFFFFu);
                a1 += wv * bf2f(g >> 16);
            }
        }
    } else {
        float m = -1e30f, s = 0.f;
        for (int i = start + l; i < end; i += 64) {
            float e = lrelu(el[src[i]] + erv);
            float nm = fmaxf(m, e);
            s = s * __expf(m - nm) + __expf(e - nm);
            m = nm;
        }
        for (int off = 32; off > 0; off >>= 1) {
            float mo = __shfl_xor(m, off), so = __shfl_xor(s, off);
            float nm = fmaxf(m, mo);
            s = s * __expf(m - nm) + so * __expf(mo - nm);
            m = nm;
        }
        const float rs = deg > 0 ? 1.f / s : 0.f;
        for (int j = sub; j < deg; j += 2) {
            int svj = src[start + j];
            float wv = __expf(lrelu(el[svj] + erv) - m) * rs;
            if (c < 24) {
                unsigned int g = *(const unsigned int*)(fs2b + (size_t)svj * 48 + c * 2);
                a0 += wv * bf2f(g & 0xFFFFu);
                a1 += wv * bf2f(g >> 16);
            }
        }
    }
    a0 += __shfl_xor(a0, 32);
    a1 += __shfl_xor(a1, 32);
    if (sub == 0 && c < 24) {
        int ch = c * 2;
        out[(size_t)n * 47 + ch] = a0 + b2[ch];
        if (ch + 1 < 47) out[(size_t)n * 47 + ch + 1] = a1 + b2[ch + 1];
    }
}

// ---------------------------------------------------------------------------
// Launch. Inputs: 0:x 1:W1 2:al1 3:ar1 4:b1 5:W2 6:al2 7:ar2 8:b2 9:src 10:dst
// ---------------------------------------------------------------------------
extern "C" void kernel_launch(void* const* d_in, const int* in_sizes, int n_in,
                              void* d_out, int out_size, void* d_ws, size_t ws_size,
                              hipStream_t stream) {
    const float* x   = (const float*)d_in[0];
    const float* W1  = (const float*)d_in[1];
    const float* al1 = (const float*)d_in[2];
    const float* ar1 = (const float*)d_in[3];
    const float* b1  = (const float*)d_in[4];
    const float* W2  = (const float*)d_in[5];
    const float* al2 = (const float*)d_in[6];
    const float* ar2 = (const float*)d_in[7];
    const float* b2  = (const float*)d_in[8];
    const int*   src = (const int*)d_in[9];
    const int*   dst = (const int*)d_in[10];
    float* out = (float*)d_out;

    char* ws = (char*)d_ws;
    size_t off = 0;
    auto alloc = [&](size_t bytes) {
        void* p = ws + off;
        off += (bytes + 255) & ~(size_t)255;
        return p;
    };
    int*            row_ptr = (int*)alloc((NNODES + 1) * sizeof(int));
    unsigned short* xb      = (unsigned short*)alloc((size_t)MPAD * 256 * 2);
    unsigned short* bfrag1  = (unsigned short*)alloc(16 * 8 * 64 * 8 * 2);
    unsigned short* bfrag2  = (unsigned short*)alloc(3 * 8 * 64 * 8 * 2);
    unsigned short* fs1b    = (unsigned short*)alloc((size_t)NNODES * 256 * 2);
    unsigned short* h1b     = (unsigned short*)alloc((size_t)MPAD * 256 * 2);
    unsigned short* fs2b    = (unsigned short*)alloc((size_t)NNODES * 48 * 2);
    float*          el1     = (float*)alloc((size_t)NNODES * 4 * sizeof(float));
    float*          er1     = (float*)alloc((size_t)NNODES * 4 * sizeof(float));
    float*          el2     = (float*)alloc((size_t)NNODES * sizeof(float));
    float*          er2     = (float*)alloc((size_t)NNODES * sizeof(float));
    (void)ws_size; (void)n_in; (void)in_sizes; (void)out_size;

    prep<<<12794, 256, 0, stream>>>(x, W1, W2, dst, xb, bfrag1, bfrag2, h1b, row_ptr);

    // Layer 1 (logits fused into gemm1 epilogue)
    mfma_gemm1<<<dim3(MPAD / 128, 4), 256, 0, stream>>>(xb, bfrag1, al1, ar1, fs1b, el1, er1);
    agg1<<<NNODES / 4, 256, 0, stream>>>(row_ptr, src, el1, er1, fs1b, b1, h1b);

    // Layer 2 (logits fused into gemm2 epilogue)
    mfma_gemm2<<<MPAD / 128, 256, 0, stream>>>(h1b, bfrag2, al2, ar2, fs2b, el2, er2);
    agg2<<<NNODES / 4, 256, 0, stream>>>(row_ptr, src, el2, er2, fs2b, b2, out);
}